// Round 5
// baseline (1072.879 us; speedup 1.0000x reference)
//
#include <hip/hip_runtime.h>

#define D 128
#define EDIM 64
#define NODE_F 32
#define EDGE_F 16
#define B_PAIRS 256
#define MAXN 64
#define PROP_STEPS 3

#define MTA 32    // rows per block in attfeat kernel
#define KC 16     // k-panel size for LDS-staged weights (fp32 kernels)

typedef __attribute__((ext_vector_type(8))) short short8;
typedef __attribute__((ext_vector_type(16))) float floatx16;

__device__ __forceinline__ short f2bf(float x) {
  unsigned u = __float_as_uint(x);
  u = (u + 0x7fff + ((u >> 16) & 1)) >> 16;   // RNE
  return (short)u;
}

// ---------------- weight prep: fragment-order layouts ----------------
// Wf[step][hi][n][j] with step = p*2+ks, k = p*32+ks*16+hi*8+j.
// Wf1: 20 steps x 2 x 256 x 8 = 81920; Wf2: 16 steps -> 65536; Wfu: 24 steps x 2 x 128 x 8 = 49152.
__global__ __launch_bounds__(256) void prep_w(
    const float* __restrict__ W1, const float* __restrict__ W2,
    const float* __restrict__ Wu,
    short* __restrict__ Wf1, short* __restrict__ Wf2, short* __restrict__ Wfu)
{
  int idx = blockIdx.x * 256 + threadIdx.x;
  if (idx < 81920) {
    int p = idx >> 13, ks = (idx >> 12) & 1, hi = (idx >> 11) & 1;
    int n = (idx >> 3) & 255, j = idx & 7;
    int k = p * 32 + ks * 16 + hi * 8 + j;
    Wf1[idx] = f2bf(W1[(size_t)k * 256 + n]);
  } else if (idx < 147456) {
    int i = idx - 81920;
    int p = i >> 13, ks = (i >> 12) & 1, hi = (i >> 11) & 1;
    int n = (i >> 3) & 255, j = i & 7;
    int k = p * 32 + ks * 16 + hi * 8 + j;
    Wf2[i] = f2bf(W2[(size_t)k * 256 + n]);
  } else if (idx < 196608) {
    int i = idx - 147456;
    int p = i >> 12, ks = (i >> 11) & 1, hi = (i >> 10) & 1;
    int n = (i >> 3) & 127, j = i & 7;
    int k = p * 32 + ks * 16 + hi * 8 + j;
    Wfu[i] = f2bf(Wu[(size_t)k * 128 + n]);
  }
}

// ---------------- encoders ----------------
__global__ __launch_bounds__(256) void encode_nodes(
    const float* __restrict__ nf, const float* __restrict__ W,
    const float* __restrict__ bias, float* __restrict__ h,
    short* __restrict__ hb, int N)
{
  int t = threadIdx.x;
  int n = blockIdx.x * 2 + (t >> 7);
  int c = t & 127;
  if (n >= N) return;
  float acc = bias[c];
  #pragma unroll
  for (int k = 0; k < NODE_F; k++)
    acc += nf[(size_t)n * NODE_F + k] * W[k * D + c];
  h[(size_t)n * D + c] = acc;
  hb[(size_t)n * D + c] = f2bf(acc);
}

__global__ __launch_bounds__(256) void encode_edges(
    const float* __restrict__ ef, const float* __restrict__ W,
    const float* __restrict__ bias, short* __restrict__ eb, int E)
{
  int t = threadIdx.x;
  int eid = blockIdx.x * 4 + (t >> 6);
  int c = t & 63;
  if (eid >= E) return;
  float acc = bias[c];
  #pragma unroll
  for (int k = 0; k < EDGE_F; k++)
    acc += ef[(size_t)eid * EDGE_F + k] * W[k * EDIM + c];
  eb[(size_t)eid * EDIM + c] = f2bf(acc);
}

// ---------------- message + aggregate: bf16 MFMA, barrier-free K-loops ----------------
// M=64 edges/block. Wave w: rows (w&1)*32..+32, cols (w>>1)*128..+128 (4 x 32-col tiles).
// B fragments streamed directly from global (L2-resident, coalesced 16B/lane).
// Only 3 barriers per block; compiler free to pipeline loads with fine vmcnt.
__global__ __launch_bounds__(256, 3) void msg_mfma(
    const short* __restrict__ hb, const short* __restrict__ eb,
    const int* __restrict__ from_idx, const int* __restrict__ to_idx,
    const short* __restrict__ Wf1, const float* __restrict__ b1,
    const short* __restrict__ Wf2, const float* __restrict__ b2,
    float* __restrict__ agg, int E)
{
  __shared__ short sA[64 * 328];   // 41984B: edge_in (K=320), later hidden (K=256)
  __shared__ int from_s[64], to_s[64];

  int t = threadIdx.x;
  int ln = t & 63, w = t >> 6;
  int l31 = ln & 31, hi = ln >> 5;
  int cb = (w >> 1) * 128;             // column base of this wave
  int rowb = (w & 1) * 32;             // row base of this wave
  int e0 = blockIdx.x * 64;

  if (t < 64) {
    int eid = e0 + t;
    from_s[t] = (eid < E) ? from_idx[eid] : 0;
    to_s[t]   = (eid < E) ? to_idx[eid]   : 0;
  }
  __syncthreads();

  // stage A = [h[from] | h[to] | e] bf16, row stride 328 shorts
  for (int i = t; i < 1024; i += 256) {
    int r = i >> 4, c = i & 15;
    *(short8*)(sA + r * 328 + c * 8) =
        *(const short8*)(hb + (size_t)from_s[r] * 128 + c * 8);
  }
  for (int i = t; i < 1024; i += 256) {
    int r = i >> 4, c = i & 15;
    *(short8*)(sA + r * 328 + 128 + c * 8) =
        *(const short8*)(hb + (size_t)to_s[r] * 128 + c * 8);
  }
  for (int i = t; i < 512; i += 256) {
    int r = i >> 3, c = i & 7;
    short8 v = {0, 0, 0, 0, 0, 0, 0, 0};
    if (e0 + r < E) v = *(const short8*)(eb + (size_t)(e0 + r) * 64 + c * 8);
    *(short8*)(sA + r * 328 + 256 + c * 8) = v;
  }
  __syncthreads();

  const int arow = (rowb + l31) * 328;
  const int bcol = (cb + l31) * 8;     // + ct*256 shorts per 32-col tile

  floatx16 acc[4];
  #pragma unroll
  for (int ct = 0; ct < 4; ct++)
    #pragma unroll
    for (int i = 0; i < 16; i++) acc[ct][i] = 0.f;

  // ---- GEMM1: 20 steps, K=320, no barriers inside
  {
    short8 a_cur = *(const short8*)(sA + arow + hi * 8);
    short8 b_cur[4];
    {
      const short* bb = Wf1 + hi * 2048;
      #pragma unroll
      for (int ct = 0; ct < 4; ct++)
        b_cur[ct] = *(const short8*)(bb + bcol + ct * 256);
    }
    #pragma unroll
    for (int step = 0; step < 20; step++) {
      short8 a_nxt;
      short8 b_nxt[4];
      if (step + 1 < 20) {
        a_nxt = *(const short8*)(sA + arow + (step + 1) * 16 + hi * 8);
        const short* bb = Wf1 + (size_t)((step + 1) * 2 + hi) * 2048;
        #pragma unroll
        for (int ct = 0; ct < 4; ct++)
          b_nxt[ct] = *(const short8*)(bb + bcol + ct * 256);
      }
      #pragma unroll
      for (int ct = 0; ct < 4; ct++)
        acc[ct] = __builtin_amdgcn_mfma_f32_32x32x16_bf16(a_cur, b_cur[ct], acc[ct], 0, 0, 0);
      a_cur = a_nxt;
      #pragma unroll
      for (int ct = 0; ct < 4; ct++) b_cur[ct] = b_nxt[ct];
    }
  }

  // relu + bias, hidden (bf16) back into sA
  __syncthreads();   // all waves done reading edge_in
  #pragma unroll
  for (int ct = 0; ct < 4; ct++) {
    int col = cb + ct * 32 + l31;
    float bv = b1[col];
    #pragma unroll
    for (int reg = 0; reg < 16; reg++) {
      int row = rowb + (reg & 3) + 8 * (reg >> 2) + 4 * hi;
      sA[row * 328 + col] = f2bf(fmaxf(acc[ct][reg] + bv, 0.f));
    }
  }
  __syncthreads();

  // ---- GEMM2: 16 steps, K=256, no barriers inside
  floatx16 acc2[4];
  #pragma unroll
  for (int ct = 0; ct < 4; ct++)
    #pragma unroll
    for (int i = 0; i < 16; i++) acc2[ct][i] = 0.f;

  {
    short8 a_cur = *(const short8*)(sA + arow + hi * 8);
    short8 b_cur[4];
    {
      const short* bb = Wf2 + hi * 2048;
      #pragma unroll
      for (int ct = 0; ct < 4; ct++)
        b_cur[ct] = *(const short8*)(bb + bcol + ct * 256);
    }
    #pragma unroll
    for (int step = 0; step < 16; step++) {
      short8 a_nxt;
      short8 b_nxt[4];
      if (step + 1 < 16) {
        a_nxt = *(const short8*)(sA + arow + (step + 1) * 16 + hi * 8);
        const short* bb = Wf2 + (size_t)((step + 1) * 2 + hi) * 2048;
        #pragma unroll
        for (int ct = 0; ct < 4; ct++)
          b_nxt[ct] = *(const short8*)(bb + bcol + ct * 256);
      }
      #pragma unroll
      for (int ct = 0; ct < 4; ct++)
        acc2[ct] = __builtin_amdgcn_mfma_f32_32x32x16_bf16(a_cur, b_cur[ct], acc2[ct], 0, 0, 0);
      a_cur = a_nxt;
      #pragma unroll
      for (int ct = 0; ct < 4; ct++) b_cur[ct] = b_nxt[ct];
    }
  }

  // segment-sum via fp32 atomics
  #pragma unroll
  for (int ct = 0; ct < 4; ct++) {
    int col = cb + ct * 32 + l31;
    float bv = b2[col];
    #pragma unroll
    for (int reg = 0; reg < 16; reg++) {
      int grow = rowb + (reg & 3) + 8 * (reg >> 2) + 4 * hi;
      if (e0 + grow < E) {
        unsafeAtomicAdd(agg + (size_t)to_s[grow] * 256 + col, acc2[ct][reg] + bv);
      }
    }
  }
}

// ---------------- node update: bf16 MFMA, barrier-free K-loop ----------------
// h += concat(h, agg) @ Wu + bu.  M=32 nodes/block, K=384, N=128; wave w owns cols w*32.
__global__ __launch_bounds__(256, 4) void update_mfma(
    float* __restrict__ h, short* __restrict__ hbf, const float* __restrict__ agg,
    const short* __restrict__ Wfu, const float* __restrict__ bu, int N)
{
  __shared__ short sA[32 * 392];   // 25088B

  int t = threadIdx.x;
  int ln = t & 63, w = t >> 6;
  int l31 = ln & 31, hi = ln >> 5;
  int n0 = blockIdx.x * 32;

  // stage A: cols 0..127 = hbf[n], cols 128..383 = bf16(agg[n])
  for (int i = t; i < 512; i += 256) {
    int r = i >> 4, c = i & 15;
    short8 v = {0, 0, 0, 0, 0, 0, 0, 0};
    if (n0 + r < N) v = *(const short8*)(hbf + (size_t)(n0 + r) * 128 + c * 8);
    *(short8*)(sA + r * 392 + c * 8) = v;
  }
  for (int i = t; i < 2048; i += 256) {
    int r = i >> 6, c4 = i & 63;
    int2 pk = {0, 0};
    if (n0 + r < N) {
      float4 v = *(const float4*)(agg + (size_t)(n0 + r) * 256 + c4 * 4);
      pk.x = (int)(unsigned short)f2bf(v.x) | ((int)(unsigned short)f2bf(v.y) << 16);
      pk.y = (int)(unsigned short)f2bf(v.z) | ((int)(unsigned short)f2bf(v.w) << 16);
    }
    *(int2*)(sA + r * 392 + 128 + c4 * 4) = pk;
  }
  __syncthreads();

  const int arow = l31 * 392;
  const int bcol = (w * 32 + l31) * 8;

  floatx16 acc;
  #pragma unroll
  for (int i = 0; i < 16; i++) acc[i] = 0.f;

  {
    short8 a_cur = *(const short8*)(sA + arow + hi * 8);
    short8 b_cur = *(const short8*)(Wfu + hi * 1024 + bcol);
    #pragma unroll
    for (int step = 0; step < 24; step++) {
      short8 a_nxt, b_nxt;
      if (step + 1 < 24) {
        a_nxt = *(const short8*)(sA + arow + (step + 1) * 16 + hi * 8);
        b_nxt = *(const short8*)(Wfu + (size_t)((step + 1) * 2 + hi) * 1024 + bcol);
      }
      acc = __builtin_amdgcn_mfma_f32_32x32x16_bf16(a_cur, b_cur, acc, 0, 0, 0);
      a_cur = a_nxt; b_cur = b_nxt;
    }
  }

  int col = w * 32 + l31;
  float bv = bu[col];
  #pragma unroll
  for (int reg = 0; reg < 16; reg++) {
    int row = (reg & 3) + 8 * (reg >> 2) + 4 * hi;
    int n = n0 + row;
    if (n < N) {
      float nv = h[(size_t)n * 128 + col] + acc[reg] + bv;
      h[(size_t)n * 128 + col] = nv;
      hbf[(size_t)n * 128 + col] = f2bf(nv);
    }
  }
}

// ---------------- scatter into padded stacks ----------------
__global__ void scatter_kernel(const float* __restrict__ h, const int* __restrict__ pos,
                               float* __restrict__ flat, int N)
{
  int idx = blockIdx.x * 256 + threadIdx.x;
  if (idx >= N * D) return;
  int n = idx >> 7, c = idx & 127;
  flat[(size_t)pos[n] * D + c] = h[idx];
}

// ---------------- attention features (fp32) ----------------
__global__ __launch_bounds__(256) void attfeat_kernel(
    const float* __restrict__ flat,
    const float* __restrict__ Wa1, const float* __restrict__ ba1,
    const float* __restrict__ Wa2, const float* __restrict__ ba2,
    const int* __restrict__ qsizes, const int* __restrict__ csizes,
    float* __restrict__ tf)
{
  __shared__ float sA[MTA * 128];
  __shared__ float sW[KC * 128];
  int t = threadIdx.x, wv = t >> 6, ln = t & 63;
  int r0 = blockIdx.x * MTA;

  for (int i = t * 4; i < MTA * 128; i += 1024)
    *(float4*)(sA + i) = *(const float4*)(flat + (size_t)r0 * 128 + i);

  float2 bb = *(const float2*)(ba1 + ln * 2);
  float acc[8][2];
  #pragma unroll
  for (int j = 0; j < 8; j++) { acc[j][0] = bb.x; acc[j][1] = bb.y; }

  for (int kc = 0; kc < 128; kc += KC) {
    __syncthreads();
    for (int i = t * 4; i < KC * 128; i += 1024) {
      int kk = i >> 7, c = i & 127;
      *(float4*)(sW + i) = *(const float4*)(Wa1 + (size_t)(kc + kk) * 128 + c);
    }
    __syncthreads();
    #pragma unroll
    for (int k4 = 0; k4 < KC; k4 += 4) {
      float4 a[8];
      #pragma unroll
      for (int j = 0; j < 8; j++)
        a[j] = *(const float4*)(sA + (wv * 8 + j) * 128 + kc + k4);
      #pragma unroll
      for (int k2 = 0; k2 < 4; k2++) {
        float2 w = *(const float2*)(sW + (k4 + k2) * 128 + ln * 2);
        #pragma unroll
        for (int j = 0; j < 8; j++) {
          float av = (k2 == 0) ? a[j].x : (k2 == 1) ? a[j].y : (k2 == 2) ? a[j].z : a[j].w;
          acc[j][0] += av * w.x; acc[j][1] += av * w.y;
        }
      }
    }
  }

  __syncthreads();
  #pragma unroll
  for (int j = 0; j < 8; j++) {
    sA[(wv * 8 + j) * 128 + ln * 2 + 0] = fmaxf(acc[j][0], 0.f);
    sA[(wv * 8 + j) * 128 + ln * 2 + 1] = fmaxf(acc[j][1], 0.f);
  }

  float2 bb2 = *(const float2*)(ba2 + ln * 2);
  #pragma unroll
  for (int j = 0; j < 8; j++) { acc[j][0] = bb2.x; acc[j][1] = bb2.y; }

  for (int kc = 0; kc < 128; kc += KC) {
    __syncthreads();
    for (int i = t * 4; i < KC * 128; i += 1024) {
      int kk = i >> 7, c = i & 127;
      *(float4*)(sW + i) = *(const float4*)(Wa2 + (size_t)(kc + kk) * 128 + c);
    }
    __syncthreads();
    #pragma unroll
    for (int k4 = 0; k4 < KC; k4 += 4) {
      float4 a[8];
      #pragma unroll
      for (int j = 0; j < 8; j++)
        a[j] = *(const float4*)(sA + (wv * 8 + j) * 128 + kc + k4);
      #pragma unroll
      for (int k2 = 0; k2 < 4; k2++) {
        float2 w = *(const float2*)(sW + (k4 + k2) * 128 + ln * 2);
        #pragma unroll
        for (int j = 0; j < 8; j++) {
          float av = (k2 == 0) ? a[j].x : (k2 == 1) ? a[j].y : (k2 == 2) ? a[j].z : a[j].w;
          acc[j][0] += av * w.x; acc[j][1] += av * w.y;
        }
      }
    }
  }

  #pragma unroll
  for (int j = 0; j < 8; j++) {
    int row = r0 + wv * 8 + j;
    int part = row >> 14, b = (row >> 6) & 255, pp = row & 63;
    int sz = part ? csizes[b] : qsizes[b];
    float m = (pp < sz) ? 1.f : 0.f;
    tf[(size_t)row * 128 + ln * 2 + 0] = acc[j][0] * m;
    tf[(size_t)row * 128 + ln * 2 + 1] = acc[j][1] * m;
  }
}

// ---------------- per-pair attention score ----------------
__global__ __launch_bounds__(256, 2) void score_kernel(
    const float* __restrict__ tf, const float* __restrict__ flat,
    const int* __restrict__ qsizes, const int* __restrict__ csizes,
    float* __restrict__ out)
{
  __shared__ float SL[64 * 65];
  __shared__ float SP[64 * 65];
  __shared__ float SP2[64 * 65];
  __shared__ float Atk[16 * 68];
  __shared__ float Btk[16 * 68];
  __shared__ float red[8];

  int b = blockIdx.x, t = threadIdx.x;
  const float* tq = tf + (size_t)b * 64 * 128;
  const float* tc = tf + ((size_t)16384 + (size_t)b * 64) * 128;
  const float* sq = flat + (size_t)b * 64 * 128;
  const float* sc = flat + ((size_t)16384 + (size_t)b * 64) * 128;
  int qs = qsizes[b], cs = csizes[b];

  int qg = (t >> 4) << 2;
  int cg = (t & 15) << 2;
  int dg = (t & 15) << 3;

  float lg[4][4] = {};
  for (int kc = 0; kc < 128; kc += 16) {
    __syncthreads();
    for (int i = t; i < 16 * 64; i += 256) {
      int q = i >> 4, kk = i & 15;
      Atk[kk * 68 + q] = tq[q * 128 + kc + kk];
      Btk[kk * 68 + q] = tc[q * 128 + kc + kk];
    }
    __syncthreads();
    #pragma unroll
    for (int kk = 0; kk < 16; kk++) {
      float4 aq = *(const float4*)(Atk + kk * 68 + qg);
      float4 bc = *(const float4*)(Btk + kk * 68 + cg);
      lg[0][0] += aq.x * bc.x; lg[0][1] += aq.x * bc.y; lg[0][2] += aq.x * bc.z; lg[0][3] += aq.x * bc.w;
      lg[1][0] += aq.y * bc.x; lg[1][1] += aq.y * bc.y; lg[1][2] += aq.y * bc.z; lg[1][3] += aq.y * bc.w;
      lg[2][0] += aq.z * bc.x; lg[2][1] += aq.z * bc.y; lg[2][2] += aq.z * bc.z; lg[2][3] += aq.z * bc.w;
      lg[3][0] += aq.w * bc.x; lg[3][1] += aq.w * bc.y; lg[3][2] += aq.w * bc.z; lg[3][3] += aq.w * bc.w;
    }
  }
  #pragma unroll
  for (int j = 0; j < 4; j++)
    #pragma unroll
    for (int i = 0; i < 4; i++) {
      int q = qg + j, c = cg + i;
      SL[q * 65 + c] = (q < qs && c < cs) ? lg[j][i] * 10.0f : -1e9f;
    }
  __syncthreads();

  if (t < 64) {
    int q = t;
    if (q < qs) {
      float m = -1e30f;
      for (int c = 0; c < 64; c++) m = fmaxf(m, SL[q * 65 + c]);
      float s = 0.f;
      for (int c = 0; c < 64; c++) s += __expf(SL[q * 65 + c] - m);
      float inv = 1.0f / s;
      for (int c = 0; c < 64; c++) SP[q * 65 + c] = __expf(SL[q * 65 + c] - m) * inv;
    } else {
      for (int c = 0; c < 64; c++) SP[q * 65 + c] = 0.f;
    }
  } else if (t < 128) {
    int c = t - 64;
    if (c < cs) {
      float m = -1e30f;
      for (int q = 0; q < 64; q++) m = fmaxf(m, SL[q * 65 + c]);
      float s = 0.f;
      for (int q = 0; q < 64; q++) s += __expf(SL[q * 65 + c] - m);
      float inv = 1.0f / s;
      for (int q = 0; q < 64; q++) SP2[q * 65 + c] = __expf(SL[q * 65 + c] - m) * inv;
    } else {
      for (int q = 0; q < 64; q++) SP2[q * 65 + c] = 0.f;
    }
  }
  __syncthreads();

  float al[4][8] = {};
  for (int c = 0; c < 64; c++) {
    float p0 = SP[(qg + 0) * 65 + c];
    float p1 = SP[(qg + 1) * 65 + c];
    float p2 = SP[(qg + 2) * 65 + c];
    float p3 = SP[(qg + 3) * 65 + c];
    float4 s0 = *(const float4*)(sc + c * 128 + dg);
    float4 s1 = *(const float4*)(sc + c * 128 + dg + 4);
    al[0][0] += p0 * s0.x; al[0][1] += p0 * s0.y; al[0][2] += p0 * s0.z; al[0][3] += p0 * s0.w;
    al[0][4] += p0 * s1.x; al[0][5] += p0 * s1.y; al[0][6] += p0 * s1.z; al[0][7] += p0 * s1.w;
    al[1][0] += p1 * s0.x; al[1][1] += p1 * s0.y; al[1][2] += p1 * s0.z; al[1][3] += p1 * s0.w;
    al[1][4] += p1 * s1.x; al[1][5] += p1 * s1.y; al[1][6] += p1 * s1.z; al[1][7] += p1 * s1.w;
    al[2][0] += p2 * s0.x; al[2][1] += p2 * s0.y; al[2][2] += p2 * s0.z; al[2][3] += p2 * s0.w;
    al[2][4] += p2 * s1.x; al[2][5] += p2 * s1.y; al[2][6] += p2 * s1.z; al[2][7] += p2 * s1.w;
    al[3][0] += p3 * s0.x; al[3][1] += p3 * s0.y; al[3][2] += p3 * s0.z; al[3][3] += p3 * s0.w;
    al[3][4] += p3 * s1.x; al[3][5] += p3 * s1.y; al[3][6] += p3 * s1.z; al[3][7] += p3 * s1.w;
  }
  float qpart = 0.f;
  #pragma unroll
  for (int j = 0; j < 4; j++) {
    float4 a0 = *(const float4*)(sq + (qg + j) * 128 + dg);
    float4 a1 = *(const float4*)(sq + (qg + j) * 128 + dg + 4);
    qpart += fmaxf(a0.x - al[j][0], 0.f) + fmaxf(a0.y - al[j][1], 0.f)
           + fmaxf(a0.z - al[j][2], 0.f) + fmaxf(a0.w - al[j][3], 0.f)
           + fmaxf(a1.x - al[j][4], 0.f) + fmaxf(a1.y - al[j][5], 0.f)
           + fmaxf(a1.z - al[j][6], 0.f) + fmaxf(a1.w - al[j][7], 0.f);
  }

  float al2[4][8] = {};
  for (int q = 0; q < 64; q++) {
    float p0 = SP2[q * 65 + qg + 0];
    float p1 = SP2[q * 65 + qg + 1];
    float p2 = SP2[q * 65 + qg + 2];
    float p3 = SP2[q * 65 + qg + 3];
    float4 s0 = *(const float4*)(sq + q * 128 + dg);
    float4 s1 = *(const float4*)(sq + q * 128 + dg + 4);
    al2[0][0] += p0 * s0.x; al2[0][1] += p0 * s0.y; al2[0][2] += p0 * s0.z; al2[0][3] += p0 * s0.w;
    al2[0][4] += p0 * s1.x; al2[0][5] += p0 * s1.y; al2[0][6] += p0 * s1.z; al2[0][7] += p0 * s1.w;
    al2[1][0] += p1 * s0.x; al2[1][1] += p1 * s0.y; al2[1][2] += p1 * s0.z; al2[1][3] += p1 * s0.w;
    al2[1][4] += p1 * s1.x; al2[1][5] += p1 * s1.y; al2[1][6] += p1 * s1.z; al2[1][7] += p1 * s1.w;
    al2[2][0] += p2 * s0.x; al2[2][1] += p2 * s0.y; al2[2][2] += p2 * s0.z; al2[2][3] += p2 * s0.w;
    al2[2][4] += p2 * s1.x; al2[2][5] += p2 * s1.y; al2[2][6] += p2 * s1.z; al2[2][7] += p2 * s1.w;
    al2[3][0] += p3 * s0.x; al2[3][1] += p3 * s0.y; al2[3][2] += p3 * s0.z; al2[3][3] += p3 * s0.w;
    al2[3][4] += p3 * s1.x; al2[3][5] += p3 * s1.y; al2[3][6] += p3 * s1.z; al2[3][7] += p3 * s1.w;
  }
  float cpart = 0.f;
  #pragma unroll
  for (int j = 0; j < 4; j++) {
    float4 b0 = *(const float4*)(sc + (qg + j) * 128 + dg);
    float4 b1 = *(const float4*)(sc + (qg + j) * 128 + dg + 4);
    cpart += fmaxf(b0.x - al2[j][0], 0.f) + fmaxf(b0.y - al2[j][1], 0.f)
           + fmaxf(b0.z - al2[j][2], 0.f) + fmaxf(b0.w - al2[j][3], 0.f)
           + fmaxf(b1.x - al2[j][4], 0.f) + fmaxf(b1.y - al2[j][5], 0.f)
           + fmaxf(b1.z - al2[j][6], 0.f) + fmaxf(b1.w - al2[j][7], 0.f);
  }

  for (int off = 32; off > 0; off >>= 1) {
    qpart += __shfl_down(qpart, off);
    cpart += __shfl_down(cpart, off);
  }
  int wv = t >> 6;
  if ((t & 63) == 0) { red[wv] = qpart; red[wv + 4] = cpart; }
  __syncthreads();
  if (t == 0) {
    float qsum = red[0] + red[1] + red[2] + red[3];
    float csum = red[4] + red[5] + red[6] + red[7];
    out[b] = fminf(-qsum, -csum);
  }
}

// ---------------- launch ----------------
extern "C" void kernel_launch(void* const* d_in, const int* in_sizes, int n_in,
                              void* d_out, int out_size, void* d_ws, size_t ws_size,
                              hipStream_t stream)
{
  const float* nf  = (const float*)d_in[0];
  const float* ef  = (const float*)d_in[1];
  const int* from_idx = (const int*)d_in[2];
  const int* to_idx   = (const int*)d_in[3];
  const int* pos      = (const int*)d_in[4];
  const int* qsz      = (const int*)d_in[5];
  const int* csz      = (const int*)d_in[6];
  const float* W_node = (const float*)d_in[7];
  const float* b_node = (const float*)d_in[8];
  const float* W_edge = (const float*)d_in[9];
  const float* b_edge = (const float*)d_in[10];
  const float* W1 = (const float*)d_in[11];
  const float* b1 = (const float*)d_in[12];
  const float* W2 = (const float*)d_in[13];
  const float* b2 = (const float*)d_in[14];
  const float* Wu = (const float*)d_in[15];
  const float* bu = (const float*)d_in[16];
  const float* Wa1 = (const float*)d_in[17];
  const float* ba1 = (const float*)d_in[18];
  const float* Wa2 = (const float*)d_in[19];
  const float* ba2 = (const float*)d_in[20];
  float* out = (float*)d_out;

  int N = in_sizes[0] / NODE_F;
  int E = in_sizes[1] / EDGE_F;

  float* h    = (float*)d_ws;
  float* agg  = h + (size_t)N * D;
  float* flat = agg + (size_t)N * 256;
  float* tfb  = flat + (size_t)2 * B_PAIRS * MAXN * D;
  short* hb   = (short*)(tfb + (size_t)2 * B_PAIRS * MAXN * D);
  short* eb   = hb + (size_t)N * D;
  short* Wf1  = eb + (size_t)E * EDIM;
  short* Wf2  = Wf1 + 81920;
  short* Wfu  = Wf2 + 65536;

  hipMemsetAsync(flat, 0, (size_t)2 * B_PAIRS * MAXN * D * sizeof(float), stream);

  prep_w<<<768, 256, 0, stream>>>(W1, W2, Wu, Wf1, Wf2, Wfu);
  encode_nodes<<<(N + 1) / 2, 256, 0, stream>>>(nf, W_node, b_node, h, hb, N);
  encode_edges<<<(E + 3) / 4, 256, 0, stream>>>(ef, W_edge, b_edge, eb, E);

  for (int s = 0; s < PROP_STEPS; s++) {
    hipMemsetAsync(agg, 0, (size_t)N * 256 * sizeof(float), stream);
    msg_mfma<<<(E + 63) / 64, 256, 0, stream>>>(hb, eb, from_idx, to_idx,
                                                Wf1, b1, Wf2, b2, agg, E);
    update_mfma<<<(N + 31) / 32, 256, 0, stream>>>(h, hb, agg, Wfu, bu, N);
  }

  scatter_kernel<<<(N * D + 255) / 256, 256, 0, stream>>>(h, pos, flat, N);
  attfeat_kernel<<<(2 * B_PAIRS * MAXN) / MTA, 256, 0, stream>>>(flat, Wa1, ba1, Wa2, ba2,
                                                                 qsz, csz, tfb);
  score_kernel<<<B_PAIRS, 256, 0, stream>>>(tfb, flat, qsz, csz, out);
}

// Round 6
// 756.857 us; speedup vs baseline: 1.4175x; 1.4175x over previous
//
#include <hip/hip_runtime.h>

#define D 128
#define EDIM 64
#define NODE_F 32
#define EDGE_F 16
#define B_PAIRS 256
#define MAXN 64
#define PROP_STEPS 3

#define MTA 32
#define KC 16

typedef __attribute__((ext_vector_type(8))) short short8;
typedef __attribute__((ext_vector_type(16))) float floatx16;

__device__ __forceinline__ short f2bf(float x) {
  unsigned u = __float_as_uint(x);
  u = (u + 0x7fff + ((u >> 16) & 1)) >> 16;   // RNE
  return (short)u;
}

// ---------------- weight prep: fragment-order layouts ----------------
__global__ __launch_bounds__(256) void prep_w(
    const float* __restrict__ W1, const float* __restrict__ W2,
    const float* __restrict__ Wu,
    short* __restrict__ Wf1, short* __restrict__ Wf2, short* __restrict__ Wfu)
{
  int idx = blockIdx.x * 256 + threadIdx.x;
  if (idx < 81920) {
    int p = idx >> 13, ks = (idx >> 12) & 1, hi = (idx >> 11) & 1;
    int n = (idx >> 3) & 255, j = idx & 7;
    int k = p * 32 + ks * 16 + hi * 8 + j;
    Wf1[idx] = f2bf(W1[(size_t)k * 256 + n]);
  } else if (idx < 147456) {
    int i = idx - 81920;
    int p = i >> 13, ks = (i >> 12) & 1, hi = (i >> 11) & 1;
    int n = (i >> 3) & 255, j = i & 7;
    int k = p * 32 + ks * 16 + hi * 8 + j;
    Wf2[i] = f2bf(W2[(size_t)k * 256 + n]);
  } else if (idx < 196608) {
    int i = idx - 147456;
    int p = i >> 12, ks = (i >> 11) & 1, hi = (i >> 10) & 1;
    int n = (i >> 3) & 127, j = i & 7;
    int k = p * 32 + ks * 16 + hi * 8 + j;
    Wfu[i] = f2bf(Wu[(size_t)k * 128 + n]);
  }
}

// ---------------- CSR build (once per launch; indices are launch-invariant) ----------------
__global__ __launch_bounds__(256) void hist_kernel(const int* __restrict__ to_idx,
                                                   int* __restrict__ deg, int E)
{
  for (int e = blockIdx.x * 256 + threadIdx.x; e < E; e += gridDim.x * 256)
    atomicAdd(&deg[to_idx[e]], 1);
}

__global__ __launch_bounds__(1024) void scan_kernel(const int* __restrict__ deg,
                                                    int* __restrict__ offsets,
                                                    int* __restrict__ cursor, int N)
{
  __shared__ int part[1024];
  int t = threadIdx.x;
  int chunk = (N + 1023) / 1024;
  int s0 = t * chunk, s1 = min(s0 + chunk, N);
  int sum = 0;
  for (int i = s0; i < s1; i++) sum += deg[i];
  part[t] = sum;
  __syncthreads();
  for (int off = 1; off < 1024; off <<= 1) {
    int v = 0;
    if (t >= off) v = part[t - off];
    __syncthreads();
    if (t >= off) part[t] += v;
    __syncthreads();
  }
  int base = (t == 0) ? 0 : part[t - 1];
  for (int i = s0; i < s1; i++) {
    offsets[i] = base; cursor[i] = base;
    base += deg[i];
  }
  if (t == 1023) offsets[N] = part[1023];
}

__global__ __launch_bounds__(256) void scatter_csr(const int* __restrict__ to_idx,
                                                   int* __restrict__ cursor,
                                                   int* __restrict__ elist, int E)
{
  for (int e = blockIdx.x * 256 + threadIdx.x; e < E; e += gridDim.x * 256) {
    int pos = atomicAdd(&cursor[to_idx[e]], 1);
    elist[pos] = e;
  }
}

// ---------------- encoders ----------------
__global__ __launch_bounds__(256) void encode_nodes(
    const float* __restrict__ nf, const float* __restrict__ W,
    const float* __restrict__ bias, float* __restrict__ h,
    short* __restrict__ hb, int N)
{
  int t = threadIdx.x;
  int n = blockIdx.x * 2 + (t >> 7);
  int c = t & 127;
  if (n >= N) return;
  float acc = bias[c];
  #pragma unroll
  for (int k = 0; k < NODE_F; k++)
    acc += nf[(size_t)n * NODE_F + k] * W[k * D + c];
  h[(size_t)n * D + c] = acc;
  hb[(size_t)n * D + c] = f2bf(acc);
}

__global__ __launch_bounds__(256) void encode_edges(
    const float* __restrict__ ef, const float* __restrict__ W,
    const float* __restrict__ bias, short* __restrict__ eb, int E)
{
  int t = threadIdx.x;
  int eid = blockIdx.x * 4 + (t >> 6);
  int c = t & 63;
  if (eid >= E) return;
  float acc = bias[c];
  #pragma unroll
  for (int k = 0; k < EDGE_F; k++)
    acc += ef[(size_t)eid * EDGE_F + k] * W[k * EDIM + c];
  eb[(size_t)eid * EDIM + c] = f2bf(acc);
}

// ---------------- message kernel: bf16 MFMA, plain bf16 stores (no atomics) ----------------
__global__ __launch_bounds__(256, 3) void msg_mfma(
    const short* __restrict__ hb, const short* __restrict__ eb,
    const int* __restrict__ from_idx, const int* __restrict__ to_idx,
    const short* __restrict__ Wf1, const float* __restrict__ b1,
    const short* __restrict__ Wf2, const float* __restrict__ b2,
    short* __restrict__ msg_buf, int E)
{
  __shared__ short sA[64 * 328];   // edge_in (K=320) -> hidden (K=256) -> msg (stride 264)
  __shared__ int from_s[64], to_s[64];

  int t = threadIdx.x;
  int ln = t & 63, w = t >> 6;
  int l31 = ln & 31, hi = ln >> 5;
  int cb = (w >> 1) * 128;
  int rowb = (w & 1) * 32;
  int e0 = blockIdx.x * 64;

  if (t < 64) {
    int eid = e0 + t;
    from_s[t] = (eid < E) ? from_idx[eid] : 0;
    to_s[t]   = (eid < E) ? to_idx[eid]   : 0;
  }
  __syncthreads();

  for (int i = t; i < 1024; i += 256) {
    int r = i >> 4, c = i & 15;
    *(short8*)(sA + r * 328 + c * 8) =
        *(const short8*)(hb + (size_t)from_s[r] * 128 + c * 8);
  }
  for (int i = t; i < 1024; i += 256) {
    int r = i >> 4, c = i & 15;
    *(short8*)(sA + r * 328 + 128 + c * 8) =
        *(const short8*)(hb + (size_t)to_s[r] * 128 + c * 8);
  }
  for (int i = t; i < 512; i += 256) {
    int r = i >> 3, c = i & 7;
    short8 v = {0, 0, 0, 0, 0, 0, 0, 0};
    if (e0 + r < E) v = *(const short8*)(eb + (size_t)(e0 + r) * 64 + c * 8);
    *(short8*)(sA + r * 328 + 256 + c * 8) = v;
  }
  __syncthreads();

  const int arow = (rowb + l31) * 328;
  const int bcol = (cb + l31) * 8;

  floatx16 acc[4];
  #pragma unroll
  for (int ct = 0; ct < 4; ct++)
    #pragma unroll
    for (int i = 0; i < 16; i++) acc[ct][i] = 0.f;

  // ---- GEMM1: 20 steps, K=320, barrier-free
  {
    short8 a_cur = *(const short8*)(sA + arow + hi * 8);
    short8 b_cur[4];
    {
      const short* bb = Wf1 + hi * 2048;
      #pragma unroll
      for (int ct = 0; ct < 4; ct++)
        b_cur[ct] = *(const short8*)(bb + bcol + ct * 256);
    }
    #pragma unroll
    for (int step = 0; step < 20; step++) {
      short8 a_nxt;
      short8 b_nxt[4];
      if (step + 1 < 20) {
        a_nxt = *(const short8*)(sA + arow + (step + 1) * 16 + hi * 8);
        const short* bb = Wf1 + (size_t)((step + 1) * 2 + hi) * 2048;
        #pragma unroll
        for (int ct = 0; ct < 4; ct++)
          b_nxt[ct] = *(const short8*)(bb + bcol + ct * 256);
      }
      #pragma unroll
      for (int ct = 0; ct < 4; ct++)
        acc[ct] = __builtin_amdgcn_mfma_f32_32x32x16_bf16(a_cur, b_cur[ct], acc[ct], 0, 0, 0);
      a_cur = a_nxt;
      #pragma unroll
      for (int ct = 0; ct < 4; ct++) b_cur[ct] = b_nxt[ct];
    }
  }

  // relu + bias, hidden (bf16) back into sA
  __syncthreads();
  #pragma unroll
  for (int ct = 0; ct < 4; ct++) {
    int col = cb + ct * 32 + l31;
    float bv = b1[col];
    #pragma unroll
    for (int reg = 0; reg < 16; reg++) {
      int row = rowb + (reg & 3) + 8 * (reg >> 2) + 4 * hi;
      sA[row * 328 + col] = f2bf(fmaxf(acc[ct][reg] + bv, 0.f));
    }
  }
  __syncthreads();

  // ---- GEMM2: 16 steps, K=256, barrier-free
  floatx16 acc2[4];
  #pragma unroll
  for (int ct = 0; ct < 4; ct++)
    #pragma unroll
    for (int i = 0; i < 16; i++) acc2[ct][i] = 0.f;

  {
    short8 a_cur = *(const short8*)(sA + arow + hi * 8);
    short8 b_cur[4];
    {
      const short* bb = Wf2 + hi * 2048;
      #pragma unroll
      for (int ct = 0; ct < 4; ct++)
        b_cur[ct] = *(const short8*)(bb + bcol + ct * 256);
    }
    #pragma unroll
    for (int step = 0; step < 16; step++) {
      short8 a_nxt;
      short8 b_nxt[4];
      if (step + 1 < 16) {
        a_nxt = *(const short8*)(sA + arow + (step + 1) * 16 + hi * 8);
        const short* bb = Wf2 + (size_t)((step + 1) * 2 + hi) * 2048;
        #pragma unroll
        for (int ct = 0; ct < 4; ct++)
          b_nxt[ct] = *(const short8*)(bb + bcol + ct * 256);
      }
      #pragma unroll
      for (int ct = 0; ct < 4; ct++)
        acc2[ct] = __builtin_amdgcn_mfma_f32_32x32x16_bf16(a_cur, b_cur[ct], acc2[ct], 0, 0, 0);
      a_cur = a_nxt;
      #pragma unroll
      for (int ct = 0; ct < 4; ct++) b_cur[ct] = b_nxt[ct];
    }
  }

  // msg (bf16) -> sA (stride 264) -> coalesced global stores
  __syncthreads();   // all waves done reading hidden from sA
  #pragma unroll
  for (int ct = 0; ct < 4; ct++) {
    int col = cb + ct * 32 + l31;
    float bv = b2[col];
    #pragma unroll
    for (int reg = 0; reg < 16; reg++) {
      int row = rowb + (reg & 3) + 8 * (reg >> 2) + 4 * hi;
      sA[row * 264 + col] = f2bf(acc2[ct][reg] + bv);
    }
  }
  __syncthreads();
  for (int i = t; i < 2048; i += 256) {
    int r = i >> 5, c = i & 31;
    if (e0 + r < E)
      *(short8*)(msg_buf + (size_t)(e0 + r) * 256 + c * 8) =
          *(const short8*)(sA + r * 264 + c * 8);
  }
}

// ---------------- CSR aggregation: agg[n] = sum of msg rows of incoming edges ----------------
__global__ __launch_bounds__(256) void agg_csr(
    const short* __restrict__ msg_buf, const int* __restrict__ offsets,
    const int* __restrict__ elist, float* __restrict__ agg, int N)
{
  int t = threadIdx.x;
  int n = blockIdx.x * 2 + (t >> 7);
  if (n >= N) return;
  int c = t & 127;                       // column pair
  int s = offsets[n], e = offsets[n + 1];
  float a0 = 0.f, a1 = 0.f;
  for (int i = s; i < e; i++) {
    int eid = elist[i];
    unsigned u = *(const unsigned*)(msg_buf + (size_t)eid * 256 + c * 2);
    a0 += __uint_as_float(u << 16);
    a1 += __uint_as_float(u & 0xffff0000u);
  }
  agg[(size_t)n * 256 + c * 2]     = a0;
  agg[(size_t)n * 256 + c * 2 + 1] = a1;
}

// ---------------- node update: bf16 MFMA ----------------
__global__ __launch_bounds__(256, 4) void update_mfma(
    float* __restrict__ h, short* __restrict__ hbf, const float* __restrict__ agg,
    const short* __restrict__ Wfu, const float* __restrict__ bu, int N)
{
  __shared__ short sA[32 * 392];

  int t = threadIdx.x;
  int ln = t & 63, w = t >> 6;
  int l31 = ln & 31, hi = ln >> 5;
  int n0 = blockIdx.x * 32;

  for (int i = t; i < 512; i += 256) {
    int r = i >> 4, c = i & 15;
    short8 v = {0, 0, 0, 0, 0, 0, 0, 0};
    if (n0 + r < N) v = *(const short8*)(hbf + (size_t)(n0 + r) * 128 + c * 8);
    *(short8*)(sA + r * 392 + c * 8) = v;
  }
  for (int i = t; i < 2048; i += 256) {
    int r = i >> 6, c4 = i & 63;
    int2 pk = {0, 0};
    if (n0 + r < N) {
      float4 v = *(const float4*)(agg + (size_t)(n0 + r) * 256 + c4 * 4);
      pk.x = (int)(unsigned short)f2bf(v.x) | ((int)(unsigned short)f2bf(v.y) << 16);
      pk.y = (int)(unsigned short)f2bf(v.z) | ((int)(unsigned short)f2bf(v.w) << 16);
    }
    *(int2*)(sA + r * 392 + 128 + c4 * 4) = pk;
  }
  __syncthreads();

  const int arow = l31 * 392;
  const int bcol = (w * 32 + l31) * 8;

  floatx16 acc;
  #pragma unroll
  for (int i = 0; i < 16; i++) acc[i] = 0.f;

  {
    short8 a_cur = *(const short8*)(sA + arow + hi * 8);
    short8 b_cur = *(const short8*)(Wfu + hi * 1024 + bcol);
    #pragma unroll
    for (int step = 0; step < 24; step++) {
      short8 a_nxt, b_nxt;
      if (step + 1 < 24) {
        a_nxt = *(const short8*)(sA + arow + (step + 1) * 16 + hi * 8);
        b_nxt = *(const short8*)(Wfu + (size_t)((step + 1) * 2 + hi) * 1024 + bcol);
      }
      acc = __builtin_amdgcn_mfma_f32_32x32x16_bf16(a_cur, b_cur, acc, 0, 0, 0);
      a_cur = a_nxt; b_cur = b_nxt;
    }
  }

  int col = w * 32 + l31;
  float bv = bu[col];
  #pragma unroll
  for (int reg = 0; reg < 16; reg++) {
    int row = (reg & 3) + 8 * (reg >> 2) + 4 * hi;
    int n = n0 + row;
    if (n < N) {
      float nv = h[(size_t)n * 128 + col] + acc[reg] + bv;
      h[(size_t)n * 128 + col] = nv;
      hbf[(size_t)n * 128 + col] = f2bf(nv);
    }
  }
}

// ---------------- scatter into padded stacks ----------------
__global__ void scatter_kernel(const float* __restrict__ h, const int* __restrict__ pos,
                               float* __restrict__ flat, int N)
{
  int idx = blockIdx.x * 256 + threadIdx.x;
  if (idx >= N * D) return;
  int n = idx >> 7, c = idx & 127;
  flat[(size_t)pos[n] * D + c] = h[idx];
}

// ---------------- attention features (fp32) ----------------
__global__ __launch_bounds__(256) void attfeat_kernel(
    const float* __restrict__ flat,
    const float* __restrict__ Wa1, const float* __restrict__ ba1,
    const float* __restrict__ Wa2, const float* __restrict__ ba2,
    const int* __restrict__ qsizes, const int* __restrict__ csizes,
    float* __restrict__ tf)
{
  __shared__ float sA[MTA * 128];
  __shared__ float sW[KC * 128];
  int t = threadIdx.x, wv = t >> 6, ln = t & 63;
  int r0 = blockIdx.x * MTA;

  for (int i = t * 4; i < MTA * 128; i += 1024)
    *(float4*)(sA + i) = *(const float4*)(flat + (size_t)r0 * 128 + i);

  float2 bb = *(const float2*)(ba1 + ln * 2);
  float acc[8][2];
  #pragma unroll
  for (int j = 0; j < 8; j++) { acc[j][0] = bb.x; acc[j][1] = bb.y; }

  for (int kc = 0; kc < 128; kc += KC) {
    __syncthreads();
    for (int i = t * 4; i < KC * 128; i += 1024) {
      int kk = i >> 7, c = i & 127;
      *(float4*)(sW + i) = *(const float4*)(Wa1 + (size_t)(kc + kk) * 128 + c);
    }
    __syncthreads();
    #pragma unroll
    for (int k4 = 0; k4 < KC; k4 += 4) {
      float4 a[8];
      #pragma unroll
      for (int j = 0; j < 8; j++)
        a[j] = *(const float4*)(sA + (wv * 8 + j) * 128 + kc + k4);
      #pragma unroll
      for (int k2 = 0; k2 < 4; k2++) {
        float2 w = *(const float2*)(sW + (k4 + k2) * 128 + ln * 2);
        #pragma unroll
        for (int j = 0; j < 8; j++) {
          float av = (k2 == 0) ? a[j].x : (k2 == 1) ? a[j].y : (k2 == 2) ? a[j].z : a[j].w;
          acc[j][0] += av * w.x; acc[j][1] += av * w.y;
        }
      }
    }
  }

  __syncthreads();
  #pragma unroll
  for (int j = 0; j < 8; j++) {
    sA[(wv * 8 + j) * 128 + ln * 2 + 0] = fmaxf(acc[j][0], 0.f);
    sA[(wv * 8 + j) * 128 + ln * 2 + 1] = fmaxf(acc[j][1], 0.f);
  }

  float2 bb2 = *(const float2*)(ba2 + ln * 2);
  #pragma unroll
  for (int j = 0; j < 8; j++) { acc[j][0] = bb2.x; acc[j][1] = bb2.y; }

  for (int kc = 0; kc < 128; kc += KC) {
    __syncthreads();
    for (int i = t * 4; i < KC * 128; i += 1024) {
      int kk = i >> 7, c = i & 127;
      *(float4*)(sW + i) = *(const float4*)(Wa2 + (size_t)(kc + kk) * 128 + c);
    }
    __syncthreads();
    #pragma unroll
    for (int k4 = 0; k4 < KC; k4 += 4) {
      float4 a[8];
      #pragma unroll
      for (int j = 0; j < 8; j++)
        a[j] = *(const float4*)(sA + (wv * 8 + j) * 128 + kc + k4);
      #pragma unroll
      for (int k2 = 0; k2 < 4; k2++) {
        float2 w = *(const float2*)(sW + (k4 + k2) * 128 + ln * 2);
        #pragma unroll
        for (int j = 0; j < 8; j++) {
          float av = (k2 == 0) ? a[j].x : (k2 == 1) ? a[j].y : (k2 == 2) ? a[j].z : a[j].w;
          acc[j][0] += av * w.x; acc[j][1] += av * w.y;
        }
      }
    }
  }

  #pragma unroll
  for (int j = 0; j < 8; j++) {
    int row = r0 + wv * 8 + j;
    int part = row >> 14, b = (row >> 6) & 255, pp = row & 63;
    int sz = part ? csizes[b] : qsizes[b];
    float m = (pp < sz) ? 1.f : 0.f;
    tf[(size_t)row * 128 + ln * 2 + 0] = acc[j][0] * m;
    tf[(size_t)row * 128 + ln * 2 + 1] = acc[j][1] * m;
  }
}

// ---------------- per-pair attention score ----------------
__global__ __launch_bounds__(256, 2) void score_kernel(
    const float* __restrict__ tf, const float* __restrict__ flat,
    const int* __restrict__ qsizes, const int* __restrict__ csizes,
    float* __restrict__ out)
{
  __shared__ float SL[64 * 65];
  __shared__ float SP[64 * 65];
  __shared__ float SP2[64 * 65];
  __shared__ float Atk[16 * 68];
  __shared__ float Btk[16 * 68];
  __shared__ float red[8];

  int b = blockIdx.x, t = threadIdx.x;
  const float* tq = tf + (size_t)b * 64 * 128;
  const float* tc = tf + ((size_t)16384 + (size_t)b * 64) * 128;
  const float* sq = flat + (size_t)b * 64 * 128;
  const float* sc = flat + ((size_t)16384 + (size_t)b * 64) * 128;
  int qs = qsizes[b], cs = csizes[b];

  int qg = (t >> 4) << 2;
  int cg = (t & 15) << 2;
  int dg = (t & 15) << 3;

  float lg[4][4] = {};
  for (int kc = 0; kc < 128; kc += 16) {
    __syncthreads();
    for (int i = t; i < 16 * 64; i += 256) {
      int q = i >> 4, kk = i & 15;
      Atk[kk * 68 + q] = tq[q * 128 + kc + kk];
      Btk[kk * 68 + q] = tc[q * 128 + kc + kk];
    }
    __syncthreads();
    #pragma unroll
    for (int kk = 0; kk < 16; kk++) {
      float4 aq = *(const float4*)(Atk + kk * 68 + qg);
      float4 bc = *(const float4*)(Btk + kk * 68 + cg);
      lg[0][0] += aq.x * bc.x; lg[0][1] += aq.x * bc.y; lg[0][2] += aq.x * bc.z; lg[0][3] += aq.x * bc.w;
      lg[1][0] += aq.y * bc.x; lg[1][1] += aq.y * bc.y; lg[1][2] += aq.y * bc.z; lg[1][3] += aq.y * bc.w;
      lg[2][0] += aq.z * bc.x; lg[2][1] += aq.z * bc.y; lg[2][2] += aq.z * bc.z; lg[2][3] += aq.z * bc.w;
      lg[3][0] += aq.w * bc.x; lg[3][1] += aq.w * bc.y; lg[3][2] += aq.w * bc.z; lg[3][3] += aq.w * bc.w;
    }
  }
  #pragma unroll
  for (int j = 0; j < 4; j++)
    #pragma unroll
    for (int i = 0; i < 4; i++) {
      int q = qg + j, c = cg + i;
      SL[q * 65 + c] = (q < qs && c < cs) ? lg[j][i] * 10.0f : -1e9f;
    }
  __syncthreads();

  if (t < 64) {
    int q = t;
    if (q < qs) {
      float m = -1e30f;
      for (int c = 0; c < 64; c++) m = fmaxf(m, SL[q * 65 + c]);
      float s = 0.f;
      for (int c = 0; c < 64; c++) s += __expf(SL[q * 65 + c] - m);
      float inv = 1.0f / s;
      for (int c = 0; c < 64; c++) SP[q * 65 + c] = __expf(SL[q * 65 + c] - m) * inv;
    } else {
      for (int c = 0; c < 64; c++) SP[q * 65 + c] = 0.f;
    }
  } else if (t < 128) {
    int c = t - 64;
    if (c < cs) {
      float m = -1e30f;
      for (int q = 0; q < 64; q++) m = fmaxf(m, SL[q * 65 + c]);
      float s = 0.f;
      for (int q = 0; q < 64; q++) s += __expf(SL[q * 65 + c] - m);
      float inv = 1.0f / s;
      for (int q = 0; q < 64; q++) SP2[q * 65 + c] = __expf(SL[q * 65 + c] - m) * inv;
    } else {
      for (int q = 0; q < 64; q++) SP2[q * 65 + c] = 0.f;
    }
  }
  __syncthreads();

  float al[4][8] = {};
  for (int c = 0; c < 64; c++) {
    float p0 = SP[(qg + 0) * 65 + c];
    float p1 = SP[(qg + 1) * 65 + c];
    float p2 = SP[(qg + 2) * 65 + c];
    float p3 = SP[(qg + 3) * 65 + c];
    float4 s0 = *(const float4*)(sc + c * 128 + dg);
    float4 s1 = *(const float4*)(sc + c * 128 + dg + 4);
    al[0][0] += p0 * s0.x; al[0][1] += p0 * s0.y; al[0][2] += p0 * s0.z; al[0][3] += p0 * s0.w;
    al[0][4] += p0 * s1.x; al[0][5] += p0 * s1.y; al[0][6] += p0 * s1.z; al[0][7] += p0 * s1.w;
    al[1][0] += p1 * s0.x; al[1][1] += p1 * s0.y; al[1][2] += p1 * s0.z; al[1][3] += p1 * s0.w;
    al[1][4] += p1 * s1.x; al[1][5] += p1 * s1.y; al[1][6] += p1 * s1.z; al[1][7] += p1 * s1.w;
    al[2][0] += p2 * s0.x; al[2][1] += p2 * s0.y; al[2][2] += p2 * s0.z; al[2][3] += p2 * s0.w;
    al[2][4] += p2 * s1.x; al[2][5] += p2 * s1.y; al[2][6] += p2 * s1.z; al[2][7] += p2 * s1.w;
    al[3][0] += p3 * s0.x; al[3][1] += p3 * s0.y; al[3][2] += p3 * s0.z; al[3][3] += p3 * s0.w;
    al[3][4] += p3 * s1.x; al[3][5] += p3 * s1.y; al[3][6] += p3 * s1.z; al[3][7] += p3 * s1.w;
  }
  float qpart = 0.f;
  #pragma unroll
  for (int j = 0; j < 4; j++) {
    float4 a0 = *(const float4*)(sq + (qg + j) * 128 + dg);
    float4 a1 = *(const float4*)(sq + (qg + j) * 128 + dg + 4);
    qpart += fmaxf(a0.x - al[j][0], 0.f) + fmaxf(a0.y - al[j][1], 0.f)
           + fmaxf(a0.z - al[j][2], 0.f) + fmaxf(a0.w - al[j][3], 0.f)
           + fmaxf(a1.x - al[j][4], 0.f) + fmaxf(a1.y - al[j][5], 0.f)
           + fmaxf(a1.z - al[j][6], 0.f) + fmaxf(a1.w - al[j][7], 0.f);
  }

  float al2[4][8] = {};
  for (int q = 0; q < 64; q++) {
    float p0 = SP2[q * 65 + qg + 0];
    float p1 = SP2[q * 65 + qg + 1];
    float p2 = SP2[q * 65 + qg + 2];
    float p3 = SP2[q * 65 + qg + 3];
    float4 s0 = *(const float4*)(sq + q * 128 + dg);
    float4 s1 = *(const float4*)(sq + q * 128 + dg + 4);
    al2[0][0] += p0 * s0.x; al2[0][1] += p0 * s0.y; al2[0][2] += p0 * s0.z; al2[0][3] += p0 * s0.w;
    al2[0][4] += p0 * s1.x; al2[0][5] += p0 * s1.y; al2[0][6] += p0 * s1.z; al2[0][7] += p0 * s1.w;
    al2[1][0] += p1 * s0.x; al2[1][1] += p1 * s0.y; al2[1][2] += p1 * s0.z; al2[1][3] += p1 * s0.w;
    al2[1][4] += p1 * s1.x; al2[1][5] += p1 * s1.y; al2[1][6] += p1 * s1.z; al2[1][7] += p1 * s1.w;
    al2[2][0] += p2 * s0.x; al2[2][1] += p2 * s0.y; al2[2][2] += p2 * s0.z; al2[2][3] += p2 * s0.w;
    al2[2][4] += p2 * s1.x; al2[2][5] += p2 * s1.y; al2[2][6] += p2 * s1.z; al2[2][7] += p2 * s1.w;
    al2[3][0] += p3 * s0.x; al2[3][1] += p3 * s0.y; al2[3][2] += p3 * s0.z; al2[3][3] += p3 * s0.w;
    al2[3][4] += p3 * s1.x; al2[3][5] += p3 * s1.y; al2[3][6] += p3 * s1.z; al2[3][7] += p3 * s1.w;
  }
  float cpart = 0.f;
  #pragma unroll
  for (int j = 0; j < 4; j++) {
    float4 b0 = *(const float4*)(sc + (qg + j) * 128 + dg);
    float4 b1 = *(const float4*)(sc + (qg + j) * 128 + dg + 4);
    cpart += fmaxf(b0.x - al2[j][0], 0.f) + fmaxf(b0.y - al2[j][1], 0.f)
           + fmaxf(b0.z - al2[j][2], 0.f) + fmaxf(b0.w - al2[j][3], 0.f)
           + fmaxf(b1.x - al2[j][4], 0.f) + fmaxf(b1.y - al2[j][5], 0.f)
           + fmaxf(b1.z - al2[j][6], 0.f) + fmaxf(b1.w - al2[j][7], 0.f);
  }

  for (int off = 32; off > 0; off >>= 1) {
    qpart += __shfl_down(qpart, off);
    cpart += __shfl_down(cpart, off);
  }
  int wv = t >> 6;
  if ((t & 63) == 0) { red[wv] = qpart; red[wv + 4] = cpart; }
  __syncthreads();
  if (t == 0) {
    float qsum = red[0] + red[1] + red[2] + red[3];
    float csum = red[4] + red[5] + red[6] + red[7];
    out[b] = fminf(-qsum, -csum);
  }
}

// ---------------- launch ----------------
extern "C" void kernel_launch(void* const* d_in, const int* in_sizes, int n_in,
                              void* d_out, int out_size, void* d_ws, size_t ws_size,
                              hipStream_t stream)
{
  const float* nf  = (const float*)d_in[0];
  const float* ef  = (const float*)d_in[1];
  const int* from_idx = (const int*)d_in[2];
  const int* to_idx   = (const int*)d_in[3];
  const int* pos      = (const int*)d_in[4];
  const int* qsz      = (const int*)d_in[5];
  const int* csz      = (const int*)d_in[6];
  const float* W_node = (const float*)d_in[7];
  const float* b_node = (const float*)d_in[8];
  const float* W_edge = (const float*)d_in[9];
  const float* b_edge = (const float*)d_in[10];
  const float* W1 = (const float*)d_in[11];
  const float* b1 = (const float*)d_in[12];
  const float* W2 = (const float*)d_in[13];
  const float* b2 = (const float*)d_in[14];
  const float* Wu = (const float*)d_in[15];
  const float* bu = (const float*)d_in[16];
  const float* Wa1 = (const float*)d_in[17];
  const float* ba1 = (const float*)d_in[18];
  const float* Wa2 = (const float*)d_in[19];
  const float* ba2 = (const float*)d_in[20];
  float* out = (float*)d_out;

  int N = in_sizes[0] / NODE_F;
  int E = in_sizes[1] / EDGE_F;

  float* h    = (float*)d_ws;                              // N*128 f32
  float* agg  = h + (size_t)N * D;                         // N*256 f32
  short* hb   = (short*)(agg + (size_t)N * 256);           // N*128 bf16
  short* eb   = hb + (size_t)N * D;                        // E*64 bf16
  short* Wf1  = eb + (size_t)E * EDIM;
  short* Wf2  = Wf1 + 81920;
  short* Wfu  = Wf2 + 65536;
  int*   deg     = (int*)(Wfu + 49152);                    // N
  int*   offsets = deg + N;                                // N+1
  int*   cursor  = offsets + N + 1;                        // N
  int*   elist   = cursor + N;                             // E
  // msg_buf (E*256 bf16 = ~101 MB) aliases flat/tfb (only live after prop loop)
  short* msg_buf = (short*)(elist + E + ((E + N) & 1));    // keep 4B->8B alignment slack
  float* flat = (float*)msg_buf;                           // 2*B*MAX*D f32
  float* tfb  = flat + (size_t)2 * B_PAIRS * MAXN * D;

  // CSR build (indices are launch-invariant; rebuilt every call, no static state)
  hipMemsetAsync(deg, 0, (size_t)N * sizeof(int), stream);
  hist_kernel<<<256, 256, 0, stream>>>(to_idx, deg, E);
  scan_kernel<<<1, 1024, 0, stream>>>(deg, offsets, cursor, N);
  scatter_csr<<<256, 256, 0, stream>>>(to_idx, cursor, elist, E);

  prep_w<<<768, 256, 0, stream>>>(W1, W2, Wu, Wf1, Wf2, Wfu);
  encode_nodes<<<(N + 1) / 2, 256, 0, stream>>>(nf, W_node, b_node, h, hb, N);
  encode_edges<<<(E + 3) / 4, 256, 0, stream>>>(ef, W_edge, b_edge, eb, E);

  for (int s = 0; s < PROP_STEPS; s++) {
    msg_mfma<<<(E + 63) / 64, 256, 0, stream>>>(hb, eb, from_idx, to_idx,
                                                Wf1, b1, Wf2, b2, msg_buf, E);
    agg_csr<<<(N + 1) / 2, 256, 0, stream>>>(msg_buf, offsets, elist, agg, N);
    update_mfma<<<(N + 31) / 32, 256, 0, stream>>>(h, hb, agg, Wfu, bu, N);
  }

  // flat/tfb alias msg_buf — safe now that the prop loop is done
  hipMemsetAsync(flat, 0, (size_t)2 * B_PAIRS * MAXN * D * sizeof(float), stream);
  scatter_kernel<<<(N * D + 255) / 256, 256, 0, stream>>>(h, pos, flat, N);
  attfeat_kernel<<<(2 * B_PAIRS * MAXN) / MTA, 256, 0, stream>>>(flat, Wa1, ba1, Wa2, ba2,
                                                                 qsz, csz, tfb);
  score_kernel<<<B_PAIRS, 256, 0, stream>>>(tfb, flat, qsz, csz, out);
}

// Round 7
// 713.668 us; speedup vs baseline: 1.5033x; 1.0605x over previous
//
#include <hip/hip_runtime.h>

#define D 128
#define EDIM 64
#define NODE_F 32
#define EDGE_F 16
#define B_PAIRS 256
#define MAXN 64
#define PROP_STEPS 3

#define MTA 32
#define KC 16

typedef __attribute__((ext_vector_type(8))) short short8;
typedef __attribute__((ext_vector_type(16))) float floatx16;

__device__ __forceinline__ short f2bf(float x) {
  unsigned u = __float_as_uint(x);
  u = (u + 0x7fff + ((u >> 16) & 1)) >> 16;   // RNE
  return (short)u;
}

// ---------------- weight prep: fragment-order layouts ----------------
__global__ __launch_bounds__(256) void prep_w(
    const float* __restrict__ W1, const float* __restrict__ W2,
    const float* __restrict__ Wu,
    short* __restrict__ Wf1, short* __restrict__ Wf2, short* __restrict__ Wfu)
{
  int idx = blockIdx.x * 256 + threadIdx.x;
  if (idx < 81920) {
    int p = idx >> 13, ks = (idx >> 12) & 1, hi = (idx >> 11) & 1;
    int n = (idx >> 3) & 255, j = idx & 7;
    int k = p * 32 + ks * 16 + hi * 8 + j;
    Wf1[idx] = f2bf(W1[(size_t)k * 256 + n]);
  } else if (idx < 147456) {
    int i = idx - 81920;
    int p = i >> 13, ks = (i >> 12) & 1, hi = (i >> 11) & 1;
    int n = (i >> 3) & 255, j = i & 7;
    int k = p * 32 + ks * 16 + hi * 8 + j;
    Wf2[i] = f2bf(W2[(size_t)k * 256 + n]);
  } else if (idx < 196608) {
    int i = idx - 147456;
    int p = i >> 12, ks = (i >> 11) & 1, hi = (i >> 10) & 1;
    int n = (i >> 3) & 127, j = i & 7;
    int k = p * 32 + ks * 16 + hi * 8 + j;
    Wfu[i] = f2bf(Wu[(size_t)k * 128 + n]);
  }
}

// ---------------- CSR build (indices are launch-invariant) ----------------
__global__ __launch_bounds__(256) void hist_kernel(const int* __restrict__ to_idx,
                                                   int* __restrict__ deg, int E)
{
  for (int e = blockIdx.x * 256 + threadIdx.x; e < E; e += gridDim.x * 256)
    atomicAdd(&deg[to_idx[e]], 1);
}

__global__ __launch_bounds__(1024) void scan_kernel(const int* __restrict__ deg,
                                                    int* __restrict__ offsets,
                                                    int* __restrict__ cursor, int N)
{
  __shared__ int part[1024];
  int t = threadIdx.x;
  int chunk = (N + 1023) / 1024;
  int s0 = t * chunk, s1 = min(s0 + chunk, N);
  int sum = 0;
  for (int i = s0; i < s1; i++) sum += deg[i];
  part[t] = sum;
  __syncthreads();
  for (int off = 1; off < 1024; off <<= 1) {
    int v = 0;
    if (t >= off) v = part[t - off];
    __syncthreads();
    if (t >= off) part[t] += v;
    __syncthreads();
  }
  int base = (t == 0) ? 0 : part[t - 1];
  for (int i = s0; i < s1; i++) {
    offsets[i] = base; cursor[i] = base;
    base += deg[i];
  }
  if (t == 1023) offsets[N] = part[1023];
}

__global__ __launch_bounds__(256) void scatter_csr(const int* __restrict__ to_idx,
                                                   int* __restrict__ cursor,
                                                   int* __restrict__ elist, int E)
{
  for (int e = blockIdx.x * 256 + threadIdx.x; e < E; e += gridDim.x * 256) {
    int pos = atomicAdd(&cursor[to_idx[e]], 1);
    elist[pos] = e;
  }
}

// ---------------- encoders ----------------
__global__ __launch_bounds__(256) void encode_nodes(
    const float* __restrict__ nf, const float* __restrict__ W,
    const float* __restrict__ bias, float* __restrict__ h,
    short* __restrict__ hb, int N)
{
  int t = threadIdx.x;
  int n = blockIdx.x * 2 + (t >> 7);
  int c = t & 127;
  if (n >= N) return;
  float acc = bias[c];
  #pragma unroll
  for (int k = 0; k < NODE_F; k++)
    acc += nf[(size_t)n * NODE_F + k] * W[k * D + c];
  h[(size_t)n * D + c] = acc;
  hb[(size_t)n * D + c] = f2bf(acc);
}

__global__ __launch_bounds__(256) void encode_edges(
    const float* __restrict__ ef, const float* __restrict__ W,
    const float* __restrict__ bias, short* __restrict__ eb, int E)
{
  int t = threadIdx.x;
  int eid = blockIdx.x * 4 + (t >> 6);
  int c = t & 63;
  if (eid >= E) return;
  float acc = bias[c];
  #pragma unroll
  for (int k = 0; k < EDGE_F; k++)
    acc += ef[(size_t)eid * EDGE_F + k] * W[k * EDIM + c];
  eb[(size_t)eid * EDIM + c] = f2bf(acc);
}

// ---------------- message kernel: CSR-ordered edges, 3-deep B pipeline ----------------
// Block processes elist[e0..e0+64); writes msg_buf at CSR position e0+r (contiguous
// per-node ranges). GEMM K-loops are barrier-free with ring-3 global B prefetch.
__global__ __launch_bounds__(256, 3) void msg_mfma(
    const short* __restrict__ hb, const short* __restrict__ eb,
    const int* __restrict__ from_idx, const int* __restrict__ to_idx,
    const int* __restrict__ elist,
    const short* __restrict__ Wf1, const float* __restrict__ b1,
    const short* __restrict__ Wf2, const float* __restrict__ b2,
    short* __restrict__ msg_buf, int E)
{
  __shared__ short sA[64 * 328];   // edge_in (K=320) -> hidden (K=256) -> msg (stride 264)
  __shared__ int from_s[64], eid_s[64];

  int t = threadIdx.x;
  int ln = t & 63, w = t >> 6;
  int l31 = ln & 31, hi = ln >> 5;
  int cb = (w >> 1) * 128;
  int rowb = (w & 1) * 32;
  int e0 = blockIdx.x * 64;

  if (t < 64) {
    int idx = e0 + t;
    int eid = (idx < E) ? elist[idx] : 0;
    eid_s[t] = eid;
    from_s[t] = from_idx[eid];
  }
  __syncthreads();

  for (int i = t; i < 1024; i += 256) {
    int r = i >> 4, c = i & 15;
    *(short8*)(sA + r * 328 + c * 8) =
        *(const short8*)(hb + (size_t)from_s[r] * 128 + c * 8);
  }
  for (int i = t; i < 1024; i += 256) {
    int r = i >> 4, c = i & 15;
    *(short8*)(sA + r * 328 + 128 + c * 8) =
        *(const short8*)(hb + (size_t)to_idx[eid_s[r]] * 128 + c * 8);
  }
  for (int i = t; i < 512; i += 256) {
    int r = i >> 3, c = i & 7;
    *(short8*)(sA + r * 328 + 256 + c * 8) =
        *(const short8*)(eb + (size_t)eid_s[r] * 64 + c * 8);
  }
  __syncthreads();

  const int arow = (rowb + l31) * 328;
  const int bcol = (cb + l31) * 8;

  floatx16 acc[4];
  #pragma unroll
  for (int ct = 0; ct < 4; ct++)
    #pragma unroll
    for (int i = 0; i < 16; i++) acc[ct][i] = 0.f;

  // ---- GEMM1: 20 steps, K=320, ring-3 B prefetch, A double-buffered
  {
    short8 bbuf[3][4];
    short8 abuf[2];
    #pragma unroll
    for (int s = 0; s < 3; s++) {
      const short* bb = Wf1 + (size_t)(s * 2 + hi) * 2048 + bcol;
      #pragma unroll
      for (int ct = 0; ct < 4; ct++) bbuf[s][ct] = *(const short8*)(bb + ct * 256);
    }
    abuf[0] = *(const short8*)(sA + arow + hi * 8);
    #pragma unroll
    for (int step = 0; step < 20; step++) {
      if (step + 1 < 20)
        abuf[(step + 1) & 1] = *(const short8*)(sA + arow + (step + 1) * 16 + hi * 8);
      #pragma unroll
      for (int ct = 0; ct < 4; ct++)
        acc[ct] = __builtin_amdgcn_mfma_f32_32x32x16_bf16(abuf[step & 1], bbuf[step % 3][ct], acc[ct], 0, 0, 0);
      if (step + 3 < 20) {   // refill the slot just consumed (WAR after MFMA issue)
        const short* bb = Wf1 + (size_t)((step + 3) * 2 + hi) * 2048 + bcol;
        #pragma unroll
        for (int ct = 0; ct < 4; ct++) bbuf[step % 3][ct] = *(const short8*)(bb + ct * 256);
      }
    }
  }

  // issue GEMM2 B prologue early — the barrier's vmcnt drain doubles as its wait
  short8 b2buf[3][4];
  #pragma unroll
  for (int s = 0; s < 3; s++) {
    const short* bb = Wf2 + (size_t)(s * 2 + hi) * 2048 + bcol;
    #pragma unroll
    for (int ct = 0; ct < 4; ct++) b2buf[s][ct] = *(const short8*)(bb + ct * 256);
  }

  // relu + bias, hidden (bf16) back into sA
  __syncthreads();
  #pragma unroll
  for (int ct = 0; ct < 4; ct++) {
    int col = cb + ct * 32 + l31;
    float bv = b1[col];
    #pragma unroll
    for (int reg = 0; reg < 16; reg++) {
      int row = rowb + (reg & 3) + 8 * (reg >> 2) + 4 * hi;
      sA[row * 328 + col] = f2bf(fmaxf(acc[ct][reg] + bv, 0.f));
    }
  }
  __syncthreads();

  // ---- GEMM2: 16 steps, K=256
  floatx16 acc2[4];
  #pragma unroll
  for (int ct = 0; ct < 4; ct++)
    #pragma unroll
    for (int i = 0; i < 16; i++) acc2[ct][i] = 0.f;

  {
    short8 abuf[2];
    abuf[0] = *(const short8*)(sA + arow + hi * 8);
    #pragma unroll
    for (int step = 0; step < 16; step++) {
      if (step + 1 < 16)
        abuf[(step + 1) & 1] = *(const short8*)(sA + arow + (step + 1) * 16 + hi * 8);
      #pragma unroll
      for (int ct = 0; ct < 4; ct++)
        acc2[ct] = __builtin_amdgcn_mfma_f32_32x32x16_bf16(abuf[step & 1], b2buf[step % 3][ct], acc2[ct], 0, 0, 0);
      if (step + 3 < 16) {
        const short* bb = Wf2 + (size_t)((step + 3) * 2 + hi) * 2048 + bcol;
        #pragma unroll
        for (int ct = 0; ct < 4; ct++) b2buf[step % 3][ct] = *(const short8*)(bb + ct * 256);
      }
    }
  }

  // msg (bf16) -> sA (stride 264) -> coalesced stores at CSR position
  __syncthreads();
  #pragma unroll
  for (int ct = 0; ct < 4; ct++) {
    int col = cb + ct * 32 + l31;
    float bv = b2[col];
    #pragma unroll
    for (int reg = 0; reg < 16; reg++) {
      int row = rowb + (reg & 3) + 8 * (reg >> 2) + 4 * hi;
      sA[row * 264 + col] = f2bf(acc2[ct][reg] + bv);
    }
  }
  __syncthreads();
  for (int i = t; i < 2048; i += 256) {
    int r = i >> 5, c = i & 31;
    if (e0 + r < E)
      *(short8*)(msg_buf + (size_t)(e0 + r) * 256 + c * 8) =
          *(const short8*)(sA + r * 264 + c * 8);
  }
}

// ---------------- CSR aggregation: contiguous streaming sum ----------------
__global__ __launch_bounds__(256) void agg_csr(
    const short* __restrict__ msg_buf, const int* __restrict__ offsets,
    float* __restrict__ agg, int N)
{
  int t = threadIdx.x;
  int n = blockIdx.x * 2 + (t >> 7);
  if (n >= N) return;
  int c = t & 127;
  int s = offsets[n], e = offsets[n + 1];
  float a0 = 0.f, a1 = 0.f;
  for (int i = s; i < e; i++) {
    unsigned u = *(const unsigned*)(msg_buf + (size_t)i * 256 + c * 2);
    a0 += __uint_as_float(u << 16);
    a1 += __uint_as_float(u & 0xffff0000u);
  }
  agg[(size_t)n * 256 + c * 2]     = a0;
  agg[(size_t)n * 256 + c * 2 + 1] = a1;
}

// ---------------- node update: bf16 MFMA, ring-3 B prefetch ----------------
__global__ __launch_bounds__(256, 4) void update_mfma(
    float* __restrict__ h, short* __restrict__ hbf, const float* __restrict__ agg,
    const short* __restrict__ Wfu, const float* __restrict__ bu, int N)
{
  __shared__ short sA[32 * 392];

  int t = threadIdx.x;
  int ln = t & 63, w = t >> 6;
  int l31 = ln & 31, hi = ln >> 5;
  int n0 = blockIdx.x * 32;

  for (int i = t; i < 512; i += 256) {
    int r = i >> 4, c = i & 15;
    short8 v = {0, 0, 0, 0, 0, 0, 0, 0};
    if (n0 + r < N) v = *(const short8*)(hbf + (size_t)(n0 + r) * 128 + c * 8);
    *(short8*)(sA + r * 392 + c * 8) = v;
  }
  for (int i = t; i < 2048; i += 256) {
    int r = i >> 6, c4 = i & 63;
    int2 pk = {0, 0};
    if (n0 + r < N) {
      float4 v = *(const float4*)(agg + (size_t)(n0 + r) * 256 + c4 * 4);
      pk.x = (int)(unsigned short)f2bf(v.x) | ((int)(unsigned short)f2bf(v.y) << 16);
      pk.y = (int)(unsigned short)f2bf(v.z) | ((int)(unsigned short)f2bf(v.w) << 16);
    }
    *(int2*)(sA + r * 392 + 128 + c4 * 4) = pk;
  }
  __syncthreads();

  const int arow = l31 * 392;
  const int bcol = (w * 32 + l31) * 8;

  floatx16 acc;
  #pragma unroll
  for (int i = 0; i < 16; i++) acc[i] = 0.f;

  {
    short8 bbuf[3];
    #pragma unroll
    for (int s = 0; s < 3; s++)
      bbuf[s] = *(const short8*)(Wfu + (size_t)(s * 2 + hi) * 1024 + bcol);
    short8 abuf[2];
    abuf[0] = *(const short8*)(sA + arow + hi * 8);
    #pragma unroll
    for (int step = 0; step < 24; step++) {
      if (step + 1 < 24)
        abuf[(step + 1) & 1] = *(const short8*)(sA + arow + (step + 1) * 16 + hi * 8);
      acc = __builtin_amdgcn_mfma_f32_32x32x16_bf16(abuf[step & 1], bbuf[step % 3], acc, 0, 0, 0);
      if (step + 3 < 24)
        bbuf[step % 3] = *(const short8*)(Wfu + (size_t)((step + 3) * 2 + hi) * 1024 + bcol);
    }
  }

  int col = w * 32 + l31;
  float bv = bu[col];
  #pragma unroll
  for (int reg = 0; reg < 16; reg++) {
    int row = (reg & 3) + 8 * (reg >> 2) + 4 * hi;
    int n = n0 + row;
    if (n < N) {
      float nv = h[(size_t)n * 128 + col] + acc[reg] + bv;
      h[(size_t)n * 128 + col] = nv;
      hbf[(size_t)n * 128 + col] = f2bf(nv);
    }
  }
}

// ---------------- scatter into padded stacks ----------------
__global__ void scatter_kernel(const float* __restrict__ h, const int* __restrict__ pos,
                               float* __restrict__ flat, int N)
{
  int idx = blockIdx.x * 256 + threadIdx.x;
  if (idx >= N * D) return;
  int n = idx >> 7, c = idx & 127;
  flat[(size_t)pos[n] * D + c] = h[idx];
}

// ---------------- attention features (fp32) ----------------
__global__ __launch_bounds__(256) void attfeat_kernel(
    const float* __restrict__ flat,
    const float* __restrict__ Wa1, const float* __restrict__ ba1,
    const float* __restrict__ Wa2, const float* __restrict__ ba2,
    const int* __restrict__ qsizes, const int* __restrict__ csizes,
    float* __restrict__ tf)
{
  __shared__ float sA[MTA * 128];
  __shared__ float sW[KC * 128];
  int t = threadIdx.x, wv = t >> 6, ln = t & 63;
  int r0 = blockIdx.x * MTA;

  for (int i = t * 4; i < MTA * 128; i += 1024)
    *(float4*)(sA + i) = *(const float4*)(flat + (size_t)r0 * 128 + i);

  float2 bb = *(const float2*)(ba1 + ln * 2);
  float acc[8][2];
  #pragma unroll
  for (int j = 0; j < 8; j++) { acc[j][0] = bb.x; acc[j][1] = bb.y; }

  for (int kc = 0; kc < 128; kc += KC) {
    __syncthreads();
    for (int i = t * 4; i < KC * 128; i += 1024) {
      int kk = i >> 7, c = i & 127;
      *(float4*)(sW + i) = *(const float4*)(Wa1 + (size_t)(kc + kk) * 128 + c);
    }
    __syncthreads();
    #pragma unroll
    for (int k4 = 0; k4 < KC; k4 += 4) {
      float4 a[8];
      #pragma unroll
      for (int j = 0; j < 8; j++)
        a[j] = *(const float4*)(sA + (wv * 8 + j) * 128 + kc + k4);
      #pragma unroll
      for (int k2 = 0; k2 < 4; k2++) {
        float2 w = *(const float2*)(sW + (k4 + k2) * 128 + ln * 2);
        #pragma unroll
        for (int j = 0; j < 8; j++) {
          float av = (k2 == 0) ? a[j].x : (k2 == 1) ? a[j].y : (k2 == 2) ? a[j].z : a[j].w;
          acc[j][0] += av * w.x; acc[j][1] += av * w.y;
        }
      }
    }
  }

  __syncthreads();
  #pragma unroll
  for (int j = 0; j < 8; j++) {
    sA[(wv * 8 + j) * 128 + ln * 2 + 0] = fmaxf(acc[j][0], 0.f);
    sA[(wv * 8 + j) * 128 + ln * 2 + 1] = fmaxf(acc[j][1], 0.f);
  }

  float2 bb2 = *(const float2*)(ba2 + ln * 2);
  #pragma unroll
  for (int j = 0; j < 8; j++) { acc[j][0] = bb2.x; acc[j][1] = bb2.y; }

  for (int kc = 0; kc < 128; kc += KC) {
    __syncthreads();
    for (int i = t * 4; i < KC * 128; i += 1024) {
      int kk = i >> 7, c = i & 127;
      *(float4*)(sW + i) = *(const float4*)(Wa2 + (size_t)(kc + kk) * 128 + c);
    }
    __syncthreads();
    #pragma unroll
    for (int k4 = 0; k4 < KC; k4 += 4) {
      float4 a[8];
      #pragma unroll
      for (int j = 0; j < 8; j++)
        a[j] = *(const float4*)(sA + (wv * 8 + j) * 128 + kc + k4);
      #pragma unroll
      for (int k2 = 0; k2 < 4; k2++) {
        float2 w = *(const float2*)(sW + (k4 + k2) * 128 + ln * 2);
        #pragma unroll
        for (int j = 0; j < 8; j++) {
          float av = (k2 == 0) ? a[j].x : (k2 == 1) ? a[j].y : (k2 == 2) ? a[j].z : a[j].w;
          acc[j][0] += av * w.x; acc[j][1] += av * w.y;
        }
      }
    }
  }

  #pragma unroll
  for (int j = 0; j < 8; j++) {
    int row = r0 + wv * 8 + j;
    int part = row >> 14, b = (row >> 6) & 255, pp = row & 63;
    int sz = part ? csizes[b] : qsizes[b];
    float m = (pp < sz) ? 1.f : 0.f;
    tf[(size_t)row * 128 + ln * 2 + 0] = acc[j][0] * m;
    tf[(size_t)row * 128 + ln * 2 + 1] = acc[j][1] * m;
  }
}

// ---------------- per-pair attention score ----------------
__global__ __launch_bounds__(256, 2) void score_kernel(
    const float* __restrict__ tf, const float* __restrict__ flat,
    const int* __restrict__ qsizes, const int* __restrict__ csizes,
    float* __restrict__ out)
{
  __shared__ float SL[64 * 65];
  __shared__ float SP[64 * 65];
  __shared__ float SP2[64 * 65];
  __shared__ float Atk[16 * 68];
  __shared__ float Btk[16 * 68];
  __shared__ float red[8];

  int b = blockIdx.x, t = threadIdx.x;
  const float* tq = tf + (size_t)b * 64 * 128;
  const float* tc = tf + ((size_t)16384 + (size_t)b * 64) * 128;
  const float* sq = flat + (size_t)b * 64 * 128;
  const float* sc = flat + ((size_t)16384 + (size_t)b * 64) * 128;
  int qs = qsizes[b], cs = csizes[b];

  int qg = (t >> 4) << 2;
  int cg = (t & 15) << 2;
  int dg = (t & 15) << 3;

  float lg[4][4] = {};
  for (int kc = 0; kc < 128; kc += 16) {
    __syncthreads();
    for (int i = t; i < 16 * 64; i += 256) {
      int q = i >> 4, kk = i & 15;
      Atk[kk * 68 + q] = tq[q * 128 + kc + kk];
      Btk[kk * 68 + q] = tc[q * 128 + kc + kk];
    }
    __syncthreads();
    #pragma unroll
    for (int kk = 0; kk < 16; kk++) {
      float4 aq = *(const float4*)(Atk + kk * 68 + qg);
      float4 bc = *(const float4*)(Btk + kk * 68 + cg);
      lg[0][0] += aq.x * bc.x; lg[0][1] += aq.x * bc.y; lg[0][2] += aq.x * bc.z; lg[0][3] += aq.x * bc.w;
      lg[1][0] += aq.y * bc.x; lg[1][1] += aq.y * bc.y; lg[1][2] += aq.y * bc.z; lg[1][3] += aq.y * bc.w;
      lg[2][0] += aq.z * bc.x; lg[2][1] += aq.z * bc.y; lg[2][2] += aq.z * bc.z; lg[2][3] += aq.z * bc.w;
      lg[3][0] += aq.w * bc.x; lg[3][1] += aq.w * bc.y; lg[3][2] += aq.w * bc.z; lg[3][3] += aq.w * bc.w;
    }
  }
  #pragma unroll
  for (int j = 0; j < 4; j++)
    #pragma unroll
    for (int i = 0; i < 4; i++) {
      int q = qg + j, c = cg + i;
      SL[q * 65 + c] = (q < qs && c < cs) ? lg[j][i] * 10.0f : -1e9f;
    }
  __syncthreads();

  if (t < 64) {
    int q = t;
    if (q < qs) {
      float m = -1e30f;
      for (int c = 0; c < 64; c++) m = fmaxf(m, SL[q * 65 + c]);
      float s = 0.f;
      for (int c = 0; c < 64; c++) s += __expf(SL[q * 65 + c] - m);
      float inv = 1.0f / s;
      for (int c = 0; c < 64; c++) SP[q * 65 + c] = __expf(SL[q * 65 + c] - m) * inv;
    } else {
      for (int c = 0; c < 64; c++) SP[q * 65 + c] = 0.f;
    }
  } else if (t < 128) {
    int c = t - 64;
    if (c < cs) {
      float m = -1e30f;
      for (int q = 0; q < 64; q++) m = fmaxf(m, SL[q * 65 + c]);
      float s = 0.f;
      for (int q = 0; q < 64; q++) s += __expf(SL[q * 65 + c] - m);
      float inv = 1.0f / s;
      for (int q = 0; q < 64; q++) SP2[q * 65 + c] = __expf(SL[q * 65 + c] - m) * inv;
    } else {
      for (int q = 0; q < 64; q++) SP2[q * 65 + c] = 0.f;
    }
  }
  __syncthreads();

  float al[4][8] = {};
  for (int c = 0; c < 64; c++) {
    float p0 = SP[(qg + 0) * 65 + c];
    float p1 = SP[(qg + 1) * 65 + c];
    float p2 = SP[(qg + 2) * 65 + c];
    float p3 = SP[(qg + 3) * 65 + c];
    float4 s0 = *(const float4*)(sc + c * 128 + dg);
    float4 s1 = *(const float4*)(sc + c * 128 + dg + 4);
    al[0][0] += p0 * s0.x; al[0][1] += p0 * s0.y; al[0][2] += p0 * s0.z; al[0][3] += p0 * s0.w;
    al[0][4] += p0 * s1.x; al[0][5] += p0 * s1.y; al[0][6] += p0 * s1.z; al[0][7] += p0 * s1.w;
    al[1][0] += p1 * s0.x; al[1][1] += p1 * s0.y; al[1][2] += p1 * s0.z; al[1][3] += p1 * s0.w;
    al[1][4] += p1 * s1.x; al[1][5] += p1 * s1.y; al[1][6] += p1 * s1.z; al[1][7] += p1 * s1.w;
    al[2][0] += p2 * s0.x; al[2][1] += p2 * s0.y; al[2][2] += p2 * s0.z; al[2][3] += p2 * s0.w;
    al[2][4] += p2 * s1.x; al[2][5] += p2 * s1.y; al[2][6] += p2 * s1.z; al[2][7] += p2 * s1.w;
    al[3][0] += p3 * s0.x; al[3][1] += p3 * s0.y; al[3][2] += p3 * s0.z; al[3][3] += p3 * s0.w;
    al[3][4] += p3 * s1.x; al[3][5] += p3 * s1.y; al[3][6] += p3 * s1.z; al[3][7] += p3 * s1.w;
  }
  float qpart = 0.f;
  #pragma unroll
  for (int j = 0; j < 4; j++) {
    float4 a0 = *(const float4*)(sq + (qg + j) * 128 + dg);
    float4 a1 = *(const float4*)(sq + (qg + j) * 128 + dg + 4);
    qpart += fmaxf(a0.x - al[j][0], 0.f) + fmaxf(a0.y - al[j][1], 0.f)
           + fmaxf(a0.z - al[j][2], 0.f) + fmaxf(a0.w - al[j][3], 0.f)
           + fmaxf(a1.x - al[j][4], 0.f) + fmaxf(a1.y - al[j][5], 0.f)
           + fmaxf(a1.z - al[j][6], 0.f) + fmaxf(a1.w - al[j][7], 0.f);
  }

  float al2[4][8] = {};
  for (int q = 0; q < 64; q++) {
    float p0 = SP2[q * 65 + qg + 0];
    float p1 = SP2[q * 65 + qg + 1];
    float p2 = SP2[q * 65 + qg + 2];
    float p3 = SP2[q * 65 + qg + 3];
    float4 s0 = *(const float4*)(sq + q * 128 + dg);
    float4 s1 = *(const float4*)(sq + q * 128 + dg + 4);
    al2[0][0] += p0 * s0.x; al2[0][1] += p0 * s0.y; al2[0][2] += p0 * s0.z; al2[0][3] += p0 * s0.w;
    al2[0][4] += p0 * s1.x; al2[0][5] += p0 * s1.y; al2[0][6] += p0 * s1.z; al2[0][7] += p0 * s1.w;
    al2[1][0] += p1 * s0.x; al2[1][1] += p1 * s0.y; al2[1][2] += p1 * s0.z; al2[1][3] += p1 * s0.w;
    al2[1][4] += p1 * s1.x; al2[1][5] += p1 * s1.y; al2[1][6] += p1 * s1.z; al2[1][7] += p1 * s1.w;
    al2[2][0] += p2 * s0.x; al2[2][1] += p2 * s0.y; al2[2][2] += p2 * s0.z; al2[2][3] += p2 * s0.w;
    al2[2][4] += p2 * s1.x; al2[2][5] += p2 * s1.y; al2[2][6] += p2 * s1.z; al2[2][7] += p2 * s1.w;
    al2[3][0] += p3 * s0.x; al2[3][1] += p3 * s0.y; al2[3][2] += p3 * s0.z; al2[3][3] += p3 * s0.w;
    al2[3][4] += p3 * s1.x; al2[3][5] += p3 * s1.y; al2[3][6] += p3 * s1.z; al2[3][7] += p3 * s1.w;
  }
  float cpart = 0.f;
  #pragma unroll
  for (int j = 0; j < 4; j++) {
    float4 b0 = *(const float4*)(sc + (qg + j) * 128 + dg);
    float4 b1 = *(const float4*)(sc + (qg + j) * 128 + dg + 4);
    cpart += fmaxf(b0.x - al2[j][0], 0.f) + fmaxf(b0.y - al2[j][1], 0.f)
           + fmaxf(b0.z - al2[j][2], 0.f) + fmaxf(b0.w - al2[j][3], 0.f)
           + fmaxf(b1.x - al2[j][4], 0.f) + fmaxf(b1.y - al2[j][5], 0.f)
           + fmaxf(b1.z - al2[j][6], 0.f) + fmaxf(b1.w - al2[j][7], 0.f);
  }

  for (int off = 32; off > 0; off >>= 1) {
    qpart += __shfl_down(qpart, off);
    cpart += __shfl_down(cpart, off);
  }
  int wv = t >> 6;
  if ((t & 63) == 0) { red[wv] = qpart; red[wv + 4] = cpart; }
  __syncthreads();
  if (t == 0) {
    float qsum = red[0] + red[1] + red[2] + red[3];
    float csum = red[4] + red[5] + red[6] + red[7];
    out[b] = fminf(-qsum, -csum);
  }
}

// ---------------- launch ----------------
extern "C" void kernel_launch(void* const* d_in, const int* in_sizes, int n_in,
                              void* d_out, int out_size, void* d_ws, size_t ws_size,
                              hipStream_t stream)
{
  const float* nf  = (const float*)d_in[0];
  const float* ef  = (const float*)d_in[1];
  const int* from_idx = (const int*)d_in[2];
  const int* to_idx   = (const int*)d_in[3];
  const int* pos      = (const int*)d_in[4];
  const int* qsz      = (const int*)d_in[5];
  const int* csz      = (const int*)d_in[6];
  const float* W_node = (const float*)d_in[7];
  const float* b_node = (const float*)d_in[8];
  const float* W_edge = (const float*)d_in[9];
  const float* b_edge = (const float*)d_in[10];
  const float* W1 = (const float*)d_in[11];
  const float* b1 = (const float*)d_in[12];
  const float* W2 = (const float*)d_in[13];
  const float* b2 = (const float*)d_in[14];
  const float* Wu = (const float*)d_in[15];
  const float* bu = (const float*)d_in[16];
  const float* Wa1 = (const float*)d_in[17];
  const float* ba1 = (const float*)d_in[18];
  const float* Wa2 = (const float*)d_in[19];
  const float* ba2 = (const float*)d_in[20];
  float* out = (float*)d_out;

  int N = in_sizes[0] / NODE_F;
  int E = in_sizes[1] / EDGE_F;

  float* h    = (float*)d_ws;                              // N*128 f32
  float* agg  = h + (size_t)N * D;                         // N*256 f32
  short* hb   = (short*)(agg + (size_t)N * 256);           // N*128 bf16
  short* eb   = hb + (size_t)N * D;                        // E*64 bf16
  short* Wf1  = eb + (size_t)E * EDIM;
  short* Wf2  = Wf1 + 81920;
  short* Wfu  = Wf2 + 65536;
  int*   deg     = (int*)(Wfu + 49152);                    // N
  int*   offsets = deg + N;                                // N+1
  int*   cursor  = offsets + N + 1;                        // N
  int*   elist   = cursor + N;                             // E
  uintptr_t mb = ((uintptr_t)(elist + E) + 15) & ~(uintptr_t)15;
  short* msg_buf = (short*)mb;                             // E*256 bf16 (CSR order)
  float* flat = (float*)msg_buf;                           // aliases msg_buf (post-loop)
  float* tfb  = flat + (size_t)2 * B_PAIRS * MAXN * D;

  // CSR build (launch-invariant indices; rebuilt every call, no static state)
  hipMemsetAsync(deg, 0, (size_t)N * sizeof(int), stream);
  hist_kernel<<<256, 256, 0, stream>>>(to_idx, deg, E);
  scan_kernel<<<1, 1024, 0, stream>>>(deg, offsets, cursor, N);
  scatter_csr<<<256, 256, 0, stream>>>(to_idx, cursor, elist, E);

  prep_w<<<768, 256, 0, stream>>>(W1, W2, Wu, Wf1, Wf2, Wfu);
  encode_nodes<<<(N + 1) / 2, 256, 0, stream>>>(nf, W_node, b_node, h, hb, N);
  encode_edges<<<(E + 3) / 4, 256, 0, stream>>>(ef, W_edge, b_edge, eb, E);

  for (int s = 0; s < PROP_STEPS; s++) {
    msg_mfma<<<(E + 63) / 64, 256, 0, stream>>>(hb, eb, from_idx, to_idx, elist,
                                                Wf1, b1, Wf2, b2, msg_buf, E);
    agg_csr<<<(N + 1) / 2, 256, 0, stream>>>(msg_buf, offsets, agg, N);
    update_mfma<<<(N + 31) / 32, 256, 0, stream>>>(h, hb, agg, Wfu, bu, N);
  }

  // flat/tfb alias msg_buf — safe now that the prop loop is done
  hipMemsetAsync(flat, 0, (size_t)2 * B_PAIRS * MAXN * D * sizeof(float), stream);
  scatter_kernel<<<(N * D + 255) / 256, 256, 0, stream>>>(h, pos, flat, N);
  attfeat_kernel<<<(2 * B_PAIRS * MAXN) / MTA, 256, 0, stream>>>(flat, Wa1, ba1, Wa2, ba2,
                                                                 qsz, csz, tfb);
  score_kernel<<<B_PAIRS, 256, 0, stream>>>(tfb, flat, qsz, csz, out);
}

// Round 8
// 667.935 us; speedup vs baseline: 1.6063x; 1.0685x over previous
//
#include <hip/hip_runtime.h>

#define D 128
#define EDIM 64
#define NODE_F 32
#define EDGE_F 16
#define B_PAIRS 256
#define MAXN 64
#define PROP_STEPS 3

#define MTA 32
#define KC 16

typedef __attribute__((ext_vector_type(8))) short short8;
typedef __attribute__((ext_vector_type(16))) float floatx16;

__device__ __forceinline__ short f2bf(float x) {
  unsigned u = __float_as_uint(x);
  u = (u + 0x7fff + ((u >> 16) & 1)) >> 16;   // RNE
  return (short)u;
}

__device__ __forceinline__ float bf2f(short s) {
  return __uint_as_float(((unsigned)(unsigned short)s) << 16);
}

// ---------------- weight prep: fragment-order layouts ----------------
__global__ __launch_bounds__(256) void prep_w(
    const float* __restrict__ W1, const float* __restrict__ W2,
    const float* __restrict__ Wu,
    short* __restrict__ Wf1, short* __restrict__ Wf2, short* __restrict__ Wfu)
{
  int idx = blockIdx.x * 256 + threadIdx.x;
  if (idx < 81920) {
    int p = idx >> 13, ks = (idx >> 12) & 1, hi = (idx >> 11) & 1;
    int n = (idx >> 3) & 255, j = idx & 7;
    int k = p * 32 + ks * 16 + hi * 8 + j;
    Wf1[idx] = f2bf(W1[(size_t)k * 256 + n]);
  } else if (idx < 147456) {
    int i = idx - 81920;
    int p = i >> 13, ks = (i >> 12) & 1, hi = (i >> 11) & 1;
    int n = (i >> 3) & 255, j = i & 7;
    int k = p * 32 + ks * 16 + hi * 8 + j;
    Wf2[i] = f2bf(W2[(size_t)k * 256 + n]);
  } else if (idx < 196608) {
    int i = idx - 147456;
    int p = i >> 12, ks = (i >> 11) & 1, hi = (i >> 10) & 1;
    int n = (i >> 3) & 127, j = i & 7;
    int k = p * 32 + ks * 16 + hi * 8 + j;
    Wfu[i] = f2bf(Wu[(size_t)k * 128 + n]);
  }
}

// ---------------- CSR build (indices are launch-invariant) ----------------
__global__ __launch_bounds__(256) void hist_kernel(const int* __restrict__ to_idx,
                                                   int* __restrict__ deg, int E)
{
  for (int e = blockIdx.x * 256 + threadIdx.x; e < E; e += gridDim.x * 256)
    atomicAdd(&deg[to_idx[e]], 1);
}

__global__ __launch_bounds__(1024) void scan_kernel(const int* __restrict__ deg,
                                                    int* __restrict__ offsets,
                                                    int* __restrict__ cursor, int N)
{
  __shared__ int part[1024];
  int t = threadIdx.x;
  int chunk = (N + 1023) / 1024;
  int s0 = t * chunk, s1 = min(s0 + chunk, N);
  int sum = 0;
  for (int i = s0; i < s1; i++) sum += deg[i];
  part[t] = sum;
  __syncthreads();
  for (int off = 1; off < 1024; off <<= 1) {
    int v = 0;
    if (t >= off) v = part[t - off];
    __syncthreads();
    if (t >= off) part[t] += v;
    __syncthreads();
  }
  int base = (t == 0) ? 0 : part[t - 1];
  for (int i = s0; i < s1; i++) {
    offsets[i] = base; cursor[i] = base;
    base += deg[i];
  }
  if (t == 1023) offsets[N] = part[1023];
}

__global__ __launch_bounds__(256) void scatter_csr(const int* __restrict__ to_idx,
                                                   int* __restrict__ cursor,
                                                   int* __restrict__ elist, int E)
{
  for (int e = blockIdx.x * 256 + threadIdx.x; e < E; e += gridDim.x * 256) {
    int pos = atomicAdd(&cursor[to_idx[e]], 1);
    elist[pos] = e;
  }
}

// ---------------- encoders ----------------
__global__ __launch_bounds__(256) void encode_nodes(
    const float* __restrict__ nf, const float* __restrict__ W,
    const float* __restrict__ bias, float* __restrict__ h,
    short* __restrict__ hb, int N)
{
  int t = threadIdx.x;
  int n = blockIdx.x * 2 + (t >> 7);
  int c = t & 127;
  if (n >= N) return;
  float acc = bias[c];
  #pragma unroll
  for (int k = 0; k < NODE_F; k++)
    acc += nf[(size_t)n * NODE_F + k] * W[k * D + c];
  h[(size_t)n * D + c] = acc;
  hb[(size_t)n * D + c] = f2bf(acc);
}

__global__ __launch_bounds__(256) void encode_edges(
    const float* __restrict__ ef, const float* __restrict__ W,
    const float* __restrict__ bias, short* __restrict__ eb, int E)
{
  int t = threadIdx.x;
  int eid = blockIdx.x * 4 + (t >> 6);
  int c = t & 63;
  if (eid >= E) return;
  float acc = bias[c];
  #pragma unroll
  for (int k = 0; k < EDGE_F; k++)
    acc += ef[(size_t)eid * EDGE_F + k] * W[k * EDIM + c];
  eb[(size_t)eid * EDIM + c] = f2bf(acc);
}

// ---------------- message + fused CSR aggregation ----------------
// Block = 64 CSR-ordered edges. Wave w: ALL 64 rows x cols [w*64, w*64+64)
// (2 row-tiles x 2 col-tiles -> each B fragment feeds 2 MFMAs, halving L2 B traffic).
// After GEMM2, per-node runs are reduced in LDS and written straight to agg
// (plain store if the node's full CSR range is inside this block, atomics else).
__global__ __launch_bounds__(256, 3) void msg_mfma(
    const short* __restrict__ hb, const short* __restrict__ eb,
    const int* __restrict__ from_idx, const int* __restrict__ to_idx,
    const int* __restrict__ elist, const int* __restrict__ offsets,
    const short* __restrict__ Wf1, const float* __restrict__ b1,
    const short* __restrict__ Wf2, const float* __restrict__ b2,
    float* __restrict__ agg, int E)
{
  __shared__ short sA[64 * 328];   // 41984B: edge_in (K=320) -> hidden (K=256) -> msg (stride 264)
  __shared__ int from_s[64], eid_s[64], to_s[64];
  __shared__ int rend_s[64], inter_s[64];

  int t = threadIdx.x;
  int ln = t & 63, w = t >> 6;
  int l31 = ln & 31, hi = ln >> 5;
  int cb = w * 64;
  int e0 = blockIdx.x * 64;

  if (t < 64) {
    int idx = e0 + t;
    int eid = (idx < E) ? elist[idx] : 0;
    eid_s[t] = eid;
    from_s[t] = from_idx[eid];
    to_s[t] = (idx < E) ? to_idx[eid] : -1;
  }
  __syncthreads();

  // per-run metadata (threads 0..63; consumed only after later barriers)
  if (t < 64) {
    int nd = to_s[t];
    bool head = (t == 0) || (nd != to_s[t - 1]);
    if (head && nd >= 0) {
      int re = t + 1;
      while (re < 64 && to_s[re] == nd) re++;
      rend_s[t] = re;
      inter_s[t] = (offsets[nd] == e0 + t) && (offsets[nd + 1] == e0 + re) ? 1 : 0;
    }
  }

  // stage A = [h[from] | h[to] | e] bf16, row stride 328 shorts
  for (int i = t; i < 1024; i += 256) {
    int r = i >> 4, c = i & 15;
    *(short8*)(sA + r * 328 + c * 8) =
        *(const short8*)(hb + (size_t)from_s[r] * 128 + c * 8);
  }
  for (int i = t; i < 1024; i += 256) {
    int r = i >> 4, c = i & 15;
    int nd = to_s[r]; if (nd < 0) nd = 0;
    *(short8*)(sA + r * 328 + 128 + c * 8) =
        *(const short8*)(hb + (size_t)nd * 128 + c * 8);
  }
  for (int i = t; i < 512; i += 256) {
    int r = i >> 3, c = i & 7;
    *(short8*)(sA + r * 328 + 256 + c * 8) =
        *(const short8*)(eb + (size_t)eid_s[r] * 64 + c * 8);
  }
  __syncthreads();

  const int arow0 = l31 * 328;
  const int arow1 = (32 + l31) * 328;
  const int bc0 = (cb + l31) * 8;
  const int bc1 = (cb + 32 + l31) * 8;

  floatx16 acc[2][2];
  #pragma unroll
  for (int rg = 0; rg < 2; rg++)
    #pragma unroll
    for (int ct = 0; ct < 2; ct++)
      #pragma unroll
      for (int i = 0; i < 16; i++) acc[rg][ct][i] = 0.f;

  // ---- GEMM1: 20 steps, K=320, ring-3 B prefetch, A double-buffered
  {
    short8 bbuf[3][2];
    #pragma unroll
    for (int s = 0; s < 3; s++) {
      const short* bb = Wf1 + (size_t)(s * 2 + hi) * 2048;
      bbuf[s][0] = *(const short8*)(bb + bc0);
      bbuf[s][1] = *(const short8*)(bb + bc1);
    }
    short8 abuf[2][2];
    abuf[0][0] = *(const short8*)(sA + arow0 + hi * 8);
    abuf[0][1] = *(const short8*)(sA + arow1 + hi * 8);
    #pragma unroll
    for (int step = 0; step < 20; step++) {
      if (step + 1 < 20) {
        abuf[(step + 1) & 1][0] = *(const short8*)(sA + arow0 + (step + 1) * 16 + hi * 8);
        abuf[(step + 1) & 1][1] = *(const short8*)(sA + arow1 + (step + 1) * 16 + hi * 8);
      }
      acc[0][0] = __builtin_amdgcn_mfma_f32_32x32x16_bf16(abuf[step & 1][0], bbuf[step % 3][0], acc[0][0], 0, 0, 0);
      acc[0][1] = __builtin_amdgcn_mfma_f32_32x32x16_bf16(abuf[step & 1][0], bbuf[step % 3][1], acc[0][1], 0, 0, 0);
      acc[1][0] = __builtin_amdgcn_mfma_f32_32x32x16_bf16(abuf[step & 1][1], bbuf[step % 3][0], acc[1][0], 0, 0, 0);
      acc[1][1] = __builtin_amdgcn_mfma_f32_32x32x16_bf16(abuf[step & 1][1], bbuf[step % 3][1], acc[1][1], 0, 0, 0);
      if (step + 3 < 20) {
        const short* bb = Wf1 + (size_t)((step + 3) * 2 + hi) * 2048;
        bbuf[step % 3][0] = *(const short8*)(bb + bc0);
        bbuf[step % 3][1] = *(const short8*)(bb + bc1);
      }
    }
  }

  // GEMM2 B prologue issued before the barrier (drain doubles as its wait)
  short8 b2buf[3][2];
  #pragma unroll
  for (int s = 0; s < 3; s++) {
    const short* bb = Wf2 + (size_t)(s * 2 + hi) * 2048;
    b2buf[s][0] = *(const short8*)(bb + bc0);
    b2buf[s][1] = *(const short8*)(bb + bc1);
  }

  // relu + bias, hidden (bf16) back into sA
  __syncthreads();
  #pragma unroll
  for (int rg = 0; rg < 2; rg++)
    #pragma unroll
    for (int ct = 0; ct < 2; ct++) {
      int col = cb + ct * 32 + l31;
      float bv = b1[col];
      #pragma unroll
      for (int reg = 0; reg < 16; reg++) {
        int row = rg * 32 + (reg & 3) + 8 * (reg >> 2) + 4 * hi;
        sA[row * 328 + col] = f2bf(fmaxf(acc[rg][ct][reg] + bv, 0.f));
      }
    }
  __syncthreads();

  // ---- GEMM2: 16 steps, K=256
  floatx16 acc2[2][2];
  #pragma unroll
  for (int rg = 0; rg < 2; rg++)
    #pragma unroll
    for (int ct = 0; ct < 2; ct++)
      #pragma unroll
      for (int i = 0; i < 16; i++) acc2[rg][ct][i] = 0.f;

  {
    short8 abuf[2][2];
    abuf[0][0] = *(const short8*)(sA + arow0 + hi * 8);
    abuf[0][1] = *(const short8*)(sA + arow1 + hi * 8);
    #pragma unroll
    for (int step = 0; step < 16; step++) {
      if (step + 1 < 16) {
        abuf[(step + 1) & 1][0] = *(const short8*)(sA + arow0 + (step + 1) * 16 + hi * 8);
        abuf[(step + 1) & 1][1] = *(const short8*)(sA + arow1 + (step + 1) * 16 + hi * 8);
      }
      acc2[0][0] = __builtin_amdgcn_mfma_f32_32x32x16_bf16(abuf[step & 1][0], b2buf[step % 3][0], acc2[0][0], 0, 0, 0);
      acc2[0][1] = __builtin_amdgcn_mfma_f32_32x32x16_bf16(abuf[step & 1][0], b2buf[step % 3][1], acc2[0][1], 0, 0, 0);
      acc2[1][0] = __builtin_amdgcn_mfma_f32_32x32x16_bf16(abuf[step & 1][1], b2buf[step % 3][0], acc2[1][0], 0, 0, 0);
      acc2[1][1] = __builtin_amdgcn_mfma_f32_32x32x16_bf16(abuf[step & 1][1], b2buf[step % 3][1], acc2[1][1], 0, 0, 0);
      if (step + 3 < 16) {
        const short* bb = Wf2 + (size_t)((step + 3) * 2 + hi) * 2048;
        b2buf[step % 3][0] = *(const short8*)(bb + bc0);
        b2buf[step % 3][1] = *(const short8*)(bb + bc1);
      }
    }
  }

  // msg (bf16) -> sA (stride 264)
  __syncthreads();
  #pragma unroll
  for (int rg = 0; rg < 2; rg++)
    #pragma unroll
    for (int ct = 0; ct < 2; ct++) {
      int col = cb + ct * 32 + l31;
      float bv = b2[col];
      #pragma unroll
      for (int reg = 0; reg < 16; reg++) {
        int row = rg * 32 + (reg & 3) + 8 * (reg >> 2) + 4 * hi;
        sA[row * 264 + col] = f2bf(acc2[rg][ct][reg] + bv);
      }
    }
  __syncthreads();

  // fused CSR reduction: thread t owns column t; walk the runs (uniform control flow)
  {
    int c = t;
    for (int r = 0; r < 64; ) {
      int nd = to_s[r];
      if (nd < 0) break;               // invalid rows trail
      int re = rend_s[r];
      float a = 0.f;
      for (int i = r; i < re; i++)
        a += bf2f(sA[i * 264 + c]);
      float* dst = agg + (size_t)nd * 256 + c;
      if (inter_s[r]) *dst = a;
      else unsafeAtomicAdd(dst, a);
      r = re;
    }
  }
}

// ---------------- node update: bf16 MFMA, ring-3 B prefetch ----------------
__global__ __launch_bounds__(256, 4) void update_mfma(
    float* __restrict__ h, short* __restrict__ hbf, const float* __restrict__ agg,
    const short* __restrict__ Wfu, const float* __restrict__ bu, int N)
{
  __shared__ short sA[32 * 392];

  int t = threadIdx.x;
  int ln = t & 63, w = t >> 6;
  int l31 = ln & 31, hi = ln >> 5;
  int n0 = blockIdx.x * 32;

  for (int i = t; i < 512; i += 256) {
    int r = i >> 4, c = i & 15;
    short8 v = {0, 0, 0, 0, 0, 0, 0, 0};
    if (n0 + r < N) v = *(const short8*)(hbf + (size_t)(n0 + r) * 128 + c * 8);
    *(short8*)(sA + r * 392 + c * 8) = v;
  }
  for (int i = t; i < 2048; i += 256) {
    int r = i >> 6, c4 = i & 63;
    int2 pk = {0, 0};
    if (n0 + r < N) {
      float4 v = *(const float4*)(agg + (size_t)(n0 + r) * 256 + c4 * 4);
      pk.x = (int)(unsigned short)f2bf(v.x) | ((int)(unsigned short)f2bf(v.y) << 16);
      pk.y = (int)(unsigned short)f2bf(v.z) | ((int)(unsigned short)f2bf(v.w) << 16);
    }
    *(int2*)(sA + r * 392 + 128 + c4 * 4) = pk;
  }
  __syncthreads();

  const int arow = l31 * 392;
  const int bcol = (w * 32 + l31) * 8;

  floatx16 acc;
  #pragma unroll
  for (int i = 0; i < 16; i++) acc[i] = 0.f;

  {
    short8 bbuf[3];
    #pragma unroll
    for (int s = 0; s < 3; s++)
      bbuf[s] = *(const short8*)(Wfu + (size_t)(s * 2 + hi) * 1024 + bcol);
    short8 abuf[2];
    abuf[0] = *(const short8*)(sA + arow + hi * 8);
    #pragma unroll
    for (int step = 0; step < 24; step++) {
      if (step + 1 < 24)
        abuf[(step + 1) & 1] = *(const short8*)(sA + arow + (step + 1) * 16 + hi * 8);
      acc = __builtin_amdgcn_mfma_f32_32x32x16_bf16(abuf[step & 1], bbuf[step % 3], acc, 0, 0, 0);
      if (step + 3 < 24)
        bbuf[step % 3] = *(const short8*)(Wfu + (size_t)((step + 3) * 2 + hi) * 1024 + bcol);
    }
  }

  int col = w * 32 + l31;
  float bv = bu[col];
  #pragma unroll
  for (int reg = 0; reg < 16; reg++) {
    int row = (reg & 3) + 8 * (reg >> 2) + 4 * hi;
    int n = n0 + row;
    if (n < N) {
      float nv = h[(size_t)n * 128 + col] + acc[reg] + bv;
      h[(size_t)n * 128 + col] = nv;
      hbf[(size_t)n * 128 + col] = f2bf(nv);
    }
  }
}

// ---------------- scatter into padded stacks ----------------
__global__ void scatter_kernel(const float* __restrict__ h, const int* __restrict__ pos,
                               float* __restrict__ flat, int N)
{
  int idx = blockIdx.x * 256 + threadIdx.x;
  if (idx >= N * D) return;
  int n = idx >> 7, c = idx & 127;
  flat[(size_t)pos[n] * D + c] = h[idx];
}

// ---------------- attention features (fp32) ----------------
__global__ __launch_bounds__(256) void attfeat_kernel(
    const float* __restrict__ flat,
    const float* __restrict__ Wa1, const float* __restrict__ ba1,
    const float* __restrict__ Wa2, const float* __restrict__ ba2,
    const int* __restrict__ qsizes, const int* __restrict__ csizes,
    float* __restrict__ tf)
{
  __shared__ float sA[MTA * 128];
  __shared__ float sW[KC * 128];
  int t = threadIdx.x, wv = t >> 6, ln = t & 63;
  int r0 = blockIdx.x * MTA;

  for (int i = t * 4; i < MTA * 128; i += 1024)
    *(float4*)(sA + i) = *(const float4*)(flat + (size_t)r0 * 128 + i);

  float2 bb = *(const float2*)(ba1 + ln * 2);
  float acc[8][2];
  #pragma unroll
  for (int j = 0; j < 8; j++) { acc[j][0] = bb.x; acc[j][1] = bb.y; }

  for (int kc = 0; kc < 128; kc += KC) {
    __syncthreads();
    for (int i = t * 4; i < KC * 128; i += 1024) {
      int kk = i >> 7, c = i & 127;
      *(float4*)(sW + i) = *(const float4*)(Wa1 + (size_t)(kc + kk) * 128 + c);
    }
    __syncthreads();
    #pragma unroll
    for (int k4 = 0; k4 < KC; k4 += 4) {
      float4 a[8];
      #pragma unroll
      for (int j = 0; j < 8; j++)
        a[j] = *(const float4*)(sA + (wv * 8 + j) * 128 + kc + k4);
      #pragma unroll
      for (int k2 = 0; k2 < 4; k2++) {
        float2 w = *(const float2*)(sW + (k4 + k2) * 128 + ln * 2);
        #pragma unroll
        for (int j = 0; j < 8; j++) {
          float av = (k2 == 0) ? a[j].x : (k2 == 1) ? a[j].y : (k2 == 2) ? a[j].z : a[j].w;
          acc[j][0] += av * w.x; acc[j][1] += av * w.y;
        }
      }
    }
  }

  __syncthreads();
  #pragma unroll
  for (int j = 0; j < 8; j++) {
    sA[(wv * 8 + j) * 128 + ln * 2 + 0] = fmaxf(acc[j][0], 0.f);
    sA[(wv * 8 + j) * 128 + ln * 2 + 1] = fmaxf(acc[j][1], 0.f);
  }

  float2 bb2 = *(const float2*)(ba2 + ln * 2);
  #pragma unroll
  for (int j = 0; j < 8; j++) { acc[j][0] = bb2.x; acc[j][1] = bb2.y; }

  for (int kc = 0; kc < 128; kc += KC) {
    __syncthreads();
    for (int i = t * 4; i < KC * 128; i += 1024) {
      int kk = i >> 7, c = i & 127;
      *(float4*)(sW + i) = *(const float4*)(Wa2 + (size_t)(kc + kk) * 128 + c);
    }
    __syncthreads();
    #pragma unroll
    for (int k4 = 0; k4 < KC; k4 += 4) {
      float4 a[8];
      #pragma unroll
      for (int j = 0; j < 8; j++)
        a[j] = *(const float4*)(sA + (wv * 8 + j) * 128 + kc + k4);
      #pragma unroll
      for (int k2 = 0; k2 < 4; k2++) {
        float2 w = *(const float2*)(sW + (k4 + k2) * 128 + ln * 2);
        #pragma unroll
        for (int j = 0; j < 8; j++) {
          float av = (k2 == 0) ? a[j].x : (k2 == 1) ? a[j].y : (k2 == 2) ? a[j].z : a[j].w;
          acc[j][0] += av * w.x; acc[j][1] += av * w.y;
        }
      }
    }
  }

  #pragma unroll
  for (int j = 0; j < 8; j++) {
    int row = r0 + wv * 8 + j;
    int part = row >> 14, b = (row >> 6) & 255, pp = row & 63;
    int sz = part ? csizes[b] : qsizes[b];
    float m = (pp < sz) ? 1.f : 0.f;
    tf[(size_t)row * 128 + ln * 2 + 0] = acc[j][0] * m;
    tf[(size_t)row * 128 + ln * 2 + 1] = acc[j][1] * m;
  }
}

// ---------------- per-pair attention score ----------------
__global__ __launch_bounds__(256, 2) void score_kernel(
    const float* __restrict__ tf, const float* __restrict__ flat,
    const int* __restrict__ qsizes, const int* __restrict__ csizes,
    float* __restrict__ out)
{
  __shared__ float SL[64 * 65];
  __shared__ float SP[64 * 65];
  __shared__ float SP2[64 * 65];
  __shared__ float Atk[16 * 68];
  __shared__ float Btk[16 * 68];
  __shared__ float red[8];

  int b = blockIdx.x, t = threadIdx.x;
  const float* tq = tf + (size_t)b * 64 * 128;
  const float* tc = tf + ((size_t)16384 + (size_t)b * 64) * 128;
  const float* sq = flat + (size_t)b * 64 * 128;
  const float* sc = flat + ((size_t)16384 + (size_t)b * 64) * 128;
  int qs = qsizes[b], cs = csizes[b];

  int qg = (t >> 4) << 2;
  int cg = (t & 15) << 2;
  int dg = (t & 15) << 3;

  float lg[4][4] = {};
  for (int kc = 0; kc < 128; kc += 16) {
    __syncthreads();
    for (int i = t; i < 16 * 64; i += 256) {
      int q = i >> 4, kk = i & 15;
      Atk[kk * 68 + q] = tq[q * 128 + kc + kk];
      Btk[kk * 68 + q] = tc[q * 128 + kc + kk];
    }
    __syncthreads();
    #pragma unroll
    for (int kk = 0; kk < 16; kk++) {
      float4 aq = *(const float4*)(Atk + kk * 68 + qg);
      float4 bc = *(const float4*)(Btk + kk * 68 + cg);
      lg[0][0] += aq.x * bc.x; lg[0][1] += aq.x * bc.y; lg[0][2] += aq.x * bc.z; lg[0][3] += aq.x * bc.w;
      lg[1][0] += aq.y * bc.x; lg[1][1] += aq.y * bc.y; lg[1][2] += aq.y * bc.z; lg[1][3] += aq.y * bc.w;
      lg[2][0] += aq.z * bc.x; lg[2][1] += aq.z * bc.y; lg[2][2] += aq.z * bc.z; lg[2][3] += aq.z * bc.w;
      lg[3][0] += aq.w * bc.x; lg[3][1] += aq.w * bc.y; lg[3][2] += aq.w * bc.z; lg[3][3] += aq.w * bc.w;
    }
  }
  #pragma unroll
  for (int j = 0; j < 4; j++)
    #pragma unroll
    for (int i = 0; i < 4; i++) {
      int q = qg + j, c = cg + i;
      SL[q * 65 + c] = (q < qs && c < cs) ? lg[j][i] * 10.0f : -1e9f;
    }
  __syncthreads();

  if (t < 64) {
    int q = t;
    if (q < qs) {
      float m = -1e30f;
      for (int c = 0; c < 64; c++) m = fmaxf(m, SL[q * 65 + c]);
      float s = 0.f;
      for (int c = 0; c < 64; c++) s += __expf(SL[q * 65 + c] - m);
      float inv = 1.0f / s;
      for (int c = 0; c < 64; c++) SP[q * 65 + c] = __expf(SL[q * 65 + c] - m) * inv;
    } else {
      for (int c = 0; c < 64; c++) SP[q * 65 + c] = 0.f;
    }
  } else if (t < 128) {
    int c = t - 64;
    if (c < cs) {
      float m = -1e30f;
      for (int q = 0; q < 64; q++) m = fmaxf(m, SL[q * 65 + c]);
      float s = 0.f;
      for (int q = 0; q < 64; q++) s += __expf(SL[q * 65 + c] - m);
      float inv = 1.0f / s;
      for (int q = 0; q < 64; q++) SP2[q * 65 + c] = __expf(SL[q * 65 + c] - m) * inv;
    } else {
      for (int q = 0; q < 64; q++) SP2[q * 65 + c] = 0.f;
    }
  }
  __syncthreads();

  float al[4][8] = {};
  for (int c = 0; c < 64; c++) {
    float p0 = SP[(qg + 0) * 65 + c];
    float p1 = SP[(qg + 1) * 65 + c];
    float p2 = SP[(qg + 2) * 65 + c];
    float p3 = SP[(qg + 3) * 65 + c];
    float4 s0 = *(const float4*)(sc + c * 128 + dg);
    float4 s1 = *(const float4*)(sc + c * 128 + dg + 4);
    al[0][0] += p0 * s0.x; al[0][1] += p0 * s0.y; al[0][2] += p0 * s0.z; al[0][3] += p0 * s0.w;
    al[0][4] += p0 * s1.x; al[0][5] += p0 * s1.y; al[0][6] += p0 * s1.z; al[0][7] += p0 * s1.w;
    al[1][0] += p1 * s0.x; al[1][1] += p1 * s0.y; al[1][2] += p1 * s0.z; al[1][3] += p1 * s0.w;
    al[1][4] += p1 * s1.x; al[1][5] += p1 * s1.y; al[1][6] += p1 * s1.z; al[1][7] += p1 * s1.w;
    al[2][0] += p2 * s0.x; al[2][1] += p2 * s0.y; al[2][2] += p2 * s0.z; al[2][3] += p2 * s0.w;
    al[2][4] += p2 * s1.x; al[2][5] += p2 * s1.y; al[2][6] += p2 * s1.z; al[2][7] += p2 * s1.w;
    al[3][0] += p3 * s0.x; al[3][1] += p3 * s0.y; al[3][2] += p3 * s0.z; al[3][3] += p3 * s0.w;
    al[3][4] += p3 * s1.x; al[3][5] += p3 * s1.y; al[3][6] += p3 * s1.z; al[3][7] += p3 * s1.w;
  }
  float qpart = 0.f;
  #pragma unroll
  for (int j = 0; j < 4; j++) {
    float4 a0 = *(const float4*)(sq + (qg + j) * 128 + dg);
    float4 a1 = *(const float4*)(sq + (qg + j) * 128 + dg + 4);
    qpart += fmaxf(a0.x - al[j][0], 0.f) + fmaxf(a0.y - al[j][1], 0.f)
           + fmaxf(a0.z - al[j][2], 0.f) + fmaxf(a0.w - al[j][3], 0.f)
           + fmaxf(a1.x - al[j][4], 0.f) + fmaxf(a1.y - al[j][5], 0.f)
           + fmaxf(a1.z - al[j][6], 0.f) + fmaxf(a1.w - al[j][7], 0.f);
  }

  float al2[4][8] = {};
  for (int q = 0; q < 64; q++) {
    float p0 = SP2[q * 65 + qg + 0];
    float p1 = SP2[q * 65 + qg + 1];
    float p2 = SP2[q * 65 + qg + 2];
    float p3 = SP2[q * 65 + qg + 3];
    float4 s0 = *(const float4*)(sq + q * 128 + dg);
    float4 s1 = *(const float4*)(sq + q * 128 + dg + 4);
    al2[0][0] += p0 * s0.x; al2[0][1] += p0 * s0.y; al2[0][2] += p0 * s0.z; al2[0][3] += p0 * s0.w;
    al2[0][4] += p0 * s1.x; al2[0][5] += p0 * s1.y; al2[0][6] += p0 * s1.z; al2[0][7] += p0 * s1.w;
    al2[1][0] += p1 * s0.x; al2[1][1] += p1 * s0.y; al2[1][2] += p1 * s0.z; al2[1][3] += p1 * s0.w;
    al2[1][4] += p1 * s1.x; al2[1][5] += p1 * s1.y; al2[1][6] += p1 * s1.z; al2[1][7] += p1 * s1.w;
    al2[2][0] += p2 * s0.x; al2[2][1] += p2 * s0.y; al2[2][2] += p2 * s0.z; al2[2][3] += p2 * s0.w;
    al2[2][4] += p2 * s1.x; al2[2][5] += p2 * s1.y; al2[2][6] += p2 * s1.z; al2[2][7] += p2 * s1.w;
    al2[3][0] += p3 * s0.x; al2[3][1] += p3 * s0.y; al2[3][2] += p3 * s0.z; al2[3][3] += p3 * s0.w;
    al2[3][4] += p3 * s1.x; al2[3][5] += p3 * s1.y; al2[3][6] += p3 * s1.z; al2[3][7] += p3 * s1.w;
  }
  float cpart = 0.f;
  #pragma unroll
  for (int j = 0; j < 4; j++) {
    float4 b0 = *(const float4*)(sc + (qg + j) * 128 + dg);
    float4 b1 = *(const float4*)(sc + (qg + j) * 128 + dg + 4);
    cpart += fmaxf(b0.x - al2[j][0], 0.f) + fmaxf(b0.y - al2[j][1], 0.f)
           + fmaxf(b0.z - al2[j][2], 0.f) + fmaxf(b0.w - al2[j][3], 0.f)
           + fmaxf(b1.x - al2[j][4], 0.f) + fmaxf(b1.y - al2[j][5], 0.f)
           + fmaxf(b1.z - al2[j][6], 0.f) + fmaxf(b1.w - al2[j][7], 0.f);
  }

  for (int off = 32; off > 0; off >>= 1) {
    qpart += __shfl_down(qpart, off);
    cpart += __shfl_down(cpart, off);
  }
  int wv = t >> 6;
  if ((t & 63) == 0) { red[wv] = qpart; red[wv + 4] = cpart; }
  __syncthreads();
  if (t == 0) {
    float qsum = red[0] + red[1] + red[2] + red[3];
    float csum = red[4] + red[5] + red[6] + red[7];
    out[b] = fminf(-qsum, -csum);
  }
}

// ---------------- launch ----------------
extern "C" void kernel_launch(void* const* d_in, const int* in_sizes, int n_in,
                              void* d_out, int out_size, void* d_ws, size_t ws_size,
                              hipStream_t stream)
{
  const float* nf  = (const float*)d_in[0];
  const float* ef  = (const float*)d_in[1];
  const int* from_idx = (const int*)d_in[2];
  const int* to_idx   = (const int*)d_in[3];
  const int* pos      = (const int*)d_in[4];
  const int* qsz      = (const int*)d_in[5];
  const int* csz      = (const int*)d_in[6];
  const float* W_node = (const float*)d_in[7];
  const float* b_node = (const float*)d_in[8];
  const float* W_edge = (const float*)d_in[9];
  const float* b_edge = (const float*)d_in[10];
  const float* W1 = (const float*)d_in[11];
  const float* b1 = (const float*)d_in[12];
  const float* W2 = (const float*)d_in[13];
  const float* b2 = (const float*)d_in[14];
  const float* Wu = (const float*)d_in[15];
  const float* bu = (const float*)d_in[16];
  const float* Wa1 = (const float*)d_in[17];
  const float* ba1 = (const float*)d_in[18];
  const float* Wa2 = (const float*)d_in[19];
  const float* ba2 = (const float*)d_in[20];
  float* out = (float*)d_out;

  int N = in_sizes[0] / NODE_F;
  int E = in_sizes[1] / EDGE_F;

  float* h    = (float*)d_ws;                              // N*128 f32
  float* agg  = h + (size_t)N * D;                         // N*256 f32
  short* hb   = (short*)(agg + (size_t)N * 256);           // N*128 bf16
  short* eb   = hb + (size_t)N * D;                        // E*64 bf16
  short* Wf1  = eb + (size_t)E * EDIM;
  short* Wf2  = Wf1 + 81920;
  short* Wfu  = Wf2 + 65536;
  int*   deg     = (int*)(Wfu + 49152);                    // N
  int*   offsets = deg + N;                                // N+1
  int*   cursor  = offsets + N + 1;                        // N
  int*   elist   = cursor + N;                             // E
  uintptr_t fb = ((uintptr_t)(elist + E) + 15) & ~(uintptr_t)15;
  float* flat = (float*)fb;                                // 2*B*MAX*D f32
  float* tfb  = flat + (size_t)2 * B_PAIRS * MAXN * D;

  // CSR build (launch-invariant indices; rebuilt every call, no static state)
  hipMemsetAsync(deg, 0, (size_t)N * sizeof(int), stream);
  hist_kernel<<<256, 256, 0, stream>>>(to_idx, deg, E);
  scan_kernel<<<1, 1024, 0, stream>>>(deg, offsets, cursor, N);
  scatter_csr<<<256, 256, 0, stream>>>(to_idx, cursor, elist, E);

  prep_w<<<768, 256, 0, stream>>>(W1, W2, Wu, Wf1, Wf2, Wfu);
  encode_nodes<<<(N + 1) / 2, 256, 0, stream>>>(nf, W_node, b_node, h, hb, N);
  encode_edges<<<(E + 3) / 4, 256, 0, stream>>>(ef, W_edge, b_edge, eb, E);

  for (int s = 0; s < PROP_STEPS; s++) {
    hipMemsetAsync(agg, 0, (size_t)N * 256 * sizeof(float), stream);
    msg_mfma<<<(E + 63) / 64, 256, 0, stream>>>(hb, eb, from_idx, to_idx, elist, offsets,
                                                Wf1, b1, Wf2, b2, agg, E);
    update_mfma<<<(N + 31) / 32, 256, 0, stream>>>(h, hb, agg, Wfu, bu, N);
  }

  hipMemsetAsync(flat, 0, (size_t)2 * B_PAIRS * MAXN * D * sizeof(float), stream);
  scatter_kernel<<<(N * D + 255) / 256, 256, 0, stream>>>(h, pos, flat, N);
  attfeat_kernel<<<(2 * B_PAIRS * MAXN) / MTA, 256, 0, stream>>>(flat, Wa1, ba1, Wa2, ba2,
                                                                 qsz, csz, tfb);
  score_kernel<<<B_PAIRS, 256, 0, stream>>>(tfb, flat, qsz, csz, out);
}

// Round 9
// 621.685 us; speedup vs baseline: 1.7258x; 1.0744x over previous
//
#include <hip/hip_runtime.h>

#define D 128
#define EDIM 64
#define NODE_F 32
#define EDGE_F 16
#define B_PAIRS 256
#define MAXN 64
#define PROP_STEPS 3

typedef __attribute__((ext_vector_type(8))) short short8;
typedef __attribute__((ext_vector_type(16))) float floatx16;

__device__ __forceinline__ short f2bf(float x) {
  unsigned u = __float_as_uint(x);
  u = (u + 0x7fff + ((u >> 16) & 1)) >> 16;   // RNE
  return (short)u;
}

__device__ __forceinline__ float bf2f(short s) {
  return __uint_as_float(((unsigned)(unsigned short)s) << 16);
}

// ---------------- weight prep: fragment-order layouts ----------------
// Wf1 (K=320,N=256): 81920 | Wf2 (K=256,N=256): 65536 | Wfu (K=384,N=128): 49152
// Wfa1 (K=128,N=128): 16384 | Wfa2: 16384.  Layout [step][hi][n][8].
__global__ __launch_bounds__(256) void prep_w(
    const float* __restrict__ W1, const float* __restrict__ W2,
    const float* __restrict__ Wu,
    const float* __restrict__ Wa1, const float* __restrict__ Wa2,
    short* __restrict__ Wf1, short* __restrict__ Wf2, short* __restrict__ Wfu,
    short* __restrict__ Wfa1, short* __restrict__ Wfa2)
{
  int idx = blockIdx.x * 256 + threadIdx.x;
  if (idx < 81920) {
    int p = idx >> 13, ks = (idx >> 12) & 1, hi = (idx >> 11) & 1;
    int n = (idx >> 3) & 255, j = idx & 7;
    int k = p * 32 + ks * 16 + hi * 8 + j;
    Wf1[idx] = f2bf(W1[(size_t)k * 256 + n]);
  } else if (idx < 147456) {
    int i = idx - 81920;
    int p = i >> 13, ks = (i >> 12) & 1, hi = (i >> 11) & 1;
    int n = (i >> 3) & 255, j = i & 7;
    int k = p * 32 + ks * 16 + hi * 8 + j;
    Wf2[i] = f2bf(W2[(size_t)k * 256 + n]);
  } else if (idx < 196608) {
    int i = idx - 147456;
    int p = i >> 12, ks = (i >> 11) & 1, hi = (i >> 10) & 1;
    int n = (i >> 3) & 127, j = i & 7;
    int k = p * 32 + ks * 16 + hi * 8 + j;
    Wfu[i] = f2bf(Wu[(size_t)k * 128 + n]);
  } else if (idx < 212992) {
    int i = idx - 196608;
    int step = i >> 11, hi = (i >> 10) & 1;
    int n = (i >> 3) & 127, j = i & 7;
    int k = step * 16 + hi * 8 + j;
    Wfa1[i] = f2bf(Wa1[(size_t)k * 128 + n]);
  } else if (idx < 229376) {
    int i = idx - 212992;
    int step = i >> 11, hi = (i >> 10) & 1;
    int n = (i >> 3) & 127, j = i & 7;
    int k = step * 16 + hi * 8 + j;
    Wfa2[i] = f2bf(Wa2[(size_t)k * 128 + n]);
  }
}

// ---------------- CSR build (indices are launch-invariant) ----------------
__global__ __launch_bounds__(256) void hist_kernel(const int* __restrict__ to_idx,
                                                   int* __restrict__ deg, int E)
{
  for (int e = blockIdx.x * 256 + threadIdx.x; e < E; e += gridDim.x * 256)
    atomicAdd(&deg[to_idx[e]], 1);
}

__global__ __launch_bounds__(1024) void scan_kernel(const int* __restrict__ deg,
                                                    int* __restrict__ offsets,
                                                    int* __restrict__ cursor, int N)
{
  __shared__ int part[1024];
  int t = threadIdx.x;
  int chunk = (N + 1023) / 1024;
  int s0 = t * chunk, s1 = min(s0 + chunk, N);
  int sum = 0;
  for (int i = s0; i < s1; i++) sum += deg[i];
  part[t] = sum;
  __syncthreads();
  for (int off = 1; off < 1024; off <<= 1) {
    int v = 0;
    if (t >= off) v = part[t - off];
    __syncthreads();
    if (t >= off) part[t] += v;
    __syncthreads();
  }
  int base = (t == 0) ? 0 : part[t - 1];
  for (int i = s0; i < s1; i++) {
    offsets[i] = base; cursor[i] = base;
    base += deg[i];
  }
  if (t == 1023) offsets[N] = part[1023];
}

__global__ __launch_bounds__(256) void scatter_csr(const int* __restrict__ to_idx,
                                                   int* __restrict__ cursor,
                                                   int* __restrict__ elist, int E)
{
  for (int e = blockIdx.x * 256 + threadIdx.x; e < E; e += gridDim.x * 256) {
    int pos = atomicAdd(&cursor[to_idx[e]], 1);
    elist[pos] = e;
  }
}

// ---------------- encoders ----------------
__global__ __launch_bounds__(256) void encode_nodes(
    const float* __restrict__ nf, const float* __restrict__ W,
    const float* __restrict__ bias, float* __restrict__ h,
    short* __restrict__ hb, int N)
{
  int t = threadIdx.x;
  int n = blockIdx.x * 2 + (t >> 7);
  int c = t & 127;
  if (n >= N) return;
  float acc = bias[c];
  #pragma unroll
  for (int k = 0; k < NODE_F; k++)
    acc += nf[(size_t)n * NODE_F + k] * W[k * D + c];
  h[(size_t)n * D + c] = acc;
  hb[(size_t)n * D + c] = f2bf(acc);
}

__global__ __launch_bounds__(256) void encode_edges(
    const float* __restrict__ ef, const float* __restrict__ W,
    const float* __restrict__ bias, short* __restrict__ eb, int E)
{
  int t = threadIdx.x;
  int eid = blockIdx.x * 4 + (t >> 6);
  int c = t & 63;
  if (eid >= E) return;
  float acc = bias[c];
  #pragma unroll
  for (int k = 0; k < EDGE_F; k++)
    acc += ef[(size_t)eid * EDGE_F + k] * W[k * EDIM + c];
  eb[(size_t)eid * EDIM + c] = f2bf(acc);
}

// ---------------- message + fused CSR aggregation (unchanged from R8) ----------------
__global__ __launch_bounds__(256, 3) void msg_mfma(
    const short* __restrict__ hb, const short* __restrict__ eb,
    const int* __restrict__ from_idx, const int* __restrict__ to_idx,
    const int* __restrict__ elist, const int* __restrict__ offsets,
    const short* __restrict__ Wf1, const float* __restrict__ b1,
    const short* __restrict__ Wf2, const float* __restrict__ b2,
    float* __restrict__ agg, int E)
{
  __shared__ short sA[64 * 328];
  __shared__ int from_s[64], eid_s[64], to_s[64];
  __shared__ int rend_s[64], inter_s[64];

  int t = threadIdx.x;
  int ln = t & 63, w = t >> 6;
  int l31 = ln & 31, hi = ln >> 5;
  int cb = w * 64;
  int e0 = blockIdx.x * 64;

  if (t < 64) {
    int idx = e0 + t;
    int eid = (idx < E) ? elist[idx] : 0;
    eid_s[t] = eid;
    from_s[t] = from_idx[eid];
    to_s[t] = (idx < E) ? to_idx[eid] : -1;
  }
  __syncthreads();

  if (t < 64) {
    int nd = to_s[t];
    bool head = (t == 0) || (nd != to_s[t - 1]);
    if (head && nd >= 0) {
      int re = t + 1;
      while (re < 64 && to_s[re] == nd) re++;
      rend_s[t] = re;
      inter_s[t] = (offsets[nd] == e0 + t) && (offsets[nd + 1] == e0 + re) ? 1 : 0;
    }
  }

  for (int i = t; i < 1024; i += 256) {
    int r = i >> 4, c = i & 15;
    *(short8*)(sA + r * 328 + c * 8) =
        *(const short8*)(hb + (size_t)from_s[r] * 128 + c * 8);
  }
  for (int i = t; i < 1024; i += 256) {
    int r = i >> 4, c = i & 15;
    int nd = to_s[r]; if (nd < 0) nd = 0;
    *(short8*)(sA + r * 328 + 128 + c * 8) =
        *(const short8*)(hb + (size_t)nd * 128 + c * 8);
  }
  for (int i = t; i < 512; i += 256) {
    int r = i >> 3, c = i & 7;
    *(short8*)(sA + r * 328 + 256 + c * 8) =
        *(const short8*)(eb + (size_t)eid_s[r] * 64 + c * 8);
  }
  __syncthreads();

  const int arow0 = l31 * 328;
  const int arow1 = (32 + l31) * 328;
  const int bc0 = (cb + l31) * 8;
  const int bc1 = (cb + 32 + l31) * 8;

  floatx16 acc[2][2];
  #pragma unroll
  for (int rg = 0; rg < 2; rg++)
    #pragma unroll
    for (int ct = 0; ct < 2; ct++)
      #pragma unroll
      for (int i = 0; i < 16; i++) acc[rg][ct][i] = 0.f;

  {
    short8 bbuf[3][2];
    #pragma unroll
    for (int s = 0; s < 3; s++) {
      const short* bb = Wf1 + (size_t)(s * 2 + hi) * 2048;
      bbuf[s][0] = *(const short8*)(bb + bc0);
      bbuf[s][1] = *(const short8*)(bb + bc1);
    }
    short8 abuf[2][2];
    abuf[0][0] = *(const short8*)(sA + arow0 + hi * 8);
    abuf[0][1] = *(const short8*)(sA + arow1 + hi * 8);
    #pragma unroll
    for (int step = 0; step < 20; step++) {
      if (step + 1 < 20) {
        abuf[(step + 1) & 1][0] = *(const short8*)(sA + arow0 + (step + 1) * 16 + hi * 8);
        abuf[(step + 1) & 1][1] = *(const short8*)(sA + arow1 + (step + 1) * 16 + hi * 8);
      }
      acc[0][0] = __builtin_amdgcn_mfma_f32_32x32x16_bf16(abuf[step & 1][0], bbuf[step % 3][0], acc[0][0], 0, 0, 0);
      acc[0][1] = __builtin_amdgcn_mfma_f32_32x32x16_bf16(abuf[step & 1][0], bbuf[step % 3][1], acc[0][1], 0, 0, 0);
      acc[1][0] = __builtin_amdgcn_mfma_f32_32x32x16_bf16(abuf[step & 1][1], bbuf[step % 3][0], acc[1][0], 0, 0, 0);
      acc[1][1] = __builtin_amdgcn_mfma_f32_32x32x16_bf16(abuf[step & 1][1], bbuf[step % 3][1], acc[1][1], 0, 0, 0);
      if (step + 3 < 20) {
        const short* bb = Wf1 + (size_t)((step + 3) * 2 + hi) * 2048;
        bbuf[step % 3][0] = *(const short8*)(bb + bc0);
        bbuf[step % 3][1] = *(const short8*)(bb + bc1);
      }
    }
  }

  short8 b2buf[3][2];
  #pragma unroll
  for (int s = 0; s < 3; s++) {
    const short* bb = Wf2 + (size_t)(s * 2 + hi) * 2048;
    b2buf[s][0] = *(const short8*)(bb + bc0);
    b2buf[s][1] = *(const short8*)(bb + bc1);
  }

  __syncthreads();
  #pragma unroll
  for (int rg = 0; rg < 2; rg++)
    #pragma unroll
    for (int ct = 0; ct < 2; ct++) {
      int col = cb + ct * 32 + l31;
      float bv = b1[col];
      #pragma unroll
      for (int reg = 0; reg < 16; reg++) {
        int row = rg * 32 + (reg & 3) + 8 * (reg >> 2) + 4 * hi;
        sA[row * 328 + col] = f2bf(fmaxf(acc[rg][ct][reg] + bv, 0.f));
      }
    }
  __syncthreads();

  floatx16 acc2[2][2];
  #pragma unroll
  for (int rg = 0; rg < 2; rg++)
    #pragma unroll
    for (int ct = 0; ct < 2; ct++)
      #pragma unroll
      for (int i = 0; i < 16; i++) acc2[rg][ct][i] = 0.f;

  {
    short8 abuf[2][2];
    abuf[0][0] = *(const short8*)(sA + arow0 + hi * 8);
    abuf[0][1] = *(const short8*)(sA + arow1 + hi * 8);
    #pragma unroll
    for (int step = 0; step < 16; step++) {
      if (step + 1 < 16) {
        abuf[(step + 1) & 1][0] = *(const short8*)(sA + arow0 + (step + 1) * 16 + hi * 8);
        abuf[(step + 1) & 1][1] = *(const short8*)(sA + arow1 + (step + 1) * 16 + hi * 8);
      }
      acc2[0][0] = __builtin_amdgcn_mfma_f32_32x32x16_bf16(abuf[step & 1][0], b2buf[step % 3][0], acc2[0][0], 0, 0, 0);
      acc2[0][1] = __builtin_amdgcn_mfma_f32_32x32x16_bf16(abuf[step & 1][0], b2buf[step % 3][1], acc2[0][1], 0, 0, 0);
      acc2[1][0] = __builtin_amdgcn_mfma_f32_32x32x16_bf16(abuf[step & 1][1], b2buf[step % 3][0], acc2[1][0], 0, 0, 0);
      acc2[1][1] = __builtin_amdgcn_mfma_f32_32x32x16_bf16(abuf[step & 1][1], b2buf[step % 3][1], acc2[1][1], 0, 0, 0);
      if (step + 3 < 16) {
        const short* bb = Wf2 + (size_t)((step + 3) * 2 + hi) * 2048;
        b2buf[step % 3][0] = *(const short8*)(bb + bc0);
        b2buf[step % 3][1] = *(const short8*)(bb + bc1);
      }
    }
  }

  __syncthreads();
  #pragma unroll
  for (int rg = 0; rg < 2; rg++)
    #pragma unroll
    for (int ct = 0; ct < 2; ct++) {
      int col = cb + ct * 32 + l31;
      float bv = b2[col];
      #pragma unroll
      for (int reg = 0; reg < 16; reg++) {
        int row = rg * 32 + (reg & 3) + 8 * (reg >> 2) + 4 * hi;
        sA[row * 264 + col] = f2bf(acc2[rg][ct][reg] + bv);
      }
    }
  __syncthreads();

  {
    int c = t;
    for (int r = 0; r < 64; ) {
      int nd = to_s[r];
      if (nd < 0) break;
      int re = rend_s[r];
      float a = 0.f;
      for (int i = r; i < re; i++)
        a += bf2f(sA[i * 264 + c]);
      float* dst = agg + (size_t)nd * 256 + c;
      if (inter_s[r]) *dst = a;
      else unsafeAtomicAdd(dst, a);
      r = re;
    }
  }
}

// ---------------- node update: bf16 MFMA; zeroes agg after consuming ----------------
__global__ __launch_bounds__(256, 4) void update_mfma(
    float* __restrict__ h, short* __restrict__ hbf, float* __restrict__ agg,
    const short* __restrict__ Wfu, const float* __restrict__ bu, int N)
{
  __shared__ short sA[32 * 392];

  int t = threadIdx.x;
  int ln = t & 63, w = t >> 6;
  int l31 = ln & 31, hi = ln >> 5;
  int n0 = blockIdx.x * 32;

  for (int i = t; i < 512; i += 256) {
    int r = i >> 4, c = i & 15;
    short8 v = {0, 0, 0, 0, 0, 0, 0, 0};
    if (n0 + r < N) v = *(const short8*)(hbf + (size_t)(n0 + r) * 128 + c * 8);
    *(short8*)(sA + r * 392 + c * 8) = v;
  }
  for (int i = t; i < 2048; i += 256) {
    int r = i >> 6, c4 = i & 63;
    int2 pk = {0, 0};
    if (n0 + r < N) {
      float4 v = *(const float4*)(agg + (size_t)(n0 + r) * 256 + c4 * 4);
      pk.x = (int)(unsigned short)f2bf(v.x) | ((int)(unsigned short)f2bf(v.y) << 16);
      pk.y = (int)(unsigned short)f2bf(v.z) | ((int)(unsigned short)f2bf(v.w) << 16);
    }
    *(int2*)(sA + r * 392 + 128 + c4 * 4) = pk;
  }
  __syncthreads();

  // agg consumed by this block's rows -> zero it for the next prop step
  {
    float4 z = {0.f, 0.f, 0.f, 0.f};
    for (int i = t; i < 2048; i += 256) {
      int r = i >> 6, c4 = i & 63;
      if (n0 + r < N)
        *(float4*)(agg + (size_t)(n0 + r) * 256 + c4 * 4) = z;
    }
  }

  const int arow = l31 * 392;
  const int bcol = (w * 32 + l31) * 8;

  floatx16 acc;
  #pragma unroll
  for (int i = 0; i < 16; i++) acc[i] = 0.f;

  {
    short8 bbuf[3];
    #pragma unroll
    for (int s = 0; s < 3; s++)
      bbuf[s] = *(const short8*)(Wfu + (size_t)(s * 2 + hi) * 1024 + bcol);
    short8 abuf[2];
    abuf[0] = *(const short8*)(sA + arow + hi * 8);
    #pragma unroll
    for (int step = 0; step < 24; step++) {
      if (step + 1 < 24)
        abuf[(step + 1) & 1] = *(const short8*)(sA + arow + (step + 1) * 16 + hi * 8);
      acc = __builtin_amdgcn_mfma_f32_32x32x16_bf16(abuf[step & 1], bbuf[step % 3], acc, 0, 0, 0);
      if (step + 3 < 24)
        bbuf[step % 3] = *(const short8*)(Wfu + (size_t)((step + 3) * 2 + hi) * 1024 + bcol);
    }
  }

  int col = w * 32 + l31;
  float bv = bu[col];
  #pragma unroll
  for (int reg = 0; reg < 16; reg++) {
    int row = (reg & 3) + 8 * (reg >> 2) + 4 * hi;
    int n = n0 + row;
    if (n < N) {
      float nv = h[(size_t)n * 128 + col] + acc[reg] + bv;
      h[(size_t)n * 128 + col] = nv;
      hbf[(size_t)n * 128 + col] = f2bf(nv);
    }
  }
}

// ---------------- scatter into padded stacks (fp32 + bf16) ----------------
__global__ void scatter_kernel(const float* __restrict__ h, const int* __restrict__ pos,
                               float* __restrict__ flat, short* __restrict__ flatb, int N)
{
  int idx = blockIdx.x * 256 + threadIdx.x;
  if (idx >= N * D) return;
  int n = idx >> 7, c = idx & 127;
  float v = h[idx];
  size_t o = (size_t)pos[n] * D + c;
  flat[o] = v;
  flatb[o] = f2bf(v);
}

// ---------------- attention features: fused 2-layer bf16 MFMA ----------------
// 64 rows/block; wave w owns cols [w*32, w*32+32), both layers K=128 (8 steps).
__global__ __launch_bounds__(256, 3) void attfeat_mfma(
    const short* __restrict__ flatb,
    const short* __restrict__ Wfa1, const float* __restrict__ ba1,
    const short* __restrict__ Wfa2, const float* __restrict__ ba2,
    const int* __restrict__ qsizes, const int* __restrict__ csizes,
    short* __restrict__ tfb)
{
  __shared__ short sA[64 * 136];   // 17408B: x, then hidden

  int t = threadIdx.x;
  int ln = t & 63, w = t >> 6;
  int l31 = ln & 31, hi = ln >> 5;
  int r0 = blockIdx.x * 64;

  for (int i = t; i < 1024; i += 256) {
    int r = i >> 4, c = i & 15;
    *(short8*)(sA + r * 136 + c * 8) =
        *(const short8*)(flatb + (size_t)(r0 + r) * 128 + c * 8);
  }
  __syncthreads();

  const int arow0 = l31 * 136, arow1 = (32 + l31) * 136;
  const int bcol = (w * 32 + l31) * 8;
  int col = w * 32 + l31;

  floatx16 acc[2];
  #pragma unroll
  for (int rg = 0; rg < 2; rg++)
    #pragma unroll
    for (int i = 0; i < 16; i++) acc[rg][i] = 0.f;

  #pragma unroll
  for (int step = 0; step < 8; step++) {
    short8 a0 = *(const short8*)(sA + arow0 + step * 16 + hi * 8);
    short8 a1 = *(const short8*)(sA + arow1 + step * 16 + hi * 8);
    short8 bfr = *(const short8*)(Wfa1 + (size_t)(step * 2 + hi) * 1024 + bcol);
    acc[0] = __builtin_amdgcn_mfma_f32_32x32x16_bf16(a0, bfr, acc[0], 0, 0, 0);
    acc[1] = __builtin_amdgcn_mfma_f32_32x32x16_bf16(a1, bfr, acc[1], 0, 0, 0);
  }

  __syncthreads();
  {
    float bv = ba1[col];
    #pragma unroll
    for (int rg = 0; rg < 2; rg++)
      #pragma unroll
      for (int reg = 0; reg < 16; reg++) {
        int row = rg * 32 + (reg & 3) + 8 * (reg >> 2) + 4 * hi;
        sA[row * 136 + col] = f2bf(fmaxf(acc[rg][reg] + bv, 0.f));
      }
  }
  __syncthreads();

  floatx16 acc2[2];
  #pragma unroll
  for (int rg = 0; rg < 2; rg++)
    #pragma unroll
    for (int i = 0; i < 16; i++) acc2[rg][i] = 0.f;

  #pragma unroll
  for (int step = 0; step < 8; step++) {
    short8 a0 = *(const short8*)(sA + arow0 + step * 16 + hi * 8);
    short8 a1 = *(const short8*)(sA + arow1 + step * 16 + hi * 8);
    short8 bfr = *(const short8*)(Wfa2 + (size_t)(step * 2 + hi) * 1024 + bcol);
    acc2[0] = __builtin_amdgcn_mfma_f32_32x32x16_bf16(a0, bfr, acc2[0], 0, 0, 0);
    acc2[1] = __builtin_amdgcn_mfma_f32_32x32x16_bf16(a1, bfr, acc2[1], 0, 0, 0);
  }

  {
    float bv = ba2[col];
    #pragma unroll
    for (int rg = 0; rg < 2; rg++)
      #pragma unroll
      for (int reg = 0; reg < 16; reg++) {
        int row = r0 + rg * 32 + (reg & 3) + 8 * (reg >> 2) + 4 * hi;
        int part = row >> 14, b = (row >> 6) & 255, pp = row & 63;
        int sz = part ? csizes[b] : qsizes[b];
        float m = (pp < sz) ? 1.f : 0.f;
        tfb[(size_t)row * 128 + col] = f2bf((acc2[rg][reg] + bv) * m);
      }
  }
}

// ---------------- per-pair attention score: MFMA logits, in-place row softmax ----------------
__global__ __launch_bounds__(256, 3) void score_kernel(
    const short* __restrict__ tfb, const float* __restrict__ flat,
    const int* __restrict__ qsizes, const int* __restrict__ csizes,
    float* __restrict__ out)
{
  __shared__ float SL[64 * 65];    // logits -> q_to_c (in place)
  __shared__ float SP2[64 * 65];   // c_to_q
  __shared__ float red[8];

  int b = blockIdx.x, t = threadIdx.x;
  int ln = t & 63, w = t >> 6;
  int l31 = ln & 31, hi = ln >> 5;
  const short* tqb = tfb + (size_t)b * 64 * 128;
  const short* tcb = tfb + ((size_t)16384 + (size_t)b * 64) * 128;
  const float* sq = flat + (size_t)b * 64 * 128;
  const float* sc = flat + ((size_t)16384 + (size_t)b * 64) * 128;
  int qs = qsizes[b], cs = csizes[b];

  // ---- logits via MFMA: wave w -> q rows (w&1)*32.., c cols (w>>1)*32..
  {
    int rowb = (w & 1) * 32, cbq = (w >> 1) * 32;
    floatx16 acc;
    #pragma unroll
    for (int i = 0; i < 16; i++) acc[i] = 0.f;
    #pragma unroll
    for (int step = 0; step < 8; step++) {
      short8 a  = *(const short8*)(tqb + (size_t)(rowb + l31) * 128 + step * 16 + hi * 8);
      short8 bf = *(const short8*)(tcb + (size_t)(cbq + l31) * 128 + step * 16 + hi * 8);
      acc = __builtin_amdgcn_mfma_f32_32x32x16_bf16(a, bf, acc, 0, 0, 0);
    }
    int ccol = cbq + l31;
    #pragma unroll
    for (int reg = 0; reg < 16; reg++) {
      int qrow = rowb + (reg & 3) + 8 * (reg >> 2) + 4 * hi;
      SL[qrow * 65 + ccol] = (qrow < qs && ccol < cs) ? acc[reg] * 10.0f : -1e9f;
    }
  }
  __syncthreads();

  // phase 1: column softmax -> SP2; row stats (no SL writes yet)
  float rmax = -1e30f, rsum = 0.f;
  if (t < 64) {
    int q = t;
    if (q < qs) {
      for (int c = 0; c < 64; c++) rmax = fmaxf(rmax, SL[q * 65 + c]);
      for (int c = 0; c < 64; c++) rsum += __expf(SL[q * 65 + c] - rmax);
    }
  } else if (t < 128) {
    int c = t - 64;
    if (c < cs) {
      float m = -1e30f;
      for (int q = 0; q < 64; q++) m = fmaxf(m, SL[q * 65 + c]);
      float s = 0.f;
      for (int q = 0; q < 64; q++) s += __expf(SL[q * 65 + c] - m);
      float inv = 1.0f / s;
      for (int q = 0; q < 64; q++) SP2[q * 65 + c] = __expf(SL[q * 65 + c] - m) * inv;
    } else {
      for (int q = 0; q < 64; q++) SP2[q * 65 + c] = 0.f;
    }
  }
  __syncthreads();

  // phase 2: row softmax in place on SL
  if (t < 64) {
    int q = t;
    if (q < qs) {
      float inv = 1.0f / rsum;
      for (int c = 0; c < 64; c++) SL[q * 65 + c] = __expf(SL[q * 65 + c] - rmax) * inv;
    } else {
      for (int c = 0; c < 64; c++) SL[q * 65 + c] = 0.f;
    }
  }
  __syncthreads();

  int qg = (t >> 4) << 2;
  int cg = (t & 15) << 2;
  int dg = (t & 15) << 3;
  (void)cg;

  float al[4][8] = {};
  for (int c = 0; c < 64; c++) {
    float p0 = SL[(qg + 0) * 65 + c];
    float p1 = SL[(qg + 1) * 65 + c];
    float p2 = SL[(qg + 2) * 65 + c];
    float p3 = SL[(qg + 3) * 65 + c];
    float4 s0 = *(const float4*)(sc + c * 128 + dg);
    float4 s1 = *(const float4*)(sc + c * 128 + dg + 4);
    al[0][0] += p0 * s0.x; al[0][1] += p0 * s0.y; al[0][2] += p0 * s0.z; al[0][3] += p0 * s0.w;
    al[0][4] += p0 * s1.x; al[0][5] += p0 * s1.y; al[0][6] += p0 * s1.z; al[0][7] += p0 * s1.w;
    al[1][0] += p1 * s0.x; al[1][1] += p1 * s0.y; al[1][2] += p1 * s0.z; al[1][3] += p1 * s0.w;
    al[1][4] += p1 * s1.x; al[1][5] += p1 * s1.y; al[1][6] += p1 * s1.z; al[1][7] += p1 * s1.w;
    al[2][0] += p2 * s0.x; al[2][1] += p2 * s0.y; al[2][2] += p2 * s0.z; al[2][3] += p2 * s0.w;
    al[2][4] += p2 * s1.x; al[2][5] += p2 * s1.y; al[2][6] += p2 * s1.z; al[2][7] += p2 * s1.w;
    al[3][0] += p3 * s0.x; al[3][1] += p3 * s0.y; al[3][2] += p3 * s0.z; al[3][3] += p3 * s0.w;
    al[3][4] += p3 * s1.x; al[3][5] += p3 * s1.y; al[3][6] += p3 * s1.z; al[3][7] += p3 * s1.w;
  }
  float qpart = 0.f;
  #pragma unroll
  for (int j = 0; j < 4; j++) {
    float4 a0 = *(const float4*)(sq + (qg + j) * 128 + dg);
    float4 a1 = *(const float4*)(sq + (qg + j) * 128 + dg + 4);
    qpart += fmaxf(a0.x - al[j][0], 0.f) + fmaxf(a0.y - al[j][1], 0.f)
           + fmaxf(a0.z - al[j][2], 0.f) + fmaxf(a0.w - al[j][3], 0.f)
           + fmaxf(a1.x - al[j][4], 0.f) + fmaxf(a1.y - al[j][5], 0.f)
           + fmaxf(a1.z - al[j][6], 0.f) + fmaxf(a1.w - al[j][7], 0.f);
  }

  float al2[4][8] = {};
  for (int q = 0; q < 64; q++) {
    float p0 = SP2[q * 65 + qg + 0];
    float p1 = SP2[q * 65 + qg + 1];
    float p2 = SP2[q * 65 + qg + 2];
    float p3 = SP2[q * 65 + qg + 3];
    float4 s0 = *(const float4*)(sq + q * 128 + dg);
    float4 s1 = *(const float4*)(sq + q * 128 + dg + 4);
    al2[0][0] += p0 * s0.x; al2[0][1] += p0 * s0.y; al2[0][2] += p0 * s0.z; al2[0][3] += p0 * s0.w;
    al2[0][4] += p0 * s1.x; al2[0][5] += p0 * s1.y; al2[0][6] += p0 * s1.z; al2[0][7] += p0 * s1.w;
    al2[1][0] += p1 * s0.x; al2[1][1] += p1 * s0.y; al2[1][2] += p1 * s0.z; al2[1][3] += p1 * s0.w;
    al2[1][4] += p1 * s1.x; al2[1][5] += p1 * s1.y; al2[1][6] += p1 * s1.z; al2[1][7] += p1 * s1.w;
    al2[2][0] += p2 * s0.x; al2[2][1] += p2 * s0.y; al2[2][2] += p2 * s0.z; al2[2][3] += p2 * s0.w;
    al2[2][4] += p2 * s1.x; al2[2][5] += p2 * s1.y; al2[2][6] += p2 * s1.z; al2[2][7] += p2 * s1.w;
    al2[3][0] += p3 * s0.x; al2[3][1] += p3 * s0.y; al2[3][2] += p3 * s0.z; al2[3][3] += p3 * s0.w;
    al2[3][4] += p3 * s1.x; al2[3][5] += p3 * s1.y; al2[3][6] += p3 * s1.z; al2[3][7] += p3 * s1.w;
  }
  float cpart = 0.f;
  #pragma unroll
  for (int j = 0; j < 4; j++) {
    float4 b0 = *(const float4*)(sc + (qg + j) * 128 + dg);
    float4 b1 = *(const float4*)(sc + (qg + j) * 128 + dg + 4);
    cpart += fmaxf(b0.x - al2[j][0], 0.f) + fmaxf(b0.y - al2[j][1], 0.f)
           + fmaxf(b0.z - al2[j][2], 0.f) + fmaxf(b0.w - al2[j][3], 0.f)
           + fmaxf(b1.x - al2[j][4], 0.f) + fmaxf(b1.y - al2[j][5], 0.f)
           + fmaxf(b1.z - al2[j][6], 0.f) + fmaxf(b1.w - al2[j][7], 0.f);
  }

  for (int off = 32; off > 0; off >>= 1) {
    qpart += __shfl_down(qpart, off);
    cpart += __shfl_down(cpart, off);
  }
  if ((t & 63) == 0) { red[w] = qpart; red[w + 4] = cpart; }
  __syncthreads();
  if (t == 0) {
    float qsum = red[0] + red[1] + red[2] + red[3];
    float csum = red[4] + red[5] + red[6] + red[7];
    out[b] = fminf(-qsum, -csum);
  }
}

// ---------------- launch ----------------
extern "C" void kernel_launch(void* const* d_in, const int* in_sizes, int n_in,
                              void* d_out, int out_size, void* d_ws, size_t ws_size,
                              hipStream_t stream)
{
  const float* nf  = (const float*)d_in[0];
  const float* ef  = (const float*)d_in[1];
  const int* from_idx = (const int*)d_in[2];
  const int* to_idx   = (const int*)d_in[3];
  const int* pos      = (const int*)d_in[4];
  const int* qsz      = (const int*)d_in[5];
  const int* csz      = (const int*)d_in[6];
  const float* W_node = (const float*)d_in[7];
  const float* b_node = (const float*)d_in[8];
  const float* W_edge = (const float*)d_in[9];
  const float* b_edge = (const float*)d_in[10];
  const float* W1 = (const float*)d_in[11];
  const float* b1 = (const float*)d_in[12];
  const float* W2 = (const float*)d_in[13];
  const float* b2 = (const float*)d_in[14];
  const float* Wu = (const float*)d_in[15];
  const float* bu = (const float*)d_in[16];
  const float* Wa1 = (const float*)d_in[17];
  const float* ba1 = (const float*)d_in[18];
  const float* Wa2 = (const float*)d_in[19];
  const float* ba2 = (const float*)d_in[20];
  float* out = (float*)d_out;

  int N = in_sizes[0] / NODE_F;
  int E = in_sizes[1] / EDGE_F;

  float* h    = (float*)d_ws;                              // N*128 f32
  float* agg  = h + (size_t)N * D;                         // N*256 f32
  short* hb   = (short*)(agg + (size_t)N * 256);           // N*128 bf16
  short* eb   = hb + (size_t)N * D;                        // E*64 bf16
  short* Wf1  = eb + (size_t)E * EDIM;                     // 81920
  short* Wf2  = Wf1 + 81920;                               // 65536
  short* Wfu  = Wf2 + 65536;                               // 49152
  short* Wfa1 = Wfu + 49152;                               // 16384
  short* Wfa2 = Wfa1 + 16384;                              // 16384
  int*   deg     = (int*)(Wfa2 + 16384);                   // N
  int*   offsets = deg + N;                                // N+1
  int*   cursor  = offsets + N + 1;                        // N
  int*   elist   = cursor + N;                             // E
  uintptr_t fb = ((uintptr_t)(elist + E) + 15) & ~(uintptr_t)15;
  float* flat  = (float*)fb;                               // 32768*128 f32
  short* flatb = (short*)(flat + (size_t)2 * B_PAIRS * MAXN * D);   // bf16
  short* tfb16 = flatb + (size_t)2 * B_PAIRS * MAXN * D;            // bf16

  // CSR build (launch-invariant indices; rebuilt every call, no static state)
  hipMemsetAsync(deg, 0, (size_t)N * sizeof(int), stream);
  hist_kernel<<<256, 256, 0, stream>>>(to_idx, deg, E);
  scan_kernel<<<1, 1024, 0, stream>>>(deg, offsets, cursor, N);
  scatter_csr<<<256, 256, 0, stream>>>(to_idx, cursor, elist, E);

  prep_w<<<896, 256, 0, stream>>>(W1, W2, Wu, Wa1, Wa2, Wf1, Wf2, Wfu, Wfa1, Wfa2);
  encode_nodes<<<(N + 1) / 2, 256, 0, stream>>>(nf, W_node, b_node, h, hb, N);
  encode_edges<<<(E + 3) / 4, 256, 0, stream>>>(ef, W_edge, b_edge, eb, E);

  hipMemsetAsync(agg, 0, (size_t)N * 256 * sizeof(float), stream);
  for (int s = 0; s < PROP_STEPS; s++) {
    msg_mfma<<<(E + 63) / 64, 256, 0, stream>>>(hb, eb, from_idx, to_idx, elist, offsets,
                                                Wf1, b1, Wf2, b2, agg, E);
    update_mfma<<<(N + 31) / 32, 256, 0, stream>>>(h, hb, agg, Wfu, bu, N);
  }

  hipMemsetAsync(flat, 0, (size_t)2 * B_PAIRS * MAXN * D * sizeof(float), stream);
  scatter_kernel<<<(N * D + 255) / 256, 256, 0, stream>>>(h, pos, flat, flatb, N);
  attfeat_mfma<<<(2 * B_PAIRS * MAXN) / 64, 256, 0, stream>>>(flatb, Wfa1, ba1, Wfa2, ba2,
                                                              qsz, csz, tfb16);
  score_kernel<<<B_PAIRS, 256, 0, stream>>>(tfb16, flat, qsz, csz, out);
}

// Round 10
// 603.251 us; speedup vs baseline: 1.7785x; 1.0306x over previous
//
#include <hip/hip_runtime.h>

#define D 128
#define EDIM 64
#define NODE_F 32
#define EDGE_F 16
#define B_PAIRS 256
#define MAXN 64
#define PROP_STEPS 3

typedef __attribute__((ext_vector_type(8))) short short8;
typedef __attribute__((ext_vector_type(16))) float floatx16;

__device__ __forceinline__ short f2bf(float x) {
  unsigned u = __float_as_uint(x);
  u = (u + 0x7fff + ((u >> 16) & 1)) >> 16;   // RNE
  return (short)u;
}

__device__ __forceinline__ float bf2f(short s) {
  return __uint_as_float(((unsigned)(unsigned short)s) << 16);
}

// ---------------- CSR build + inv init ----------------
__global__ __launch_bounds__(256) void hist_kernel(const int* __restrict__ to_idx,
                                                   int* __restrict__ deg,
                                                   int* __restrict__ inv, int E)
{
  int g = gridDim.x * 256;
  for (int e = blockIdx.x * 256 + threadIdx.x; e < E; e += g)
    atomicAdd(&deg[to_idx[e]], 1);
  for (int i = blockIdx.x * 256 + threadIdx.x; i < 2 * B_PAIRS * MAXN; i += g)
    inv[i] = -1;
}

__global__ __launch_bounds__(1024) void scan_kernel(const int* __restrict__ deg,
                                                    int* __restrict__ offsets,
                                                    int* __restrict__ cursor,
                                                    const int* __restrict__ pos,
                                                    int* __restrict__ inv, int N)
{
  __shared__ int part[1024];
  int t = threadIdx.x;
  int chunk = (N + 1023) / 1024;
  int s0 = t * chunk, s1 = min(s0 + chunk, N);
  int sum = 0;
  for (int i = s0; i < s1; i++) sum += deg[i];
  part[t] = sum;
  __syncthreads();
  for (int off = 1; off < 1024; off <<= 1) {
    int v = 0;
    if (t >= off) v = part[t - off];
    __syncthreads();
    if (t >= off) part[t] += v;
    __syncthreads();
  }
  int base = (t == 0) ? 0 : part[t - 1];
  for (int i = s0; i < s1; i++) {
    offsets[i] = base; cursor[i] = base;
    base += deg[i];
  }
  if (t == 1023) offsets[N] = part[1023];
  // pos-inverse map (after hist's inv init; stream-ordered)
  for (int i = t; i < N; i += 1024) inv[pos[i]] = i;
}

__global__ __launch_bounds__(256) void scatter_csr(const int* __restrict__ to_idx,
                                                   int* __restrict__ cursor,
                                                   int* __restrict__ elist, int E)
{
  for (int e = blockIdx.x * 256 + threadIdx.x; e < E; e += gridDim.x * 256) {
    int pos = atomicAdd(&cursor[to_idx[e]], 1);
    elist[pos] = e;
  }
}

// ---------------- fused weight prep + encoders (block-range dispatch) ----------------
__global__ __launch_bounds__(256) void prep_all(
    const float* __restrict__ W1, const float* __restrict__ W2,
    const float* __restrict__ Wu,
    const float* __restrict__ Wa1, const float* __restrict__ Wa2,
    short* __restrict__ Wf1, short* __restrict__ Wf2, short* __restrict__ Wfu,
    short* __restrict__ Wfa1, short* __restrict__ Wfa2,
    const float* __restrict__ nf, const float* __restrict__ W_node,
    const float* __restrict__ b_node, float* __restrict__ h,
    short* __restrict__ hb, int N, int nb_n,
    const float* __restrict__ ef, const float* __restrict__ W_edge,
    const float* __restrict__ b_edge, short* __restrict__ eb, int E)
{
  int bid = blockIdx.x;
  int t = threadIdx.x;
  if (bid < 896) {
    int idx = bid * 256 + t;
    if (idx < 81920) {
      int p = idx >> 13, ks = (idx >> 12) & 1, hi = (idx >> 11) & 1;
      int n = (idx >> 3) & 255, j = idx & 7;
      int k = p * 32 + ks * 16 + hi * 8 + j;
      Wf1[idx] = f2bf(W1[(size_t)k * 256 + n]);
    } else if (idx < 147456) {
      int i = idx - 81920;
      int p = i >> 13, ks = (i >> 12) & 1, hi = (i >> 11) & 1;
      int n = (i >> 3) & 255, j = i & 7;
      int k = p * 32 + ks * 16 + hi * 8 + j;
      Wf2[i] = f2bf(W2[(size_t)k * 256 + n]);
    } else if (idx < 196608) {
      int i = idx - 147456;
      int p = i >> 12, ks = (i >> 11) & 1, hi = (i >> 10) & 1;
      int n = (i >> 3) & 127, j = i & 7;
      int k = p * 32 + ks * 16 + hi * 8 + j;
      Wfu[i] = f2bf(Wu[(size_t)k * 128 + n]);
    } else if (idx < 212992) {
      int i = idx - 196608;
      int step = i >> 11, hi = (i >> 10) & 1;
      int n = (i >> 3) & 127, j = i & 7;
      int k = step * 16 + hi * 8 + j;
      Wfa1[i] = f2bf(Wa1[(size_t)k * 128 + n]);
    } else if (idx < 229376) {
      int i = idx - 212992;
      int step = i >> 11, hi = (i >> 10) & 1;
      int n = (i >> 3) & 127, j = i & 7;
      int k = step * 16 + hi * 8 + j;
      Wfa2[i] = f2bf(Wa2[(size_t)k * 128 + n]);
    }
  } else if (bid < 896 + nb_n) {
    int n = (bid - 896) * 2 + (t >> 7);
    int c = t & 127;
    if (n >= N) return;
    float acc = b_node[c];
    #pragma unroll
    for (int k = 0; k < NODE_F; k++)
      acc += nf[(size_t)n * NODE_F + k] * W_node[k * D + c];
    h[(size_t)n * D + c] = acc;
    hb[(size_t)n * D + c] = f2bf(acc);
  } else {
    int eid = (bid - 896 - nb_n) * 4 + (t >> 6);
    int c = t & 63;
    if (eid >= E) return;
    float acc = b_edge[c];
    #pragma unroll
    for (int k = 0; k < EDGE_F; k++)
      acc += ef[(size_t)eid * EDGE_F + k] * W_edge[k * EDIM + c];
    eb[(size_t)eid * EDIM + c] = f2bf(acc);
  }
}

// ---------------- message + fused CSR aggregation (ring-5 B prefetch) ----------------
__global__ __launch_bounds__(256, 3) void msg_mfma(
    const short* __restrict__ hb, const short* __restrict__ eb,
    const int* __restrict__ from_idx, const int* __restrict__ to_idx,
    const int* __restrict__ elist, const int* __restrict__ offsets,
    const short* __restrict__ Wf1, const float* __restrict__ b1,
    const short* __restrict__ Wf2, const float* __restrict__ b2,
    float* __restrict__ agg, int E)
{
  __shared__ short sA[64 * 328];
  __shared__ int from_s[64], eid_s[64], to_s[64];
  __shared__ int rend_s[64], inter_s[64];

  int t = threadIdx.x;
  int ln = t & 63, w = t >> 6;
  int l31 = ln & 31, hi = ln >> 5;
  int cb = w * 64;
  int e0 = blockIdx.x * 64;

  if (t < 64) {
    int idx = e0 + t;
    int eid = (idx < E) ? elist[idx] : 0;
    eid_s[t] = eid;
    from_s[t] = from_idx[eid];
    to_s[t] = (idx < E) ? to_idx[eid] : -1;
  }
  __syncthreads();

  if (t < 64) {
    int nd = to_s[t];
    bool head = (t == 0) || (nd != to_s[t - 1]);
    if (head && nd >= 0) {
      int re = t + 1;
      while (re < 64 && to_s[re] == nd) re++;
      rend_s[t] = re;
      inter_s[t] = (offsets[nd] == e0 + t) && (offsets[nd + 1] == e0 + re) ? 1 : 0;
    }
  }

  for (int i = t; i < 1024; i += 256) {
    int r = i >> 4, c = i & 15;
    *(short8*)(sA + r * 328 + c * 8) =
        *(const short8*)(hb + (size_t)from_s[r] * 128 + c * 8);
  }
  for (int i = t; i < 1024; i += 256) {
    int r = i >> 4, c = i & 15;
    int nd = to_s[r]; if (nd < 0) nd = 0;
    *(short8*)(sA + r * 328 + 128 + c * 8) =
        *(const short8*)(hb + (size_t)nd * 128 + c * 8);
  }
  for (int i = t; i < 512; i += 256) {
    int r = i >> 3, c = i & 7;
    *(short8*)(sA + r * 328 + 256 + c * 8) =
        *(const short8*)(eb + (size_t)eid_s[r] * 64 + c * 8);
  }
  __syncthreads();

  const int arow0 = l31 * 328;
  const int arow1 = (32 + l31) * 328;
  const int bc0 = (cb + l31) * 8;
  const int bc1 = (cb + 32 + l31) * 8;

  floatx16 acc[2][2];
  #pragma unroll
  for (int rg = 0; rg < 2; rg++)
    #pragma unroll
    for (int ct = 0; ct < 2; ct++)
      #pragma unroll
      for (int i = 0; i < 16; i++) acc[rg][ct][i] = 0.f;

  // ---- GEMM1: 20 steps, K=320, ring-5 B prefetch
  {
    short8 bbuf[5][2];
    #pragma unroll
    for (int s = 0; s < 5; s++) {
      const short* bb = Wf1 + (size_t)(s * 2 + hi) * 2048;
      bbuf[s][0] = *(const short8*)(bb + bc0);
      bbuf[s][1] = *(const short8*)(bb + bc1);
    }
    short8 abuf[2][2];
    abuf[0][0] = *(const short8*)(sA + arow0 + hi * 8);
    abuf[0][1] = *(const short8*)(sA + arow1 + hi * 8);
    #pragma unroll
    for (int step = 0; step < 20; step++) {
      if (step + 1 < 20) {
        abuf[(step + 1) & 1][0] = *(const short8*)(sA + arow0 + (step + 1) * 16 + hi * 8);
        abuf[(step + 1) & 1][1] = *(const short8*)(sA + arow1 + (step + 1) * 16 + hi * 8);
      }
      acc[0][0] = __builtin_amdgcn_mfma_f32_32x32x16_bf16(abuf[step & 1][0], bbuf[step % 5][0], acc[0][0], 0, 0, 0);
      acc[0][1] = __builtin_amdgcn_mfma_f32_32x32x16_bf16(abuf[step & 1][0], bbuf[step % 5][1], acc[0][1], 0, 0, 0);
      acc[1][0] = __builtin_amdgcn_mfma_f32_32x32x16_bf16(abuf[step & 1][1], bbuf[step % 5][0], acc[1][0], 0, 0, 0);
      acc[1][1] = __builtin_amdgcn_mfma_f32_32x32x16_bf16(abuf[step & 1][1], bbuf[step % 5][1], acc[1][1], 0, 0, 0);
      if (step + 5 < 20) {
        const short* bb = Wf1 + (size_t)((step + 5) * 2 + hi) * 2048;
        bbuf[step % 5][0] = *(const short8*)(bb + bc0);
        bbuf[step % 5][1] = *(const short8*)(bb + bc1);
      }
    }
  }

  // GEMM2 B prologue (ring-5) issued before the barrier
  short8 b2buf[5][2];
  #pragma unroll
  for (int s = 0; s < 5; s++) {
    const short* bb = Wf2 + (size_t)(s * 2 + hi) * 2048;
    b2buf[s][0] = *(const short8*)(bb + bc0);
    b2buf[s][1] = *(const short8*)(bb + bc1);
  }

  __syncthreads();
  #pragma unroll
  for (int rg = 0; rg < 2; rg++)
    #pragma unroll
    for (int ct = 0; ct < 2; ct++) {
      int col = cb + ct * 32 + l31;
      float bv = b1[col];
      #pragma unroll
      for (int reg = 0; reg < 16; reg++) {
        int row = rg * 32 + (reg & 3) + 8 * (reg >> 2) + 4 * hi;
        sA[row * 328 + col] = f2bf(fmaxf(acc[rg][ct][reg] + bv, 0.f));
      }
    }
  __syncthreads();

  floatx16 acc2[2][2];
  #pragma unroll
  for (int rg = 0; rg < 2; rg++)
    #pragma unroll
    for (int ct = 0; ct < 2; ct++)
      #pragma unroll
      for (int i = 0; i < 16; i++) acc2[rg][ct][i] = 0.f;

  {
    short8 abuf[2][2];
    abuf[0][0] = *(const short8*)(sA + arow0 + hi * 8);
    abuf[0][1] = *(const short8*)(sA + arow1 + hi * 8);
    #pragma unroll
    for (int step = 0; step < 16; step++) {
      if (step + 1 < 16) {
        abuf[(step + 1) & 1][0] = *(const short8*)(sA + arow0 + (step + 1) * 16 + hi * 8);
        abuf[(step + 1) & 1][1] = *(const short8*)(sA + arow1 + (step + 1) * 16 + hi * 8);
      }
      acc2[0][0] = __builtin_amdgcn_mfma_f32_32x32x16_bf16(abuf[step & 1][0], b2buf[step % 5][0], acc2[0][0], 0, 0, 0);
      acc2[0][1] = __builtin_amdgcn_mfma_f32_32x32x16_bf16(abuf[step & 1][0], b2buf[step % 5][1], acc2[0][1], 0, 0, 0);
      acc2[1][0] = __builtin_amdgcn_mfma_f32_32x32x16_bf16(abuf[step & 1][1], b2buf[step % 5][0], acc2[1][0], 0, 0, 0);
      acc2[1][1] = __builtin_amdgcn_mfma_f32_32x32x16_bf16(abuf[step & 1][1], b2buf[step % 5][1], acc2[1][1], 0, 0, 0);
      if (step + 5 < 16) {
        const short* bb = Wf2 + (size_t)((step + 5) * 2 + hi) * 2048;
        b2buf[step % 5][0] = *(const short8*)(bb + bc0);
        b2buf[step % 5][1] = *(const short8*)(bb + bc1);
      }
    }
  }

  __syncthreads();
  #pragma unroll
  for (int rg = 0; rg < 2; rg++)
    #pragma unroll
    for (int ct = 0; ct < 2; ct++) {
      int col = cb + ct * 32 + l31;
      float bv = b2[col];
      #pragma unroll
      for (int reg = 0; reg < 16; reg++) {
        int row = rg * 32 + (reg & 3) + 8 * (reg >> 2) + 4 * hi;
        sA[row * 264 + col] = f2bf(acc2[rg][ct][reg] + bv);
      }
    }
  __syncthreads();

  {
    int c = t;
    for (int r = 0; r < 64; ) {
      int nd = to_s[r];
      if (nd < 0) break;
      int re = rend_s[r];
      float a = 0.f;
      for (int i = r; i < re; i++)
        a += bf2f(sA[i * 264 + c]);
      float* dst = agg + (size_t)nd * 256 + c;
      if (inter_s[r]) *dst = a;
      else unsafeAtomicAdd(dst, a);
      r = re;
    }
  }
}

// ---------------- node update: bf16 MFMA; zeroes agg after consuming ----------------
__global__ __launch_bounds__(256, 4) void update_mfma(
    float* __restrict__ h, short* __restrict__ hbf, float* __restrict__ agg,
    const short* __restrict__ Wfu, const float* __restrict__ bu, int N)
{
  __shared__ short sA[32 * 392];

  int t = threadIdx.x;
  int ln = t & 63, w = t >> 6;
  int l31 = ln & 31, hi = ln >> 5;
  int n0 = blockIdx.x * 32;

  for (int i = t; i < 512; i += 256) {
    int r = i >> 4, c = i & 15;
    short8 v = {0, 0, 0, 0, 0, 0, 0, 0};
    if (n0 + r < N) v = *(const short8*)(hbf + (size_t)(n0 + r) * 128 + c * 8);
    *(short8*)(sA + r * 392 + c * 8) = v;
  }
  for (int i = t; i < 2048; i += 256) {
    int r = i >> 6, c4 = i & 63;
    int2 pk = {0, 0};
    if (n0 + r < N) {
      float4 v = *(const float4*)(agg + (size_t)(n0 + r) * 256 + c4 * 4);
      pk.x = (int)(unsigned short)f2bf(v.x) | ((int)(unsigned short)f2bf(v.y) << 16);
      pk.y = (int)(unsigned short)f2bf(v.z) | ((int)(unsigned short)f2bf(v.w) << 16);
    }
    *(int2*)(sA + r * 392 + 128 + c4 * 4) = pk;
  }
  __syncthreads();

  {
    float4 z = {0.f, 0.f, 0.f, 0.f};
    for (int i = t; i < 2048; i += 256) {
      int r = i >> 6, c4 = i & 63;
      if (n0 + r < N)
        *(float4*)(agg + (size_t)(n0 + r) * 256 + c4 * 4) = z;
    }
  }

  const int arow = l31 * 392;
  const int bcol = (w * 32 + l31) * 8;

  floatx16 acc;
  #pragma unroll
  for (int i = 0; i < 16; i++) acc[i] = 0.f;

  {
    short8 bbuf[3];
    #pragma unroll
    for (int s = 0; s < 3; s++)
      bbuf[s] = *(const short8*)(Wfu + (size_t)(s * 2 + hi) * 1024 + bcol);
    short8 abuf[2];
    abuf[0] = *(const short8*)(sA + arow + hi * 8);
    #pragma unroll
    for (int step = 0; step < 24; step++) {
      if (step + 1 < 24)
        abuf[(step + 1) & 1] = *(const short8*)(sA + arow + (step + 1) * 16 + hi * 8);
      acc = __builtin_amdgcn_mfma_f32_32x32x16_bf16(abuf[step & 1], bbuf[step % 3], acc, 0, 0, 0);
      if (step + 3 < 24)
        bbuf[step % 3] = *(const short8*)(Wfu + (size_t)((step + 3) * 2 + hi) * 1024 + bcol);
    }
  }

  int col = w * 32 + l31;
  float bv = bu[col];
  #pragma unroll
  for (int reg = 0; reg < 16; reg++) {
    int row = (reg & 3) + 8 * (reg >> 2) + 4 * hi;
    int n = n0 + row;
    if (n < N) {
      float nv = h[(size_t)n * 128 + col] + acc[reg] + bv;
      h[(size_t)n * 128 + col] = nv;
      hbf[(size_t)n * 128 + col] = f2bf(nv);
    }
  }
}

// ---------------- fused stack + attention features ----------------
// Block g covers padded rows [g*64, g*64+64). Writes flat (fp32, zeros in gaps),
// flatT (bf16 transposed [g][d][row]), and tfb (masked attention features, bf16).
__global__ __launch_bounds__(256, 3) void stack_attfeat(
    const float* __restrict__ h, const int* __restrict__ inv,
    const short* __restrict__ Wfa1, const float* __restrict__ ba1,
    const short* __restrict__ Wfa2, const float* __restrict__ ba2,
    const int* __restrict__ qsizes, const int* __restrict__ csizes,
    float* __restrict__ flat, short* __restrict__ flatT, short* __restrict__ tfb)
{
  __shared__ short sA[64 * 136];
  __shared__ int nd_s[64];

  int t = threadIdx.x;
  int ln = t & 63, w = t >> 6;
  int l31 = ln & 31, hi = ln >> 5;
  int r0 = blockIdx.x * 64;

  if (t < 64) nd_s[t] = inv[r0 + t];
  __syncthreads();

  for (int i = t; i < 1024; i += 256) {
    int r = i >> 4, c = (i & 15) * 8;
    int nd = nd_s[r];
    float4 v0 = {0.f, 0.f, 0.f, 0.f}, v1 = {0.f, 0.f, 0.f, 0.f};
    if (nd >= 0) {
      v0 = *(const float4*)(h + (size_t)nd * 128 + c);
      v1 = *(const float4*)(h + (size_t)nd * 128 + c + 4);
    }
    *(float4*)(flat + (size_t)(r0 + r) * 128 + c) = v0;
    *(float4*)(flat + (size_t)(r0 + r) * 128 + c + 4) = v1;
    short8 s;
    s[0] = f2bf(v0.x); s[1] = f2bf(v0.y); s[2] = f2bf(v0.z); s[3] = f2bf(v0.w);
    s[4] = f2bf(v1.x); s[5] = f2bf(v1.y); s[6] = f2bf(v1.z); s[7] = f2bf(v1.w);
    *(short8*)(sA + r * 136 + c) = s;
  }
  __syncthreads();

  // transposed bf16 copy for score's PV MFMAs (read-only on sA)
  for (int i = t; i < 8192; i += 256) {
    int d = i >> 6, r = i & 63;
    flatT[(size_t)blockIdx.x * 8192 + d * 64 + r] = sA[r * 136 + d];
  }

  const int arow0 = l31 * 136, arow1 = (32 + l31) * 136;
  const int bcol = (w * 32 + l31) * 8;
  int col = w * 32 + l31;

  floatx16 acc[2];
  #pragma unroll
  for (int rg = 0; rg < 2; rg++)
    #pragma unroll
    for (int i = 0; i < 16; i++) acc[rg][i] = 0.f;

  #pragma unroll
  for (int step = 0; step < 8; step++) {
    short8 a0 = *(const short8*)(sA + arow0 + step * 16 + hi * 8);
    short8 a1 = *(const short8*)(sA + arow1 + step * 16 + hi * 8);
    short8 bfr = *(const short8*)(Wfa1 + (size_t)(step * 2 + hi) * 1024 + bcol);
    acc[0] = __builtin_amdgcn_mfma_f32_32x32x16_bf16(a0, bfr, acc[0], 0, 0, 0);
    acc[1] = __builtin_amdgcn_mfma_f32_32x32x16_bf16(a1, bfr, acc[1], 0, 0, 0);
  }

  __syncthreads();
  {
    float bv = ba1[col];
    #pragma unroll
    for (int rg = 0; rg < 2; rg++)
      #pragma unroll
      for (int reg = 0; reg < 16; reg++) {
        int row = rg * 32 + (reg & 3) + 8 * (reg >> 2) + 4 * hi;
        sA[row * 136 + col] = f2bf(fmaxf(acc[rg][reg] + bv, 0.f));
      }
  }
  __syncthreads();

  floatx16 acc2[2];
  #pragma unroll
  for (int rg = 0; rg < 2; rg++)
    #pragma unroll
    for (int i = 0; i < 16; i++) acc2[rg][i] = 0.f;

  #pragma unroll
  for (int step = 0; step < 8; step++) {
    short8 a0 = *(const short8*)(sA + arow0 + step * 16 + hi * 8);
    short8 a1 = *(const short8*)(sA + arow1 + step * 16 + hi * 8);
    short8 bfr = *(const short8*)(Wfa2 + (size_t)(step * 2 + hi) * 1024 + bcol);
    acc2[0] = __builtin_amdgcn_mfma_f32_32x32x16_bf16(a0, bfr, acc2[0], 0, 0, 0);
    acc2[1] = __builtin_amdgcn_mfma_f32_32x32x16_bf16(a1, bfr, acc2[1], 0, 0, 0);
  }

  {
    float bv = ba2[col];
    #pragma unroll
    for (int rg = 0; rg < 2; rg++)
      #pragma unroll
      for (int reg = 0; reg < 16; reg++) {
        int row = r0 + rg * 32 + (reg & 3) + 8 * (reg >> 2) + 4 * hi;
        int part = row >> 14, b = (row >> 6) & 255, pp = row & 63;
        int sz = part ? csizes[b] : qsizes[b];
        float m = (pp < sz) ? 1.f : 0.f;
        tfb[(size_t)row * 128 + col] = f2bf((acc2[rg][reg] + bv) * m);
      }
  }
}

// ---------------- per-pair score: MFMA logits + MFMA PV ----------------
__global__ __launch_bounds__(256, 3) void score_kernel(
    const short* __restrict__ tfb, const float* __restrict__ flat,
    const short* __restrict__ flatT,
    const int* __restrict__ qsizes, const int* __restrict__ csizes,
    float* __restrict__ out)
{
  __shared__ float SL[64 * 65];    // logits -> q_to_c (in place)
  __shared__ float SP2[64 * 65];   // c_to_q
  __shared__ float red[8];

  int b = blockIdx.x, t = threadIdx.x;
  int ln = t & 63, w = t >> 6;
  int l31 = ln & 31, hi = ln >> 5;
  const short* tqb = tfb + (size_t)b * 8192;
  const short* tcb = tfb + (size_t)(256 + b) * 8192;
  const float* sq = flat + (size_t)b * 8192;
  const float* sc = flat + (size_t)(256 + b) * 8192;
  const short* sqT = flatT + (size_t)b * 8192;
  const short* scT = flatT + (size_t)(256 + b) * 8192;
  int qs = qsizes[b], cs = csizes[b];

  // ---- logits via MFMA
  {
    int rowb = (w & 1) * 32, cbq = (w >> 1) * 32;
    floatx16 acc;
    #pragma unroll
    for (int i = 0; i < 16; i++) acc[i] = 0.f;
    #pragma unroll
    for (int step = 0; step < 8; step++) {
      short8 a  = *(const short8*)(tqb + (size_t)(rowb + l31) * 128 + step * 16 + hi * 8);
      short8 bf = *(const short8*)(tcb + (size_t)(cbq + l31) * 128 + step * 16 + hi * 8);
      acc = __builtin_amdgcn_mfma_f32_32x32x16_bf16(a, bf, acc, 0, 0, 0);
    }
    int ccol = cbq + l31;
    #pragma unroll
    for (int reg = 0; reg < 16; reg++) {
      int qrow = rowb + (reg & 3) + 8 * (reg >> 2) + 4 * hi;
      SL[qrow * 65 + ccol] = (qrow < qs && ccol < cs) ? acc[reg] * 10.0f : -1e9f;
    }
  }
  __syncthreads();

  // phase 1: column softmax -> SP2; row stats
  float rmax = -1e30f, rsum = 0.f;
  if (t < 64) {
    int q = t;
    if (q < qs) {
      for (int c = 0; c < 64; c++) rmax = fmaxf(rmax, SL[q * 65 + c]);
      for (int c = 0; c < 64; c++) rsum += __expf(SL[q * 65 + c] - rmax);
    }
  } else if (t < 128) {
    int c = t - 64;
    if (c < cs) {
      float m = -1e30f;
      for (int q = 0; q < 64; q++) m = fmaxf(m, SL[q * 65 + c]);
      float s = 0.f;
      for (int q = 0; q < 64; q++) s += __expf(SL[q * 65 + c] - m);
      float inv = 1.0f / s;
      for (int q = 0; q < 64; q++) SP2[q * 65 + c] = __expf(SL[q * 65 + c] - m) * inv;
    } else {
      for (int q = 0; q < 64; q++) SP2[q * 65 + c] = 0.f;
    }
  }
  __syncthreads();

  // phase 2: row softmax in place on SL
  if (t < 64) {
    int q = t;
    if (q < qs) {
      float inv = 1.0f / rsum;
      for (int c = 0; c < 64; c++) SL[q * 65 + c] = __expf(SL[q * 65 + c] - rmax) * inv;
    } else {
      for (int c = 0; c < 64; c++) SL[q * 65 + c] = 0.f;
    }
  }
  __syncthreads();

  // ---- PV via MFMA: wave w owns d cols [w*32, w*32+32)
  int dcol = w * 32 + l31;
  floatx16 accq[2], accc[2];
  #pragma unroll
  for (int rt = 0; rt < 2; rt++) {
    #pragma unroll
    for (int i = 0; i < 16; i++) { accq[rt][i] = 0.f; accc[rt][i] = 0.f; }
  }

  #pragma unroll
  for (int rt = 0; rt < 2; rt++) {
    #pragma unroll
    for (int step = 0; step < 4; step++) {
      int kb = step * 16 + hi * 8;
      int row = rt * 32 + l31;
      short8 a;
      #pragma unroll
      for (int j = 0; j < 8; j++) a[j] = f2bf(SL[row * 65 + kb + j]);
      short8 bf = *(const short8*)(scT + (size_t)dcol * 64 + kb);
      accq[rt] = __builtin_amdgcn_mfma_f32_32x32x16_bf16(a, bf, accq[rt], 0, 0, 0);
    }
  }
  #pragma unroll
  for (int rt = 0; rt < 2; rt++) {
    #pragma unroll
    for (int step = 0; step < 4; step++) {
      int kb = step * 16 + hi * 8;
      int crow = rt * 32 + l31;
      short8 a;
      #pragma unroll
      for (int j = 0; j < 8; j++) a[j] = f2bf(SP2[(kb + j) * 65 + crow]);
      short8 bf = *(const short8*)(sqT + (size_t)dcol * 64 + kb);
      accc[rt] = __builtin_amdgcn_mfma_f32_32x32x16_bf16(a, bf, accc[rt], 0, 0, 0);
    }
  }

  // hinge epilogues
  float qpart = 0.f, cpart = 0.f;
  #pragma unroll
  for (int rt = 0; rt < 2; rt++) {
    #pragma unroll
    for (int reg = 0; reg < 16; reg++) {
      int row = rt * 32 + (reg & 3) + 8 * (reg >> 2) + 4 * hi;
      qpart += fmaxf(sq[(size_t)row * 128 + dcol] - accq[rt][reg], 0.f);
      cpart += fmaxf(sc[(size_t)row * 128 + dcol] - accc[rt][reg], 0.f);
    }
  }

  for (int off = 32; off > 0; off >>= 1) {
    qpart += __shfl_down(qpart, off);
    cpart += __shfl_down(cpart, off);
  }
  if ((t & 63) == 0) { red[w] = qpart; red[w + 4] = cpart; }
  __syncthreads();
  if (t == 0) {
    float qsum = red[0] + red[1] + red[2] + red[3];
    float csum = red[4] + red[5] + red[6] + red[7];
    out[b] = fminf(-qsum, -csum);
  }
}

// ---------------- launch ----------------
extern "C" void kernel_launch(void* const* d_in, const int* in_sizes, int n_in,
                              void* d_out, int out_size, void* d_ws, size_t ws_size,
                              hipStream_t stream)
{
  const float* nf  = (const float*)d_in[0];
  const float* ef  = (const float*)d_in[1];
  const int* from_idx = (const int*)d_in[2];
  const int* to_idx   = (const int*)d_in[3];
  const int* pos      = (const int*)d_in[4];
  const int* qsz      = (const int*)d_in[5];
  const int* csz      = (const int*)d_in[6];
  const float* W_node = (const float*)d_in[7];
  const float* b_node = (const float*)d_in[8];
  const float* W_edge = (const float*)d_in[9];
  const float* b_edge = (const float*)d_in[10];
  const float* W1 = (const float*)d_in[11];
  const float* b1 = (const float*)d_in[12];
  const float* W2 = (const float*)d_in[13];
  const float* b2 = (const float*)d_in[14];
  const float* Wu = (const float*)d_in[15];
  const float* bu = (const float*)d_in[16];
  const float* Wa1 = (const float*)d_in[17];
  const float* ba1 = (const float*)d_in[18];
  const float* Wa2 = (const float*)d_in[19];
  const float* ba2 = (const float*)d_in[20];
  float* out = (float*)d_out;

  int N = in_sizes[0] / NODE_F;
  int E = in_sizes[1] / EDGE_F;
  int PAD = 2 * B_PAIRS * MAXN;   // 32768

  float* h    = (float*)d_ws;                              // N*128 f32
  float* agg  = h + (size_t)N * D;                         // N*256 f32
  short* hb   = (short*)(agg + (size_t)N * 256);           // N*128 bf16
  short* eb   = hb + (size_t)N * D;                        // E*64 bf16
  short* Wf1  = eb + (size_t)E * EDIM;                     // 81920
  short* Wf2  = Wf1 + 81920;                               // 65536
  short* Wfu  = Wf2 + 65536;                               // 49152
  short* Wfa1 = Wfu + 49152;                               // 16384
  short* Wfa2 = Wfa1 + 16384;                              // 16384
  int*   deg     = (int*)(Wfa2 + 16384);                   // N
  int*   offsets = deg + N;                                // N+1
  int*   cursor  = offsets + N + 1;                        // N
  int*   elist   = cursor + N;                             // E
  int*   inv     = elist + E;                              // PAD
  uintptr_t fb = ((uintptr_t)(inv + PAD) + 15) & ~(uintptr_t)15;
  float* flat  = (float*)fb;                               // PAD*128 f32
  short* flatT = (short*)(flat + (size_t)PAD * D);         // PAD*128 bf16 (transposed per 64-block)
  short* tfb16 = flatT + (size_t)PAD * D;                  // PAD*128 bf16

  int nb_n = (N + 1) / 2, nb_e = (E + 3) / 4;

  // CSR + inv build (launch-invariant inputs; rebuilt every call)
  hipMemsetAsync(deg, 0, (size_t)N * sizeof(int), stream);
  hist_kernel<<<256, 256, 0, stream>>>(to_idx, deg, inv, E);
  scan_kernel<<<1, 1024, 0, stream>>>(deg, offsets, cursor, pos, inv, N);
  scatter_csr<<<256, 256, 0, stream>>>(to_idx, cursor, elist, E);

  prep_all<<<896 + nb_n + nb_e, 256, 0, stream>>>(
      W1, W2, Wu, Wa1, Wa2, Wf1, Wf2, Wfu, Wfa1, Wfa2,
      nf, W_node, b_node, h, hb, N, nb_n,
      ef, W_edge, b_edge, eb, E);

  hipMemsetAsync(agg, 0, (size_t)N * 256 * sizeof(float), stream);
  for (int s = 0; s < PROP_STEPS; s++) {
    msg_mfma<<<(E + 63) / 64, 256, 0, stream>>>(hb, eb, from_idx, to_idx, elist, offsets,
                                                Wf1, b1, Wf2, b2, agg, E);
    update_mfma<<<(N + 31) / 32, 256, 0, stream>>>(h, hb, agg, Wfu, bu, N);
  }

  stack_attfeat<<<PAD / 64, 256, 0, stream>>>(h, inv, Wfa1, ba1, Wfa2, ba2,
                                              qsz, csz, flat, flatT, tfb16);
  score_kernel<<<B_PAIRS, 256, 0, stream>>>(tfb16, flat, flatT, qsz, csz, out);
}

// Round 11
// 595.463 us; speedup vs baseline: 1.8018x; 1.0131x over previous
//
#include <hip/hip_runtime.h>

#define D 128
#define EDIM 64
#define NODE_F 32
#define EDGE_F 16
#define B_PAIRS 256
#define MAXN 64
#define PROP_STEPS 3

typedef __attribute__((ext_vector_type(8))) short short8;
typedef __attribute__((ext_vector_type(16))) float floatx16;

__device__ __forceinline__ short f2bf(float x) {
  unsigned u = __float_as_uint(x);
  u = (u + 0x7fff + ((u >> 16) & 1)) >> 16;   // RNE
  return (short)u;
}

__device__ __forceinline__ float bf2f(short s) {
  return __uint_as_float(((unsigned)(unsigned short)s) << 16);
}

// ---------------- CSR build + inv init ----------------
__global__ __launch_bounds__(256) void hist_kernel(const int* __restrict__ to_idx,
                                                   int* __restrict__ deg,
                                                   int* __restrict__ inv, int E)
{
  int g = gridDim.x * 256;
  for (int e = blockIdx.x * 256 + threadIdx.x; e < E; e += g)
    atomicAdd(&deg[to_idx[e]], 1);
  for (int i = blockIdx.x * 256 + threadIdx.x; i < 2 * B_PAIRS * MAXN; i += g)
    inv[i] = -1;
}

__global__ __launch_bounds__(1024) void scan_kernel(const int* __restrict__ deg,
                                                    int* __restrict__ offsets,
                                                    int* __restrict__ cursor,
                                                    const int* __restrict__ pos,
                                                    int* __restrict__ inv, int N)
{
  __shared__ int part[1024];
  int t = threadIdx.x;
  int chunk = (N + 1023) / 1024;
  int s0 = t * chunk, s1 = min(s0 + chunk, N);
  int sum = 0;
  for (int i = s0; i < s1; i++) sum += deg[i];
  part[t] = sum;
  __syncthreads();
  for (int off = 1; off < 1024; off <<= 1) {
    int v = 0;
    if (t >= off) v = part[t - off];
    __syncthreads();
    if (t >= off) part[t] += v;
    __syncthreads();
  }
  int base = (t == 0) ? 0 : part[t - 1];
  for (int i = s0; i < s1; i++) {
    offsets[i] = base; cursor[i] = base;
    base += deg[i];
  }
  if (t == 1023) offsets[N] = part[1023];
  for (int i = t; i < N; i += 1024) inv[pos[i]] = i;
}

__global__ __launch_bounds__(256) void scatter_csr(const int* __restrict__ to_idx,
                                                   int* __restrict__ cursor,
                                                   int* __restrict__ elist, int E)
{
  for (int e = blockIdx.x * 256 + threadIdx.x; e < E; e += gridDim.x * 256) {
    int pos = atomicAdd(&cursor[to_idx[e]], 1);
    elist[pos] = e;
  }
}

// ---------------- fused weight prep + encoders (block-range dispatch) ----------------
// Wf1a [k0:128]->32768, Wf1b [k128:256]->32768, Wf1e [k256:320]->16384,
// Wf2->65536, Wfu->49152, Wfa1->16384, Wfa2->16384.  All [step][hi][n][8].
__global__ __launch_bounds__(256) void prep_all(
    const float* __restrict__ W1, const float* __restrict__ W2,
    const float* __restrict__ Wu,
    const float* __restrict__ Wa1, const float* __restrict__ Wa2,
    short* __restrict__ Wf1a, short* __restrict__ Wf1b, short* __restrict__ Wf1e,
    short* __restrict__ Wf2, short* __restrict__ Wfu,
    short* __restrict__ Wfa1, short* __restrict__ Wfa2,
    const float* __restrict__ nf, const float* __restrict__ W_node,
    const float* __restrict__ b_node, float* __restrict__ h,
    short* __restrict__ hb, int N, int nb_n,
    const float* __restrict__ ef, const float* __restrict__ W_edge,
    const float* __restrict__ b_edge, short* __restrict__ eb, int E)
{
  int bid = blockIdx.x;
  int t = threadIdx.x;
  if (bid < 896) {
    int idx = bid * 256 + t;
    if (idx < 32768) {
      int step = idx >> 12, hi = (idx >> 11) & 1;
      int n = (idx >> 3) & 255, j = idx & 7;
      int k = step * 16 + hi * 8 + j;
      Wf1a[idx] = f2bf(W1[(size_t)k * 256 + n]);
    } else if (idx < 65536) {
      int i = idx - 32768;
      int step = i >> 12, hi = (i >> 11) & 1;
      int n = (i >> 3) & 255, j = i & 7;
      int k = step * 16 + hi * 8 + j;
      Wf1b[i] = f2bf(W1[(size_t)(128 + k) * 256 + n]);
    } else if (idx < 81920) {
      int i = idx - 65536;
      int step = i >> 12, hi = (i >> 11) & 1;
      int n = (i >> 3) & 255, j = i & 7;
      int k = step * 16 + hi * 8 + j;
      Wf1e[i] = f2bf(W1[(size_t)(256 + k) * 256 + n]);
    } else if (idx < 147456) {
      int i = idx - 81920;
      int step = i >> 12, hi = (i >> 11) & 1;
      int n = (i >> 3) & 255, j = i & 7;
      int k = step * 16 + hi * 8 + j;
      Wf2[i] = f2bf(W2[(size_t)k * 256 + n]);
    } else if (idx < 196608) {
      int i = idx - 147456;
      int step = i >> 11, hi = (i >> 10) & 1;
      int n = (i >> 3) & 127, j = i & 7;
      int k = step * 16 + hi * 8 + j;
      Wfu[i] = f2bf(Wu[(size_t)k * 128 + n]);
    } else if (idx < 212992) {
      int i = idx - 196608;
      int step = i >> 11, hi = (i >> 10) & 1;
      int n = (i >> 3) & 127, j = i & 7;
      int k = step * 16 + hi * 8 + j;
      Wfa1[i] = f2bf(Wa1[(size_t)k * 128 + n]);
    } else if (idx < 229376) {
      int i = idx - 212992;
      int step = i >> 11, hi = (i >> 10) & 1;
      int n = (i >> 3) & 127, j = i & 7;
      int k = step * 16 + hi * 8 + j;
      Wfa2[i] = f2bf(Wa2[(size_t)k * 128 + n]);
    }
  } else if (bid < 896 + nb_n) {
    int n = (bid - 896) * 2 + (t >> 7);
    int c = t & 127;
    if (n >= N) return;
    float acc = b_node[c];
    #pragma unroll
    for (int k = 0; k < NODE_F; k++)
      acc += nf[(size_t)n * NODE_F + k] * W_node[k * D + c];
    h[(size_t)n * D + c] = acc;
    hb[(size_t)n * D + c] = f2bf(acc);
  } else {
    int eid = (bid - 896 - nb_n) * 4 + (t >> 6);
    int c = t & 63;
    if (eid >= E) return;
    float acc = b_edge[c];
    #pragma unroll
    for (int k = 0; k < EDGE_F; k++)
      acc += ef[(size_t)eid * EDGE_F + k] * W_edge[k * EDIM + c];
    eb[(size_t)eid * EDIM + c] = f2bf(acc);
  }
}

// ---------------- Pe = e @ W1[256:320] + b1, once per launch, CSR-ordered ----------------
__global__ __launch_bounds__(256, 4) void pe_prep(
    const short* __restrict__ eb, const int* __restrict__ elist,
    const short* __restrict__ Wf1e, const float* __restrict__ b1,
    short* __restrict__ Pe, int E)
{
  __shared__ short sE[64 * 72];
  __shared__ int eid_s[64];
  int t = threadIdx.x;
  int ln = t & 63, w = t >> 6;
  int l31 = ln & 31, hi = ln >> 5;
  int cb = w * 64;
  int e0 = blockIdx.x * 64;

  if (t < 64) eid_s[t] = (e0 + t < E) ? elist[e0 + t] : 0;
  __syncthreads();
  for (int i = t; i < 512; i += 256) {
    int r = i >> 3, c = (i & 7) * 8;
    *(short8*)(sE + r * 72 + c) = *(const short8*)(eb + (size_t)eid_s[r] * 64 + c);
  }
  __syncthreads();

  const int bc0 = (cb + l31) * 8, bc1 = (cb + 32 + l31) * 8;
  floatx16 acc[2][2];
  #pragma unroll
  for (int rg = 0; rg < 2; rg++)
    #pragma unroll
    for (int ct = 0; ct < 2; ct++)
      #pragma unroll
      for (int i = 0; i < 16; i++) acc[rg][ct][i] = 0.f;

  #pragma unroll
  for (int step = 0; step < 4; step++) {
    short8 a0 = *(const short8*)(sE + l31 * 72 + step * 16 + hi * 8);
    short8 a1 = *(const short8*)(sE + (32 + l31) * 72 + step * 16 + hi * 8);
    short8 b0 = *(const short8*)(Wf1e + (size_t)(step * 2 + hi) * 2048 + bc0);
    short8 b1v = *(const short8*)(Wf1e + (size_t)(step * 2 + hi) * 2048 + bc1);
    acc[0][0] = __builtin_amdgcn_mfma_f32_32x32x16_bf16(a0, b0,  acc[0][0], 0, 0, 0);
    acc[0][1] = __builtin_amdgcn_mfma_f32_32x32x16_bf16(a0, b1v, acc[0][1], 0, 0, 0);
    acc[1][0] = __builtin_amdgcn_mfma_f32_32x32x16_bf16(a1, b0,  acc[1][0], 0, 0, 0);
    acc[1][1] = __builtin_amdgcn_mfma_f32_32x32x16_bf16(a1, b1v, acc[1][1], 0, 0, 0);
  }

  #pragma unroll
  for (int rg = 0; rg < 2; rg++)
    #pragma unroll
    for (int ct = 0; ct < 2; ct++) {
      int col = cb + ct * 32 + l31;
      float bv = b1[col];
      #pragma unroll
      for (int reg = 0; reg < 16; reg++) {
        int row = rg * 32 + (reg & 3) + 8 * (reg >> 2) + 4 * hi;
        Pe[(size_t)(e0 + row) * 256 + col] = f2bf(acc[rg][ct][reg] + bv);  // Pe padded to Epad
      }
    }
}

// ---------------- P1/P2 = h @ W1[0:128] / W1[128:256]  (node-level, bf16 out) ----------------
__global__ __launch_bounds__(256, 4) void pnode(
    const short* __restrict__ hbf,
    const short* __restrict__ Wf1a, const short* __restrict__ Wf1b,
    short* __restrict__ P1f, short* __restrict__ P2f, int N)
{
  __shared__ short sA[32 * 136];
  int t = threadIdx.x;
  int ln = t & 63, w = t >> 6;
  int l31 = ln & 31, hi = ln >> 5;
  int cb = w * 64;
  int n0 = blockIdx.x * 32;

  for (int i = t; i < 512; i += 256) {
    int r = i >> 4, c = (i & 15) * 8;
    short8 v = {0, 0, 0, 0, 0, 0, 0, 0};
    if (n0 + r < N) v = *(const short8*)(hbf + (size_t)(n0 + r) * 128 + c);
    *(short8*)(sA + r * 136 + c) = v;
  }
  __syncthreads();

  const int arow = l31 * 136;
  const int bc0 = (cb + l31) * 8, bc1 = (cb + 32 + l31) * 8;
  floatx16 acc[2][2];   // [P1/P2][col-tile]
  #pragma unroll
  for (int o = 0; o < 2; o++)
    #pragma unroll
    for (int ct = 0; ct < 2; ct++)
      #pragma unroll
      for (int i = 0; i < 16; i++) acc[o][ct][i] = 0.f;

  #pragma unroll
  for (int step = 0; step < 8; step++) {
    short8 a = *(const short8*)(sA + arow + step * 16 + hi * 8);
    short8 ba0 = *(const short8*)(Wf1a + (size_t)(step * 2 + hi) * 2048 + bc0);
    short8 ba1 = *(const short8*)(Wf1a + (size_t)(step * 2 + hi) * 2048 + bc1);
    short8 bb0 = *(const short8*)(Wf1b + (size_t)(step * 2 + hi) * 2048 + bc0);
    short8 bb1 = *(const short8*)(Wf1b + (size_t)(step * 2 + hi) * 2048 + bc1);
    acc[0][0] = __builtin_amdgcn_mfma_f32_32x32x16_bf16(a, ba0, acc[0][0], 0, 0, 0);
    acc[0][1] = __builtin_amdgcn_mfma_f32_32x32x16_bf16(a, ba1, acc[0][1], 0, 0, 0);
    acc[1][0] = __builtin_amdgcn_mfma_f32_32x32x16_bf16(a, bb0, acc[1][0], 0, 0, 0);
    acc[1][1] = __builtin_amdgcn_mfma_f32_32x32x16_bf16(a, bb1, acc[1][1], 0, 0, 0);
  }

  #pragma unroll
  for (int ct = 0; ct < 2; ct++) {
    int col = cb + ct * 32 + l31;
    #pragma unroll
    for (int reg = 0; reg < 16; reg++) {
      int row = (reg & 3) + 8 * (reg >> 2) + 4 * hi;
      int n = n0 + row;
      if (n < N) {
        P1f[(size_t)n * 256 + col] = f2bf(acc[0][ct][reg]);
        P2f[(size_t)n * 256 + col] = f2bf(acc[1][ct][reg]);
      }
    }
  }
}

// ---------------- message: gather-sum staging + GEMM2 + fused CSR aggregation ----------------
__global__ __launch_bounds__(256, 4) void msg_mfma(
    const short* __restrict__ P1f, const short* __restrict__ P2f,
    const short* __restrict__ Pe,
    const int* __restrict__ from_idx, const int* __restrict__ to_idx,
    const int* __restrict__ elist, const int* __restrict__ offsets,
    const short* __restrict__ Wf2, const float* __restrict__ b2,
    float* __restrict__ agg, int E)
{
  __shared__ short sA[64 * 264];   // hidden (K=256) then msg; 33792B
  __shared__ int from_s[64], to_s[64];
  __shared__ int rend_s[64], inter_s[64];

  int t = threadIdx.x;
  int ln = t & 63, w = t >> 6;
  int l31 = ln & 31, hi = ln >> 5;
  int cb = w * 64;
  int e0 = blockIdx.x * 64;

  if (t < 64) {
    int idx = e0 + t;
    int eid = (idx < E) ? elist[idx] : 0;
    from_s[t] = from_idx[eid];
    to_s[t] = (idx < E) ? to_idx[eid] : -1;
  }
  __syncthreads();

  if (t < 64) {
    int nd = to_s[t];
    bool head = (t == 0) || (nd != to_s[t - 1]);
    if (head && nd >= 0) {
      int re = t + 1;
      while (re < 64 && to_s[re] == nd) re++;
      rend_s[t] = re;
      inter_s[t] = (offsets[nd] == e0 + t) && (offsets[nd + 1] == e0 + re) ? 1 : 0;
    }
  }

  // hidden = relu(P1[from] + P2[to] + Pe[csr])  -> bf16 sA
  for (int i = t; i < 2048; i += 256) {
    int r = i >> 5, c8 = (i & 31) * 8;
    int nd = to_s[r]; if (nd < 0) nd = 0;
    short8 a = *(const short8*)(P1f + (size_t)from_s[r] * 256 + c8);
    short8 b = *(const short8*)(P2f + (size_t)nd * 256 + c8);
    short8 c = *(const short8*)(Pe + (size_t)(e0 + r) * 256 + c8);
    short8 o;
    #pragma unroll
    for (int j = 0; j < 8; j++)
      o[j] = f2bf(fmaxf(bf2f(a[j]) + bf2f(b[j]) + bf2f(c[j]), 0.f));
    *(short8*)(sA + r * 264 + c8) = o;
  }
  __syncthreads();

  const int arow0 = l31 * 264;
  const int arow1 = (32 + l31) * 264;
  const int bc0 = (cb + l31) * 8;
  const int bc1 = (cb + 32 + l31) * 8;

  // ---- GEMM2: 16 steps, K=256, ring-3 B prefetch
  floatx16 acc2[2][2];
  #pragma unroll
  for (int rg = 0; rg < 2; rg++)
    #pragma unroll
    for (int ct = 0; ct < 2; ct++)
      #pragma unroll
      for (int i = 0; i < 16; i++) acc2[rg][ct][i] = 0.f;

  {
    short8 b2buf[3][2];
    #pragma unroll
    for (int s = 0; s < 3; s++) {
      const short* bb = Wf2 + (size_t)(s * 2 + hi) * 2048;
      b2buf[s][0] = *(const short8*)(bb + bc0);
      b2buf[s][1] = *(const short8*)(bb + bc1);
    }
    short8 abuf[2][2];
    abuf[0][0] = *(const short8*)(sA + arow0 + hi * 8);
    abuf[0][1] = *(const short8*)(sA + arow1 + hi * 8);
    #pragma unroll
    for (int step = 0; step < 16; step++) {
      if (step + 1 < 16) {
        abuf[(step + 1) & 1][0] = *(const short8*)(sA + arow0 + (step + 1) * 16 + hi * 8);
        abuf[(step + 1) & 1][1] = *(const short8*)(sA + arow1 + (step + 1) * 16 + hi * 8);
      }
      acc2[0][0] = __builtin_amdgcn_mfma_f32_32x32x16_bf16(abuf[step & 1][0], b2buf[step % 3][0], acc2[0][0], 0, 0, 0);
      acc2[0][1] = __builtin_amdgcn_mfma_f32_32x32x16_bf16(abuf[step & 1][0], b2buf[step % 3][1], acc2[0][1], 0, 0, 0);
      acc2[1][0] = __builtin_amdgcn_mfma_f32_32x32x16_bf16(abuf[step & 1][1], b2buf[step % 3][0], acc2[1][0], 0, 0, 0);
      acc2[1][1] = __builtin_amdgcn_mfma_f32_32x32x16_bf16(abuf[step & 1][1], b2buf[step % 3][1], acc2[1][1], 0, 0, 0);
      if (step + 3 < 16) {
        const short* bb = Wf2 + (size_t)((step + 3) * 2 + hi) * 2048;
        b2buf[step % 3][0] = *(const short8*)(bb + bc0);
        b2buf[step % 3][1] = *(const short8*)(bb + bc1);
      }
    }
  }

  // msg (bf16) -> sA
  __syncthreads();
  #pragma unroll
  for (int rg = 0; rg < 2; rg++)
    #pragma unroll
    for (int ct = 0; ct < 2; ct++) {
      int col = cb + ct * 32 + l31;
      float bv = b2[col];
      #pragma unroll
      for (int reg = 0; reg < 16; reg++) {
        int row = rg * 32 + (reg & 3) + 8 * (reg >> 2) + 4 * hi;
        sA[row * 264 + col] = f2bf(acc2[rg][ct][reg] + bv);
      }
    }
  __syncthreads();

  // fused CSR reduction: thread t owns column t
  {
    int c = t;
    for (int r = 0; r < 64; ) {
      int nd = to_s[r];
      if (nd < 0) break;
      int re = rend_s[r];
      float a = 0.f;
      for (int i = r; i < re; i++)
        a += bf2f(sA[i * 264 + c]);
      float* dst = agg + (size_t)nd * 256 + c;
      if (inter_s[r]) *dst = a;
      else unsafeAtomicAdd(dst, a);
      r = re;
    }
  }
}

// ---------------- node update: bf16 MFMA; zeroes agg after consuming ----------------
__global__ __launch_bounds__(256, 4) void update_mfma(
    float* __restrict__ h, short* __restrict__ hbf, float* __restrict__ agg,
    const short* __restrict__ Wfu, const float* __restrict__ bu, int N)
{
  __shared__ short sA[32 * 392];

  int t = threadIdx.x;
  int ln = t & 63, w = t >> 6;
  int l31 = ln & 31, hi = ln >> 5;
  int n0 = blockIdx.x * 32;

  for (int i = t; i < 512; i += 256) {
    int r = i >> 4, c = i & 15;
    short8 v = {0, 0, 0, 0, 0, 0, 0, 0};
    if (n0 + r < N) v = *(const short8*)(hbf + (size_t)(n0 + r) * 128 + c * 8);
    *(short8*)(sA + r * 392 + c * 8) = v;
  }
  for (int i = t; i < 2048; i += 256) {
    int r = i >> 6, c4 = i & 63;
    int2 pk = {0, 0};
    if (n0 + r < N) {
      float4 v = *(const float4*)(agg + (size_t)(n0 + r) * 256 + c4 * 4);
      pk.x = (int)(unsigned short)f2bf(v.x) | ((int)(unsigned short)f2bf(v.y) << 16);
      pk.y = (int)(unsigned short)f2bf(v.z) | ((int)(unsigned short)f2bf(v.w) << 16);
    }
    *(int2*)(sA + r * 392 + 128 + c4 * 4) = pk;
  }
  __syncthreads();

  {
    float4 z = {0.f, 0.f, 0.f, 0.f};
    for (int i = t; i < 2048; i += 256) {
      int r = i >> 6, c4 = i & 63;
      if (n0 + r < N)
        *(float4*)(agg + (size_t)(n0 + r) * 256 + c4 * 4) = z;
    }
  }

  const int arow = l31 * 392;
  const int bcol = (w * 32 + l31) * 8;

  floatx16 acc;
  #pragma unroll
  for (int i = 0; i < 16; i++) acc[i] = 0.f;

  {
    short8 bbuf[3];
    #pragma unroll
    for (int s = 0; s < 3; s++)
      bbuf[s] = *(const short8*)(Wfu + (size_t)(s * 2 + hi) * 1024 + bcol);
    short8 abuf[2];
    abuf[0] = *(const short8*)(sA + arow + hi * 8);
    #pragma unroll
    for (int step = 0; step < 24; step++) {
      if (step + 1 < 24)
        abuf[(step + 1) & 1] = *(const short8*)(sA + arow + (step + 1) * 16 + hi * 8);
      acc = __builtin_amdgcn_mfma_f32_32x32x16_bf16(abuf[step & 1], bbuf[step % 3], acc, 0, 0, 0);
      if (step + 3 < 24)
        bbuf[step % 3] = *(const short8*)(Wfu + (size_t)((step + 3) * 2 + hi) * 1024 + bcol);
    }
  }

  int col = w * 32 + l31;
  float bv = bu[col];
  #pragma unroll
  for (int reg = 0; reg < 16; reg++) {
    int row = (reg & 3) + 8 * (reg >> 2) + 4 * hi;
    int n = n0 + row;
    if (n < N) {
      float nv = h[(size_t)n * 128 + col] + acc[reg] + bv;
      h[(size_t)n * 128 + col] = nv;
      hbf[(size_t)n * 128 + col] = f2bf(nv);
    }
  }
}

// ---------------- fused stack + attention features ----------------
__global__ __launch_bounds__(256, 3) void stack_attfeat(
    const float* __restrict__ h, const int* __restrict__ inv,
    const short* __restrict__ Wfa1, const float* __restrict__ ba1,
    const short* __restrict__ Wfa2, const float* __restrict__ ba2,
    const int* __restrict__ qsizes, const int* __restrict__ csizes,
    float* __restrict__ flat, short* __restrict__ flatT, short* __restrict__ tfb)
{
  __shared__ short sA[64 * 136];
  __shared__ int nd_s[64];

  int t = threadIdx.x;
  int ln = t & 63, w = t >> 6;
  int l31 = ln & 31, hi = ln >> 5;
  int r0 = blockIdx.x * 64;

  if (t < 64) nd_s[t] = inv[r0 + t];
  __syncthreads();

  for (int i = t; i < 1024; i += 256) {
    int r = i >> 4, c = (i & 15) * 8;
    int nd = nd_s[r];
    float4 v0 = {0.f, 0.f, 0.f, 0.f}, v1 = {0.f, 0.f, 0.f, 0.f};
    if (nd >= 0) {
      v0 = *(const float4*)(h + (size_t)nd * 128 + c);
      v1 = *(const float4*)(h + (size_t)nd * 128 + c + 4);
    }
    *(float4*)(flat + (size_t)(r0 + r) * 128 + c) = v0;
    *(float4*)(flat + (size_t)(r0 + r) * 128 + c + 4) = v1;
    short8 s;
    s[0] = f2bf(v0.x); s[1] = f2bf(v0.y); s[2] = f2bf(v0.z); s[3] = f2bf(v0.w);
    s[4] = f2bf(v1.x); s[5] = f2bf(v1.y); s[6] = f2bf(v1.z); s[7] = f2bf(v1.w);
    *(short8*)(sA + r * 136 + c) = s;
  }
  __syncthreads();

  for (int i = t; i < 8192; i += 256) {
    int d = i >> 6, r = i & 63;
    flatT[(size_t)blockIdx.x * 8192 + d * 64 + r] = sA[r * 136 + d];
  }

  const int arow0 = l31 * 136, arow1 = (32 + l31) * 136;
  const int bcol = (w * 32 + l31) * 8;
  int col = w * 32 + l31;

  floatx16 acc[2];
  #pragma unroll
  for (int rg = 0; rg < 2; rg++)
    #pragma unroll
    for (int i = 0; i < 16; i++) acc[rg][i] = 0.f;

  #pragma unroll
  for (int step = 0; step < 8; step++) {
    short8 a0 = *(const short8*)(sA + arow0 + step * 16 + hi * 8);
    short8 a1 = *(const short8*)(sA + arow1 + step * 16 + hi * 8);
    short8 bfr = *(const short8*)(Wfa1 + (size_t)(step * 2 + hi) * 1024 + bcol);
    acc[0] = __builtin_amdgcn_mfma_f32_32x32x16_bf16(a0, bfr, acc[0], 0, 0, 0);
    acc[1] = __builtin_amdgcn_mfma_f32_32x32x16_bf16(a1, bfr, acc[1], 0, 0, 0);
  }

  __syncthreads();
  {
    float bv = ba1[col];
    #pragma unroll
    for (int rg = 0; rg < 2; rg++)
      #pragma unroll
      for (int reg = 0; reg < 16; reg++) {
        int row = rg * 32 + (reg & 3) + 8 * (reg >> 2) + 4 * hi;
        sA[row * 136 + col] = f2bf(fmaxf(acc[rg][reg] + bv, 0.f));
      }
  }
  __syncthreads();

  floatx16 acc2[2];
  #pragma unroll
  for (int rg = 0; rg < 2; rg++)
    #pragma unroll
    for (int i = 0; i < 16; i++) acc2[rg][i] = 0.f;

  #pragma unroll
  for (int step = 0; step < 8; step++) {
    short8 a0 = *(const short8*)(sA + arow0 + step * 16 + hi * 8);
    short8 a1 = *(const short8*)(sA + arow1 + step * 16 + hi * 8);
    short8 bfr = *(const short8*)(Wfa2 + (size_t)(step * 2 + hi) * 1024 + bcol);
    acc2[0] = __builtin_amdgcn_mfma_f32_32x32x16_bf16(a0, bfr, acc2[0], 0, 0, 0);
    acc2[1] = __builtin_amdgcn_mfma_f32_32x32x16_bf16(a1, bfr, acc2[1], 0, 0, 0);
  }

  {
    float bv = ba2[col];
    #pragma unroll
    for (int rg = 0; rg < 2; rg++)
      #pragma unroll
      for (int reg = 0; reg < 16; reg++) {
        int row = r0 + rg * 32 + (reg & 3) + 8 * (reg >> 2) + 4 * hi;
        int part = row >> 14, b = (row >> 6) & 255, pp = row & 63;
        int sz = part ? csizes[b] : qsizes[b];
        float m = (pp < sz) ? 1.f : 0.f;
        tfb[(size_t)row * 128 + col] = f2bf((acc2[rg][reg] + bv) * m);
      }
  }
}

// ---------------- per-pair score: MFMA logits + MFMA PV ----------------
__global__ __launch_bounds__(256, 3) void score_kernel(
    const short* __restrict__ tfb, const float* __restrict__ flat,
    const short* __restrict__ flatT,
    const int* __restrict__ qsizes, const int* __restrict__ csizes,
    float* __restrict__ out)
{
  __shared__ float SL[64 * 65];
  __shared__ float SP2[64 * 65];
  __shared__ float red[8];

  int b = blockIdx.x, t = threadIdx.x;
  int ln = t & 63, w = t >> 6;
  int l31 = ln & 31, hi = ln >> 5;
  const short* tqb = tfb + (size_t)b * 8192;
  const short* tcb = tfb + (size_t)(256 + b) * 8192;
  const float* sq = flat + (size_t)b * 8192;
  const float* sc = flat + (size_t)(256 + b) * 8192;
  const short* sqT = flatT + (size_t)b * 8192;
  const short* scT = flatT + (size_t)(256 + b) * 8192;
  int qs = qsizes[b], cs = csizes[b];

  {
    int rowb = (w & 1) * 32, cbq = (w >> 1) * 32;
    floatx16 acc;
    #pragma unroll
    for (int i = 0; i < 16; i++) acc[i] = 0.f;
    #pragma unroll
    for (int step = 0; step < 8; step++) {
      short8 a  = *(const short8*)(tqb + (size_t)(rowb + l31) * 128 + step * 16 + hi * 8);
      short8 bf = *(const short8*)(tcb + (size_t)(cbq + l31) * 128 + step * 16 + hi * 8);
      acc = __builtin_amdgcn_mfma_f32_32x32x16_bf16(a, bf, acc, 0, 0, 0);
    }
    int ccol = cbq + l31;
    #pragma unroll
    for (int reg = 0; reg < 16; reg++) {
      int qrow = rowb + (reg & 3) + 8 * (reg >> 2) + 4 * hi;
      SL[qrow * 65 + ccol] = (qrow < qs && ccol < cs) ? acc[reg] * 10.0f : -1e9f;
    }
  }
  __syncthreads();

  float rmax = -1e30f, rsum = 0.f;
  if (t < 64) {
    int q = t;
    if (q < qs) {
      for (int c = 0; c < 64; c++) rmax = fmaxf(rmax, SL[q * 65 + c]);
      for (int c = 0; c < 64; c++) rsum += __expf(SL[q * 65 + c] - rmax);
    }
  } else if (t < 128) {
    int c = t - 64;
    if (c < cs) {
      float m = -1e30f;
      for (int q = 0; q < 64; q++) m = fmaxf(m, SL[q * 65 + c]);
      float s = 0.f;
      for (int q = 0; q < 64; q++) s += __expf(SL[q * 65 + c] - m);
      float inv = 1.0f / s;
      for (int q = 0; q < 64; q++) SP2[q * 65 + c] = __expf(SL[q * 65 + c] - m) * inv;
    } else {
      for (int q = 0; q < 64; q++) SP2[q * 65 + c] = 0.f;
    }
  }
  __syncthreads();

  if (t < 64) {
    int q = t;
    if (q < qs) {
      float inv = 1.0f / rsum;
      for (int c = 0; c < 64; c++) SL[q * 65 + c] = __expf(SL[q * 65 + c] - rmax) * inv;
    } else {
      for (int c = 0; c < 64; c++) SL[q * 65 + c] = 0.f;
    }
  }
  __syncthreads();

  int dcol = w * 32 + l31;
  floatx16 accq[2], accc[2];
  #pragma unroll
  for (int rt = 0; rt < 2; rt++) {
    #pragma unroll
    for (int i = 0; i < 16; i++) { accq[rt][i] = 0.f; accc[rt][i] = 0.f; }
  }

  #pragma unroll
  for (int rt = 0; rt < 2; rt++) {
    #pragma unroll
    for (int step = 0; step < 4; step++) {
      int kb = step * 16 + hi * 8;
      int row = rt * 32 + l31;
      short8 a;
      #pragma unroll
      for (int j = 0; j < 8; j++) a[j] = f2bf(SL[row * 65 + kb + j]);
      short8 bf = *(const short8*)(scT + (size_t)dcol * 64 + kb);
      accq[rt] = __builtin_amdgcn_mfma_f32_32x32x16_bf16(a, bf, accq[rt], 0, 0, 0);
    }
  }
  #pragma unroll
  for (int rt = 0; rt < 2; rt++) {
    #pragma unroll
    for (int step = 0; step < 4; step++) {
      int kb = step * 16 + hi * 8;
      int crow = rt * 32 + l31;
      short8 a;
      #pragma unroll
      for (int j = 0; j < 8; j++) a[j] = f2bf(SP2[(kb + j) * 65 + crow]);
      short8 bf = *(const short8*)(sqT + (size_t)dcol * 64 + kb);
      accc[rt] = __builtin_amdgcn_mfma_f32_32x32x16_bf16(a, bf, accc[rt], 0, 0, 0);
    }
  }

  float qpart = 0.f, cpart = 0.f;
  #pragma unroll
  for (int rt = 0; rt < 2; rt++) {
    #pragma unroll
    for (int reg = 0; reg < 16; reg++) {
      int row = rt * 32 + (reg & 3) + 8 * (reg >> 2) + 4 * hi;
      qpart += fmaxf(sq[(size_t)row * 128 + dcol] - accq[rt][reg], 0.f);
      cpart += fmaxf(sc[(size_t)row * 128 + dcol] - accc[rt][reg], 0.f);
    }
  }

  for (int off = 32; off > 0; off >>= 1) {
    qpart += __shfl_down(qpart, off);
    cpart += __shfl_down(cpart, off);
  }
  if ((t & 63) == 0) { red[w] = qpart; red[w + 4] = cpart; }
  __syncthreads();
  if (t == 0) {
    float qsum = red[0] + red[1] + red[2] + red[3];
    float csum = red[4] + red[5] + red[6] + red[7];
    out[b] = fminf(-qsum, -csum);
  }
}

// ---------------- launch ----------------
extern "C" void kernel_launch(void* const* d_in, const int* in_sizes, int n_in,
                              void* d_out, int out_size, void* d_ws, size_t ws_size,
                              hipStream_t stream)
{
  const float* nf  = (const float*)d_in[0];
  const float* ef  = (const float*)d_in[1];
  const int* from_idx = (const int*)d_in[2];
  const int* to_idx   = (const int*)d_in[3];
  const int* pos      = (const int*)d_in[4];
  const int* qsz      = (const int*)d_in[5];
  const int* csz      = (const int*)d_in[6];
  const float* W_node = (const float*)d_in[7];
  const float* b_node = (const float*)d_in[8];
  const float* W_edge = (const float*)d_in[9];
  const float* b_edge = (const float*)d_in[10];
  const float* W1 = (const float*)d_in[11];
  const float* b1 = (const float*)d_in[12];
  const float* W2 = (const float*)d_in[13];
  const float* b2 = (const float*)d_in[14];
  const float* Wu = (const float*)d_in[15];
  const float* bu = (const float*)d_in[16];
  const float* Wa1 = (const float*)d_in[17];
  const float* ba1 = (const float*)d_in[18];
  const float* Wa2 = (const float*)d_in[19];
  const float* ba2 = (const float*)d_in[20];
  float* out = (float*)d_out;

  int N = in_sizes[0] / NODE_F;
  int E = in_sizes[1] / EDGE_F;
  int Epad = (E + 63) & ~63;
  int PAD = 2 * B_PAIRS * MAXN;   // 32768

  float* h    = (float*)d_ws;                              // N*128 f32
  float* agg  = h + (size_t)N * D;                         // N*256 f32
  short* hb   = (short*)(agg + (size_t)N * 256);           // N*128 bf16
  short* eb   = hb + (size_t)N * D;                        // E*64 bf16
  // P1f/P2f alias eb (dead after pe_prep) when it fits, else live past weights.
  short* Wf1a = eb + (size_t)E * EDIM;                     // 32768
  short* Wf1b = Wf1a + 32768;                              // 32768
  short* Wf1e = Wf1b + 32768;                              // 16384
  short* Wf2  = Wf1e + 16384;                              // 65536
  short* Wfu  = Wf2 + 65536;                               // 49152
  short* Wfa1 = Wfu + 49152;                               // 16384
  short* Wfa2 = Wfa1 + 16384;                              // 16384
  int*   deg     = (int*)(Wfa2 + 16384);                   // N
  int*   offsets = deg + N;                                // N+1
  int*   cursor  = offsets + N + 1;                        // N
  int*   elist   = cursor + N;                             // E
  int*   inv     = elist + E;                              // PAD
  uintptr_t pb = ((uintptr_t)(inv + PAD) + 15) & ~(uintptr_t)15;
  short* Pe = (short*)pb;                                  // Epad*256 bf16 (CSR order)
  short* P1f, *P2f;
  short* tail = Pe + (size_t)Epad * 256;
  if ((size_t)E * EDIM >= (size_t)N * 512) { P1f = eb; P2f = P1f + (size_t)N * 256; }
  else { P1f = tail; P2f = P1f + (size_t)N * 256; tail = P2f + (size_t)N * 256; }
  // flat group aliases Pe (Pe dead after prop loop; 33.6MB <= Pe size)
  float* flat  = (float*)Pe;
  short* flatT = (short*)(flat + (size_t)PAD * D);
  short* tfb16 = flatT + (size_t)PAD * D;

  int nb_n = (N + 1) / 2, nb_e = (E + 3) / 4;

  hipMemsetAsync(deg, 0, (size_t)N * sizeof(int), stream);
  hist_kernel<<<256, 256, 0, stream>>>(to_idx, deg, inv, E);
  scan_kernel<<<1, 1024, 0, stream>>>(deg, offsets, cursor, pos, inv, N);
  scatter_csr<<<256, 256, 0, stream>>>(to_idx, cursor, elist, E);

  prep_all<<<896 + nb_n + nb_e, 256, 0, stream>>>(
      W1, W2, Wu, Wa1, Wa2, Wf1a, Wf1b, Wf1e, Wf2, Wfu, Wfa1, Wfa2,
      nf, W_node, b_node, h, hb, N, nb_n,
      ef, W_edge, b_edge, eb, E);

  pe_prep<<<Epad / 64, 256, 0, stream>>>(eb, elist, Wf1e, b1, Pe, E);

  hipMemsetAsync(agg, 0, (size_t)N * 256 * sizeof(float), stream);
  pnode<<<(N + 31) / 32, 256, 0, stream>>>(hb, Wf1a, Wf1b, P1f, P2f, N);

  for (int s = 0; s < PROP_STEPS; s++) {
    msg_mfma<<<Epad / 64, 256, 0, stream>>>(P1f, P2f, Pe, from_idx, to_idx, elist, offsets,
                                            Wf2, b2, agg, E);
    update_mfma<<<(N + 31) / 32, 256, 0, stream>>>(h, hb, agg, Wfu, bu, N);
    if (s + 1 < PROP_STEPS)
      pnode<<<(N + 31) / 32, 256, 0, stream>>>(hb, Wf1a, Wf1b, P1f, P2f, N);
  }

  stack_attfeat<<<PAD / 64, 256, 0, stream>>>(h, inv, Wfa1, ba1, Wfa2, ba2,
                                              qsz, csz, flat, flatT, tfb16);
  score_kernel<<<B_PAIRS, 256, 0, stream>>>(tfb16, flat, flatT, qsz, csz, out);
}

// Round 12
// 523.965 us; speedup vs baseline: 2.0476x; 1.1365x over previous
//
#include <hip/hip_runtime.h>

#define D 128
#define EDIM 64
#define NODE_F 32
#define EDGE_F 16
#define B_PAIRS 256
#define MAXN 64
#define PROP_STEPS 3

typedef __attribute__((ext_vector_type(4))) short short4v;
typedef __attribute__((ext_vector_type(8))) short short8;
typedef __attribute__((ext_vector_type(16))) float floatx16;

__device__ __forceinline__ short f2bf(float x) {
  unsigned u = __float_as_uint(x);
  u = (u + 0x7fff + ((u >> 16) & 1)) >> 16;   // RNE
  return (short)u;
}

__device__ __forceinline__ float bf2f(short s) {
  return __uint_as_float(((unsigned)(unsigned short)s) << 16);
}

// ---------------- CSR build + inv init ----------------
__global__ __launch_bounds__(256) void hist_kernel(const int* __restrict__ to_idx,
                                                   int* __restrict__ deg,
                                                   int* __restrict__ inv, int E)
{
  int g = gridDim.x * 256;
  for (int e = blockIdx.x * 256 + threadIdx.x; e < E; e += g)
    atomicAdd(&deg[to_idx[e]], 1);
  for (int i = blockIdx.x * 256 + threadIdx.x; i < 2 * B_PAIRS * MAXN; i += g)
    inv[i] = -1;
}

__global__ __launch_bounds__(1024) void scan_kernel(const int* __restrict__ deg,
                                                    int* __restrict__ offsets,
                                                    int* __restrict__ cursor,
                                                    const int* __restrict__ pos,
                                                    int* __restrict__ inv, int N)
{
  __shared__ int part[1024];
  int t = threadIdx.x;
  int chunk = (N + 1023) / 1024;
  int s0 = t * chunk, s1 = min(s0 + chunk, N);
  int sum = 0;
  for (int i = s0; i < s1; i++) sum += deg[i];
  part[t] = sum;
  __syncthreads();
  for (int off = 1; off < 1024; off <<= 1) {
    int v = 0;
    if (t >= off) v = part[t - off];
    __syncthreads();
    if (t >= off) part[t] += v;
    __syncthreads();
  }
  int base = (t == 0) ? 0 : part[t - 1];
  for (int i = s0; i < s1; i++) {
    offsets[i] = base; cursor[i] = base;
    base += deg[i];
  }
  if (t == 1023) offsets[N] = part[1023];
  for (int i = t; i < N; i += 1024) inv[pos[i]] = i;
}

__global__ __launch_bounds__(256) void scatter_csr(const int* __restrict__ to_idx,
                                                   int* __restrict__ cursor,
                                                   int* __restrict__ elist, int E)
{
  for (int e = blockIdx.x * 256 + threadIdx.x; e < E; e += gridDim.x * 256) {
    int pos = atomicAdd(&cursor[to_idx[e]], 1);
    elist[pos] = e;
  }
}

// ---------------- weight prep: fragment-order layouts only ----------------
// Wfn 4096 | Wfe 1024 | Wf1a 32768 | Wf1b 32768 | Wf1e 16384 | Wf2 65536 |
// Wfu 49152 | Wfa1 16384 | Wfa2 16384.  Total 234496 -> 916 blocks.
__global__ __launch_bounds__(256) void prep_w(
    const float* __restrict__ W_node, const float* __restrict__ W_edge,
    const float* __restrict__ W1, const float* __restrict__ W2,
    const float* __restrict__ Wu,
    const float* __restrict__ Wa1, const float* __restrict__ Wa2,
    short* __restrict__ Wfn, short* __restrict__ Wfe,
    short* __restrict__ Wf1a, short* __restrict__ Wf1b, short* __restrict__ Wf1e,
    short* __restrict__ Wf2, short* __restrict__ Wfu,
    short* __restrict__ Wfa1, short* __restrict__ Wfa2)
{
  int idx = blockIdx.x * 256 + threadIdx.x;
  if (idx < 4096) {
    int step = idx >> 11, hi = (idx >> 10) & 1;
    int n = (idx >> 3) & 127, j = idx & 7;
    int k = step * 16 + hi * 8 + j;
    Wfn[idx] = f2bf(W_node[(size_t)k * 128 + n]);
  } else if (idx < 5120) {
    int i = idx - 4096;
    int hi = (i >> 9) & 1, n = (i >> 3) & 63, j = i & 7;
    int k = hi * 8 + j;
    Wfe[i] = f2bf(W_edge[(size_t)k * 64 + n]);
  } else if (idx < 37888) {
    int i = idx - 5120;
    int step = i >> 12, hi = (i >> 11) & 1;
    int n = (i >> 3) & 255, j = i & 7;
    int k = step * 16 + hi * 8 + j;
    Wf1a[i] = f2bf(W1[(size_t)k * 256 + n]);
  } else if (idx < 70656) {
    int i = idx - 37888;
    int step = i >> 12, hi = (i >> 11) & 1;
    int n = (i >> 3) & 255, j = i & 7;
    int k = step * 16 + hi * 8 + j;
    Wf1b[i] = f2bf(W1[(size_t)(128 + k) * 256 + n]);
  } else if (idx < 87040) {
    int i = idx - 70656;
    int step = i >> 12, hi = (i >> 11) & 1;
    int n = (i >> 3) & 255, j = i & 7;
    int k = step * 16 + hi * 8 + j;
    Wf1e[i] = f2bf(W1[(size_t)(256 + k) * 256 + n]);
  } else if (idx < 152576) {
    int i = idx - 87040;
    int step = i >> 12, hi = (i >> 11) & 1;
    int n = (i >> 3) & 255, j = i & 7;
    int k = step * 16 + hi * 8 + j;
    Wf2[i] = f2bf(W2[(size_t)k * 256 + n]);
  } else if (idx < 201728) {
    int i = idx - 152576;
    int step = i >> 11, hi = (i >> 10) & 1;
    int n = (i >> 3) & 127, j = i & 7;
    int k = step * 16 + hi * 8 + j;
    Wfu[i] = f2bf(Wu[(size_t)k * 128 + n]);
  } else if (idx < 218112) {
    int i = idx - 201728;
    int step = i >> 11, hi = (i >> 10) & 1;
    int n = (i >> 3) & 127, j = i & 7;
    int k = step * 16 + hi * 8 + j;
    Wfa1[i] = f2bf(Wa1[(size_t)k * 128 + n]);
  } else if (idx < 234496) {
    int i = idx - 218112;
    int step = i >> 11, hi = (i >> 10) & 1;
    int n = (i >> 3) & 127, j = i & 7;
    int k = step * 16 + hi * 8 + j;
    Wfa2[i] = f2bf(Wa2[(size_t)k * 128 + n]);
  }
}

// ---------------- node encoder: h = nf @ W_node + b_node (MFMA, K=32) ----------------
__global__ __launch_bounds__(256, 4) void enc_nodes(
    const float* __restrict__ nf, const short* __restrict__ Wfn,
    const float* __restrict__ b_node, float* __restrict__ h,
    short* __restrict__ hb, int N)
{
  __shared__ short sN[32 * 40];   // 32 nodes x 32 k, stride 40
  int t = threadIdx.x;
  int ln = t & 63, w = t >> 6;
  int l31 = ln & 31, hi = ln >> 5;
  int n0 = blockIdx.x * 32;

  {
    int r = t >> 3, q = t & 7;     // 32 rows x 8 float4s
    float4 v = {0.f, 0.f, 0.f, 0.f};
    if (n0 + r < N) v = *(const float4*)(nf + (size_t)(n0 + r) * 32 + q * 4);
    short4v s;
    s[0] = f2bf(v.x); s[1] = f2bf(v.y); s[2] = f2bf(v.z); s[3] = f2bf(v.w);
    *(short4v*)(sN + r * 40 + q * 4) = s;
  }
  __syncthreads();

  int col = w * 32 + l31;
  floatx16 acc;
  #pragma unroll
  for (int i = 0; i < 16; i++) acc[i] = 0.f;

  #pragma unroll
  for (int step = 0; step < 2; step++) {
    short8 a = *(const short8*)(sN + l31 * 40 + step * 16 + hi * 8);
    short8 b = *(const short8*)(Wfn + (size_t)(step * 2 + hi) * 1024 + col * 8);
    acc = __builtin_amdgcn_mfma_f32_32x32x16_bf16(a, b, acc, 0, 0, 0);
  }

  float bv = b_node[col];
  #pragma unroll
  for (int reg = 0; reg < 16; reg++) {
    int row = (reg & 3) + 8 * (reg >> 2) + 4 * hi;
    int n = n0 + row;
    if (n < N) {
      float v = acc[reg] + bv;
      h[(size_t)n * 128 + col] = v;
      hb[(size_t)n * 128 + col] = f2bf(v);
    }
  }
}

// ---------------- fused edge encoder + Pe: ef -> e (LDS) -> Pe = e@W1e + b1 ----------------
// CSR-ordered: block covers elist[e0..e0+64). MFMA1: K=16 (1 step). MFMA2: K=64 (4 steps).
__global__ __launch_bounds__(256, 4) void pe_fused(
    const float* __restrict__ ef, const int* __restrict__ elist,
    const short* __restrict__ Wfe, const float* __restrict__ b_edge,
    const short* __restrict__ Wf1e, const float* __restrict__ b1,
    short* __restrict__ Pe, int E)
{
  __shared__ short sE[64 * 24];   // ef bf16 (16 + pad)
  __shared__ short sF[64 * 72];   // encoded e (64 + pad)
  __shared__ int eid_s[64];

  int t = threadIdx.x;
  int ln = t & 63, w = t >> 6;
  int l31 = ln & 31, hi = ln >> 5;
  int e0 = blockIdx.x * 64;

  if (t < 64) eid_s[t] = (e0 + t < E) ? elist[e0 + t] : 0;
  __syncthreads();

  {
    int r = t >> 2, q = t & 3;     // 64 rows x 4 float4s
    float4 v = *(const float4*)(ef + (size_t)eid_s[r] * 16 + q * 4);
    short4v s;
    s[0] = f2bf(v.x); s[1] = f2bf(v.y); s[2] = f2bf(v.z); s[3] = f2bf(v.w);
    *(short4v*)(sE + r * 24 + q * 4) = s;
  }
  __syncthreads();

  // MFMA1: e[64][64]; wave w: rows (w&1)*32, cols (w>>1)*32; single K=16 step
  {
    int rowb = (w & 1) * 32, cbq = (w >> 1) * 32;
    floatx16 acc;
    #pragma unroll
    for (int i = 0; i < 16; i++) acc[i] = 0.f;
    short8 a = *(const short8*)(sE + (rowb + l31) * 24 + hi * 8);
    short8 b = *(const short8*)(Wfe + (size_t)hi * 512 + (cbq + l31) * 8);
    acc = __builtin_amdgcn_mfma_f32_32x32x16_bf16(a, b, acc, 0, 0, 0);
    int col = cbq + l31;
    float bv = b_edge[col];
    #pragma unroll
    for (int reg = 0; reg < 16; reg++) {
      int row = rowb + (reg & 3) + 8 * (reg >> 2) + 4 * hi;
      sF[row * 72 + col] = f2bf(acc[reg] + bv);
    }
  }
  __syncthreads();

  // MFMA2: Pe[64][256]; wave w: col tile w*64, K=64 (4 steps)
  const int cb = w * 64;
  const int bc0 = (cb + l31) * 8, bc1 = (cb + 32 + l31) * 8;
  floatx16 acc[2][2];
  #pragma unroll
  for (int rg = 0; rg < 2; rg++)
    #pragma unroll
    for (int ct = 0; ct < 2; ct++)
      #pragma unroll
      for (int i = 0; i < 16; i++) acc[rg][ct][i] = 0.f;

  #pragma unroll
  for (int step = 0; step < 4; step++) {
    short8 a0 = *(const short8*)(sF + l31 * 72 + step * 16 + hi * 8);
    short8 a1 = *(const short8*)(sF + (32 + l31) * 72 + step * 16 + hi * 8);
    short8 b0 = *(const short8*)(Wf1e + (size_t)(step * 2 + hi) * 2048 + bc0);
    short8 b1v = *(const short8*)(Wf1e + (size_t)(step * 2 + hi) * 2048 + bc1);
    acc[0][0] = __builtin_amdgcn_mfma_f32_32x32x16_bf16(a0, b0,  acc[0][0], 0, 0, 0);
    acc[0][1] = __builtin_amdgcn_mfma_f32_32x32x16_bf16(a0, b1v, acc[0][1], 0, 0, 0);
    acc[1][0] = __builtin_amdgcn_mfma_f32_32x32x16_bf16(a1, b0,  acc[1][0], 0, 0, 0);
    acc[1][1] = __builtin_amdgcn_mfma_f32_32x32x16_bf16(a1, b1v, acc[1][1], 0, 0, 0);
  }

  #pragma unroll
  for (int rg = 0; rg < 2; rg++)
    #pragma unroll
    for (int ct = 0; ct < 2; ct++) {
      int col = cb + ct * 32 + l31;
      float bv = b1[col];
      #pragma unroll
      for (int reg = 0; reg < 16; reg++) {
        int row = rg * 32 + (reg & 3) + 8 * (reg >> 2) + 4 * hi;
        Pe[(size_t)(e0 + row) * 256 + col] = f2bf(acc[rg][ct][reg] + bv);
      }
    }
}

// ---------------- P1/P2 = h @ W1[0:128] / W1[128:256]  (node-level, bf16 out) ----------------
__global__ __launch_bounds__(256, 4) void pnode(
    const short* __restrict__ hbf,
    const short* __restrict__ Wf1a, const short* __restrict__ Wf1b,
    short* __restrict__ P1f, short* __restrict__ P2f, int N)
{
  __shared__ short sA[32 * 136];
  int t = threadIdx.x;
  int ln = t & 63, w = t >> 6;
  int l31 = ln & 31, hi = ln >> 5;
  int cb = w * 64;
  int n0 = blockIdx.x * 32;

  for (int i = t; i < 512; i += 256) {
    int r = i >> 4, c = (i & 15) * 8;
    short8 v = {0, 0, 0, 0, 0, 0, 0, 0};
    if (n0 + r < N) v = *(const short8*)(hbf + (size_t)(n0 + r) * 128 + c);
    *(short8*)(sA + r * 136 + c) = v;
  }
  __syncthreads();

  const int arow = l31 * 136;
  const int bc0 = (cb + l31) * 8, bc1 = (cb + 32 + l31) * 8;
  floatx16 acc[2][2];
  #pragma unroll
  for (int o = 0; o < 2; o++)
    #pragma unroll
    for (int ct = 0; ct < 2; ct++)
      #pragma unroll
      for (int i = 0; i < 16; i++) acc[o][ct][i] = 0.f;

  #pragma unroll
  for (int step = 0; step < 8; step++) {
    short8 a = *(const short8*)(sA + arow + step * 16 + hi * 8);
    short8 ba0 = *(const short8*)(Wf1a + (size_t)(step * 2 + hi) * 2048 + bc0);
    short8 ba1 = *(const short8*)(Wf1a + (size_t)(step * 2 + hi) * 2048 + bc1);
    short8 bb0 = *(const short8*)(Wf1b + (size_t)(step * 2 + hi) * 2048 + bc0);
    short8 bb1 = *(const short8*)(Wf1b + (size_t)(step * 2 + hi) * 2048 + bc1);
    acc[0][0] = __builtin_amdgcn_mfma_f32_32x32x16_bf16(a, ba0, acc[0][0], 0, 0, 0);
    acc[0][1] = __builtin_amdgcn_mfma_f32_32x32x16_bf16(a, ba1, acc[0][1], 0, 0, 0);
    acc[1][0] = __builtin_amdgcn_mfma_f32_32x32x16_bf16(a, bb0, acc[1][0], 0, 0, 0);
    acc[1][1] = __builtin_amdgcn_mfma_f32_32x32x16_bf16(a, bb1, acc[1][1], 0, 0, 0);
  }

  #pragma unroll
  for (int ct = 0; ct < 2; ct++) {
    int col = cb + ct * 32 + l31;
    #pragma unroll
    for (int reg = 0; reg < 16; reg++) {
      int row = (reg & 3) + 8 * (reg >> 2) + 4 * hi;
      int n = n0 + row;
      if (n < N) {
        P1f[(size_t)n * 256 + col] = f2bf(acc[0][ct][reg]);
        P2f[(size_t)n * 256 + col] = f2bf(acc[1][ct][reg]);
      }
    }
  }
}

// ---------------- message: gather-sum staging + GEMM2 + fused CSR aggregation ----------------
__global__ __launch_bounds__(256, 4) void msg_mfma(
    const short* __restrict__ P1f, const short* __restrict__ P2f,
    const short* __restrict__ Pe,
    const int* __restrict__ from_idx, const int* __restrict__ to_idx,
    const int* __restrict__ elist, const int* __restrict__ offsets,
    const short* __restrict__ Wf2, const float* __restrict__ b2,
    float* __restrict__ agg, int E)
{
  __shared__ short sA[64 * 264];
  __shared__ int from_s[64], to_s[64];
  __shared__ int rend_s[64], inter_s[64];

  int t = threadIdx.x;
  int ln = t & 63, w = t >> 6;
  int l31 = ln & 31, hi = ln >> 5;
  int cb = w * 64;
  int e0 = blockIdx.x * 64;

  if (t < 64) {
    int idx = e0 + t;
    int eid = (idx < E) ? elist[idx] : 0;
    from_s[t] = from_idx[eid];
    to_s[t] = (idx < E) ? to_idx[eid] : -1;
  }
  __syncthreads();

  if (t < 64) {
    int nd = to_s[t];
    bool head = (t == 0) || (nd != to_s[t - 1]);
    if (head && nd >= 0) {
      int re = t + 1;
      while (re < 64 && to_s[re] == nd) re++;
      rend_s[t] = re;
      inter_s[t] = (offsets[nd] == e0 + t) && (offsets[nd + 1] == e0 + re) ? 1 : 0;
    }
  }

  for (int i = t; i < 2048; i += 256) {
    int r = i >> 5, c8 = (i & 31) * 8;
    int nd = to_s[r]; if (nd < 0) nd = 0;
    short8 a = *(const short8*)(P1f + (size_t)from_s[r] * 256 + c8);
    short8 b = *(const short8*)(P2f + (size_t)nd * 256 + c8);
    short8 c = *(const short8*)(Pe + (size_t)(e0 + r) * 256 + c8);
    short8 o;
    #pragma unroll
    for (int j = 0; j < 8; j++)
      o[j] = f2bf(fmaxf(bf2f(a[j]) + bf2f(b[j]) + bf2f(c[j]), 0.f));
    *(short8*)(sA + r * 264 + c8) = o;
  }
  __syncthreads();

  const int arow0 = l31 * 264;
  const int arow1 = (32 + l31) * 264;
  const int bc0 = (cb + l31) * 8;
  const int bc1 = (cb + 32 + l31) * 8;

  floatx16 acc2[2][2];
  #pragma unroll
  for (int rg = 0; rg < 2; rg++)
    #pragma unroll
    for (int ct = 0; ct < 2; ct++)
      #pragma unroll
      for (int i = 0; i < 16; i++) acc2[rg][ct][i] = 0.f;

  {
    short8 b2buf[3][2];
    #pragma unroll
    for (int s = 0; s < 3; s++) {
      const short* bb = Wf2 + (size_t)(s * 2 + hi) * 2048;
      b2buf[s][0] = *(const short8*)(bb + bc0);
      b2buf[s][1] = *(const short8*)(bb + bc1);
    }
    short8 abuf[2][2];
    abuf[0][0] = *(const short8*)(sA + arow0 + hi * 8);
    abuf[0][1] = *(const short8*)(sA + arow1 + hi * 8);
    #pragma unroll
    for (int step = 0; step < 16; step++) {
      if (step + 1 < 16) {
        abuf[(step + 1) & 1][0] = *(const short8*)(sA + arow0 + (step + 1) * 16 + hi * 8);
        abuf[(step + 1) & 1][1] = *(const short8*)(sA + arow1 + (step + 1) * 16 + hi * 8);
      }
      acc2[0][0] = __builtin_amdgcn_mfma_f32_32x32x16_bf16(abuf[step & 1][0], b2buf[step % 3][0], acc2[0][0], 0, 0, 0);
      acc2[0][1] = __builtin_amdgcn_mfma_f32_32x32x16_bf16(abuf[step & 1][0], b2buf[step % 3][1], acc2[0][1], 0, 0, 0);
      acc2[1][0] = __builtin_amdgcn_mfma_f32_32x32x16_bf16(abuf[step & 1][1], b2buf[step % 3][0], acc2[1][0], 0, 0, 0);
      acc2[1][1] = __builtin_amdgcn_mfma_f32_32x32x16_bf16(abuf[step & 1][1], b2buf[step % 3][1], acc2[1][1], 0, 0, 0);
      if (step + 3 < 16) {
        const short* bb = Wf2 + (size_t)((step + 3) * 2 + hi) * 2048;
        b2buf[step % 3][0] = *(const short8*)(bb + bc0);
        b2buf[step % 3][1] = *(const short8*)(bb + bc1);
      }
    }
  }

  __syncthreads();
  #pragma unroll
  for (int rg = 0; rg < 2; rg++)
    #pragma unroll
    for (int ct = 0; ct < 2; ct++) {
      int col = cb + ct * 32 + l31;
      float bv = b2[col];
      #pragma unroll
      for (int reg = 0; reg < 16; reg++) {
        int row = rg * 32 + (reg & 3) + 8 * (reg >> 2) + 4 * hi;
        sA[row * 264 + col] = f2bf(acc2[rg][ct][reg] + bv);
      }
    }
  __syncthreads();

  {
    int c = t;
    for (int r = 0; r < 64; ) {
      int nd = to_s[r];
      if (nd < 0) break;
      int re = rend_s[r];
      float a = 0.f;
      for (int i = r; i < re; i++)
        a += bf2f(sA[i * 264 + c]);
      float* dst = agg + (size_t)nd * 256 + c;
      if (inter_s[r]) *dst = a;
      else unsafeAtomicAdd(dst, a);
      r = re;
    }
  }
}

// ---------------- node update: bf16 MFMA; zeroes agg after consuming ----------------
__global__ __launch_bounds__(256, 4) void update_mfma(
    float* __restrict__ h, short* __restrict__ hbf, float* __restrict__ agg,
    const short* __restrict__ Wfu, const float* __restrict__ bu, int N)
{
  __shared__ short sA[32 * 392];

  int t = threadIdx.x;
  int ln = t & 63, w = t >> 6;
  int l31 = ln & 31, hi = ln >> 5;
  int n0 = blockIdx.x * 32;

  for (int i = t; i < 512; i += 256) {
    int r = i >> 4, c = i & 15;
    short8 v = {0, 0, 0, 0, 0, 0, 0, 0};
    if (n0 + r < N) v = *(const short8*)(hbf + (size_t)(n0 + r) * 128 + c * 8);
    *(short8*)(sA + r * 392 + c * 8) = v;
  }
  for (int i = t; i < 2048; i += 256) {
    int r = i >> 6, c4 = i & 63;
    int2 pk = {0, 0};
    if (n0 + r < N) {
      float4 v = *(const float4*)(agg + (size_t)(n0 + r) * 256 + c4 * 4);
      pk.x = (int)(unsigned short)f2bf(v.x) | ((int)(unsigned short)f2bf(v.y) << 16);
      pk.y = (int)(unsigned short)f2bf(v.z) | ((int)(unsigned short)f2bf(v.w) << 16);
    }
    *(int2*)(sA + r * 392 + 128 + c4 * 4) = pk;
  }
  __syncthreads();

  {
    float4 z = {0.f, 0.f, 0.f, 0.f};
    for (int i = t; i < 2048; i += 256) {
      int r = i >> 6, c4 = i & 63;
      if (n0 + r < N)
        *(float4*)(agg + (size_t)(n0 + r) * 256 + c4 * 4) = z;
    }
  }

  const int arow = l31 * 392;
  const int bcol = (w * 32 + l31) * 8;

  floatx16 acc;
  #pragma unroll
  for (int i = 0; i < 16; i++) acc[i] = 0.f;

  {
    short8 bbuf[3];
    #pragma unroll
    for (int s = 0; s < 3; s++)
      bbuf[s] = *(const short8*)(Wfu + (size_t)(s * 2 + hi) * 1024 + bcol);
    short8 abuf[2];
    abuf[0] = *(const short8*)(sA + arow + hi * 8);
    #pragma unroll
    for (int step = 0; step < 24; step++) {
      if (step + 1 < 24)
        abuf[(step + 1) & 1] = *(const short8*)(sA + arow + (step + 1) * 16 + hi * 8);
      acc = __builtin_amdgcn_mfma_f32_32x32x16_bf16(abuf[step & 1], bbuf[step % 3], acc, 0, 0, 0);
      if (step + 3 < 24)
        bbuf[step % 3] = *(const short8*)(Wfu + (size_t)((step + 3) * 2 + hi) * 1024 + bcol);
    }
  }

  int col = w * 32 + l31;
  float bv = bu[col];
  #pragma unroll
  for (int reg = 0; reg < 16; reg++) {
    int row = (reg & 3) + 8 * (reg >> 2) + 4 * hi;
    int n = n0 + row;
    if (n < N) {
      float nv = h[(size_t)n * 128 + col] + acc[reg] + bv;
      h[(size_t)n * 128 + col] = nv;
      hbf[(size_t)n * 128 + col] = f2bf(nv);
    }
  }
}

// ---------------- fused stack + attention features ----------------
__global__ __launch_bounds__(256, 3) void stack_attfeat(
    const float* __restrict__ h, const int* __restrict__ inv,
    const short* __restrict__ Wfa1, const float* __restrict__ ba1,
    const short* __restrict__ Wfa2, const float* __restrict__ ba2,
    const int* __restrict__ qsizes, const int* __restrict__ csizes,
    float* __restrict__ flat, short* __restrict__ flatT, short* __restrict__ tfb)
{
  __shared__ short sA[64 * 136];
  __shared__ int nd_s[64];

  int t = threadIdx.x;
  int ln = t & 63, w = t >> 6;
  int l31 = ln & 31, hi = ln >> 5;
  int r0 = blockIdx.x * 64;

  if (t < 64) nd_s[t] = inv[r0 + t];
  __syncthreads();

  for (int i = t; i < 1024; i += 256) {
    int r = i >> 4, c = (i & 15) * 8;
    int nd = nd_s[r];
    float4 v0 = {0.f, 0.f, 0.f, 0.f}, v1 = {0.f, 0.f, 0.f, 0.f};
    if (nd >= 0) {
      v0 = *(const float4*)(h + (size_t)nd * 128 + c);
      v1 = *(const float4*)(h + (size_t)nd * 128 + c + 4);
    }
    *(float4*)(flat + (size_t)(r0 + r) * 128 + c) = v0;
    *(float4*)(flat + (size_t)(r0 + r) * 128 + c + 4) = v1;
    short8 s;
    s[0] = f2bf(v0.x); s[1] = f2bf(v0.y); s[2] = f2bf(v0.z); s[3] = f2bf(v0.w);
    s[4] = f2bf(v1.x); s[5] = f2bf(v1.y); s[6] = f2bf(v1.z); s[7] = f2bf(v1.w);
    *(short8*)(sA + r * 136 + c) = s;
  }
  __syncthreads();

  for (int i = t; i < 8192; i += 256) {
    int d = i >> 6, r = i & 63;
    flatT[(size_t)blockIdx.x * 8192 + d * 64 + r] = sA[r * 136 + d];
  }

  const int arow0 = l31 * 136, arow1 = (32 + l31) * 136;
  const int bcol = (w * 32 + l31) * 8;
  int col = w * 32 + l31;

  floatx16 acc[2];
  #pragma unroll
  for (int rg = 0; rg < 2; rg++)
    #pragma unroll
    for (int i = 0; i < 16; i++) acc[rg][i] = 0.f;

  #pragma unroll
  for (int step = 0; step < 8; step++) {
    short8 a0 = *(const short8*)(sA + arow0 + step * 16 + hi * 8);
    short8 a1 = *(const short8*)(sA + arow1 + step * 16 + hi * 8);
    short8 bfr = *(const short8*)(Wfa1 + (size_t)(step * 2 + hi) * 1024 + bcol);
    acc[0] = __builtin_amdgcn_mfma_f32_32x32x16_bf16(a0, bfr, acc[0], 0, 0, 0);
    acc[1] = __builtin_amdgcn_mfma_f32_32x32x16_bf16(a1, bfr, acc[1], 0, 0, 0);
  }

  __syncthreads();
  {
    float bv = ba1[col];
    #pragma unroll
    for (int rg = 0; rg < 2; rg++)
      #pragma unroll
      for (int reg = 0; reg < 16; reg++) {
        int row = rg * 32 + (reg & 3) + 8 * (reg >> 2) + 4 * hi;
        sA[row * 136 + col] = f2bf(fmaxf(acc[rg][reg] + bv, 0.f));
      }
  }
  __syncthreads();

  floatx16 acc2[2];
  #pragma unroll
  for (int rg = 0; rg < 2; rg++)
    #pragma unroll
    for (int i = 0; i < 16; i++) acc2[rg][i] = 0.f;

  #pragma unroll
  for (int step = 0; step < 8; step++) {
    short8 a0 = *(const short8*)(sA + arow0 + step * 16 + hi * 8);
    short8 a1 = *(const short8*)(sA + arow1 + step * 16 + hi * 8);
    short8 bfr = *(const short8*)(Wfa2 + (size_t)(step * 2 + hi) * 1024 + bcol);
    acc2[0] = __builtin_amdgcn_mfma_f32_32x32x16_bf16(a0, bfr, acc2[0], 0, 0, 0);
    acc2[1] = __builtin_amdgcn_mfma_f32_32x32x16_bf16(a1, bfr, acc2[1], 0, 0, 0);
  }

  {
    float bv = ba2[col];
    #pragma unroll
    for (int rg = 0; rg < 2; rg++)
      #pragma unroll
      for (int reg = 0; reg < 16; reg++) {
        int row = r0 + rg * 32 + (reg & 3) + 8 * (reg >> 2) + 4 * hi;
        int part = row >> 14, b = (row >> 6) & 255, pp = row & 63;
        int sz = part ? csizes[b] : qsizes[b];
        float m = (pp < sz) ? 1.f : 0.f;
        tfb[(size_t)row * 128 + col] = f2bf((acc2[rg][reg] + bv) * m);
      }
  }
}

// ---------------- per-pair score: MFMA logits + MFMA PV ----------------
__global__ __launch_bounds__(256, 3) void score_kernel(
    const short* __restrict__ tfb, const float* __restrict__ flat,
    const short* __restrict__ flatT,
    const int* __restrict__ qsizes, const int* __restrict__ csizes,
    float* __restrict__ out)
{
  __shared__ float SL[64 * 65];
  __shared__ float SP2[64 * 65];
  __shared__ float red[8];

  int b = blockIdx.x, t = threadIdx.x;
  int ln = t & 63, w = t >> 6;
  int l31 = ln & 31, hi = ln >> 5;
  const short* tqb = tfb + (size_t)b * 8192;
  const short* tcb = tfb + (size_t)(256 + b) * 8192;
  const float* sq = flat + (size_t)b * 8192;
  const float* sc = flat + (size_t)(256 + b) * 8192;
  const short* sqT = flatT + (size_t)b * 8192;
  const short* scT = flatT + (size_t)(256 + b) * 8192;
  int qs = qsizes[b], cs = csizes[b];

  {
    int rowb = (w & 1) * 32, cbq = (w >> 1) * 32;
    floatx16 acc;
    #pragma unroll
    for (int i = 0; i < 16; i++) acc[i] = 0.f;
    #pragma unroll
    for (int step = 0; step < 8; step++) {
      short8 a  = *(const short8*)(tqb + (size_t)(rowb + l31) * 128 + step * 16 + hi * 8);
      short8 bf = *(const short8*)(tcb + (size_t)(cbq + l31) * 128 + step * 16 + hi * 8);
      acc = __builtin_amdgcn_mfma_f32_32x32x16_bf16(a, bf, acc, 0, 0, 0);
    }
    int ccol = cbq + l31;
    #pragma unroll
    for (int reg = 0; reg < 16; reg++) {
      int qrow = rowb + (reg & 3) + 8 * (reg >> 2) + 4 * hi;
      SL[qrow * 65 + ccol] = (qrow < qs && ccol < cs) ? acc[reg] * 10.0f : -1e9f;
    }
  }
  __syncthreads();

  float rmax = -1e30f, rsum = 0.f;
  if (t < 64) {
    int q = t;
    if (q < qs) {
      for (int c = 0; c < 64; c++) rmax = fmaxf(rmax, SL[q * 65 + c]);
      for (int c = 0; c < 64; c++) rsum += __expf(SL[q * 65 + c] - rmax);
    }
  } else if (t < 128) {
    int c = t - 64;
    if (c < cs) {
      float m = -1e30f;
      for (int q = 0; q < 64; q++) m = fmaxf(m, SL[q * 65 + c]);
      float s = 0.f;
      for (int q = 0; q < 64; q++) s += __expf(SL[q * 65 + c] - m);
      float inv = 1.0f / s;
      for (int q = 0; q < 64; q++) SP2[q * 65 + c] = __expf(SL[q * 65 + c] - m) * inv;
    } else {
      for (int q = 0; q < 64; q++) SP2[q * 65 + c] = 0.f;
    }
  }
  __syncthreads();

  if (t < 64) {
    int q = t;
    if (q < qs) {
      float inv = 1.0f / rsum;
      for (int c = 0; c < 64; c++) SL[q * 65 + c] = __expf(SL[q * 65 + c] - rmax) * inv;
    } else {
      for (int c = 0; c < 64; c++) SL[q * 65 + c] = 0.f;
    }
  }
  __syncthreads();

  int dcol = w * 32 + l31;
  floatx16 accq[2], accc[2];
  #pragma unroll
  for (int rt = 0; rt < 2; rt++) {
    #pragma unroll
    for (int i = 0; i < 16; i++) { accq[rt][i] = 0.f; accc[rt][i] = 0.f; }
  }

  #pragma unroll
  for (int rt = 0; rt < 2; rt++) {
    #pragma unroll
    for (int step = 0; step < 4; step++) {
      int kb = step * 16 + hi * 8;
      int row = rt * 32 + l31;
      short8 a;
      #pragma unroll
      for (int j = 0; j < 8; j++) a[j] = f2bf(SL[row * 65 + kb + j]);
      short8 bf = *(const short8*)(scT + (size_t)dcol * 64 + kb);
      accq[rt] = __builtin_amdgcn_mfma_f32_32x32x16_bf16(a, bf, accq[rt], 0, 0, 0);
    }
  }
  #pragma unroll
  for (int rt = 0; rt < 2; rt++) {
    #pragma unroll
    for (int step = 0; step < 4; step++) {
      int kb = step * 16 + hi * 8;
      int crow = rt * 32 + l31;
      short8 a;
      #pragma unroll
      for (int j = 0; j < 8; j++) a[j] = f2bf(SP2[(kb + j) * 65 + crow]);
      short8 bf = *(const short8*)(sqT + (size_t)dcol * 64 + kb);
      accc[rt] = __builtin_amdgcn_mfma_f32_32x32x16_bf16(a, bf, accc[rt], 0, 0, 0);
    }
  }

  float qpart = 0.f, cpart = 0.f;
  #pragma unroll
  for (int rt = 0; rt < 2; rt++) {
    #pragma unroll
    for (int reg = 0; reg < 16; reg++) {
      int row = rt * 32 + (reg & 3) + 8 * (reg >> 2) + 4 * hi;
      qpart += fmaxf(sq[(size_t)row * 128 + dcol] - accq[rt][reg], 0.f);
      cpart += fmaxf(sc[(size_t)row * 128 + dcol] - accc[rt][reg], 0.f);
    }
  }

  for (int off = 32; off > 0; off >>= 1) {
    qpart += __shfl_down(qpart, off);
    cpart += __shfl_down(cpart, off);
  }
  if ((t & 63) == 0) { red[w] = qpart; red[w + 4] = cpart; }
  __syncthreads();
  if (t == 0) {
    float qsum = red[0] + red[1] + red[2] + red[3];
    float csum = red[4] + red[5] + red[6] + red[7];
    out[b] = fminf(-qsum, -csum);
  }
}

// ---------------- launch ----------------
extern "C" void kernel_launch(void* const* d_in, const int* in_sizes, int n_in,
                              void* d_out, int out_size, void* d_ws, size_t ws_size,
                              hipStream_t stream)
{
  const float* nf  = (const float*)d_in[0];
  const float* ef  = (const float*)d_in[1];
  const int* from_idx = (const int*)d_in[2];
  const int* to_idx   = (const int*)d_in[3];
  const int* pos      = (const int*)d_in[4];
  const int* qsz      = (const int*)d_in[5];
  const int* csz      = (const int*)d_in[6];
  const float* W_node = (const float*)d_in[7];
  const float* b_node = (const float*)d_in[8];
  const float* W_edge = (const float*)d_in[9];
  const float* b_edge = (const float*)d_in[10];
  const float* W1 = (const float*)d_in[11];
  const float* b1 = (const float*)d_in[12];
  const float* W2 = (const float*)d_in[13];
  const float* b2 = (const float*)d_in[14];
  const float* Wu = (const float*)d_in[15];
  const float* bu = (const float*)d_in[16];
  const float* Wa1 = (const float*)d_in[17];
  const float* ba1 = (const float*)d_in[18];
  const float* Wa2 = (const float*)d_in[19];
  const float* ba2 = (const float*)d_in[20];
  float* out = (float*)d_out;

  int N = in_sizes[0] / NODE_F;
  int E = in_sizes[1] / EDGE_F;
  int Epad = (E + 63) & ~63;
  int PAD = 2 * B_PAIRS * MAXN;   // 32768

  float* h    = (float*)d_ws;                              // N*128 f32
  float* agg  = h + (size_t)N * D;                         // N*256 f32
  short* hb   = (short*)(agg + (size_t)N * 256);           // N*128 bf16
  short* P1f  = hb + (size_t)N * D;                        // N*256 bf16
  short* P2f  = P1f + (size_t)N * 256;                     // N*256 bf16
  short* Wfn  = P2f + (size_t)N * 256;                     // 4096
  short* Wfe  = Wfn + 4096;                                // 1024
  short* Wf1a = Wfe + 1024;                                // 32768
  short* Wf1b = Wf1a + 32768;                              // 32768
  short* Wf1e = Wf1b + 32768;                              // 16384
  short* Wf2  = Wf1e + 16384;                              // 65536
  short* Wfu  = Wf2 + 65536;                               // 49152
  short* Wfa1 = Wfu + 49152;                               // 16384
  short* Wfa2 = Wfa1 + 16384;                              // 16384
  int*   deg     = (int*)(Wfa2 + 16384);                   // N
  int*   offsets = deg + N;                                // N+1
  int*   cursor  = offsets + N + 1;                        // N
  int*   elist   = cursor + N;                             // E
  int*   inv     = elist + E;                              // PAD
  uintptr_t pb = ((uintptr_t)(inv + PAD) + 15) & ~(uintptr_t)15;
  short* Pe = (short*)pb;                                  // Epad*256 bf16 (CSR order)
  // flat group aliases Pe (Pe dead after prop loop)
  float* flat  = (float*)Pe;
  short* flatT = (short*)(flat + (size_t)PAD * D);
  short* tfb16 = flatT + (size_t)PAD * D;

  hipMemsetAsync(deg, 0, (size_t)N * sizeof(int), stream);
  hist_kernel<<<256, 256, 0, stream>>>(to_idx, deg, inv, E);
  scan_kernel<<<1, 1024, 0, stream>>>(deg, offsets, cursor, pos, inv, N);
  scatter_csr<<<256, 256, 0, stream>>>(to_idx, cursor, elist, E);

  prep_w<<<916, 256, 0, stream>>>(W_node, W_edge, W1, W2, Wu, Wa1, Wa2,
                                  Wfn, Wfe, Wf1a, Wf1b, Wf1e, Wf2, Wfu, Wfa1, Wfa2);
  enc_nodes<<<(N + 31) / 32, 256, 0, stream>>>(nf, Wfn, b_node, h, hb, N);
  pe_fused<<<Epad / 64, 256, 0, stream>>>(ef, elist, Wfe, b_edge, Wf1e, b1, Pe, E);

  hipMemsetAsync(agg, 0, (size_t)N * 256 * sizeof(float), stream);
  pnode<<<(N + 31) / 32, 256, 0, stream>>>(hb, Wf1a, Wf1b, P1f, P2f, N);

  for (int s = 0; s < PROP_STEPS; s++) {
    msg_mfma<<<Epad / 64, 256, 0, stream>>>(P1f, P2f, Pe, from_idx, to_idx, elist, offsets,
                                            Wf2, b2, agg, E);
    update_mfma<<<(N + 31) / 32, 256, 0, stream>>>(h, hb, agg, Wfu, bu, N);
    if (s + 1 < PROP_STEPS)
      pnode<<<(N + 31) / 32, 256, 0, stream>>>(hb, Wf1a, Wf1b, P1f, P2f, N);
  }

  stack_attfeat<<<PAD / 64, 256, 0, stream>>>(h, inv, Wfa1, ba1, Wfa2, ba2,
                                              qsz, csz, flat, flatT, tfb16);
  score_kernel<<<B_PAIRS, 256, 0, stream>>>(tfb16, flat, flatT, qsz, csz, out);
}